// Round 1
// baseline (5767.187 us; speedup 1.0000x reference)
//
#include <hip/hip_runtime.h>

#define NN 100000   // nodes
#define NE 640000   // edges
#define DIN 128
#define DH 256
#define DOUT 256
#define NG 256      // graphs

typedef __bf16 bf16_t;
typedef __bf16 bf16x8 __attribute__((ext_vector_type(8)));
typedef float f32x4 __attribute__((ext_vector_type(4)));

__device__ __forceinline__ float bf2f(unsigned u) {
  union { unsigned i; float f; } c; c.i = u << 16; return c.f;
}

// ---------------- degree count ----------------
__global__ void k_count(const int* __restrict__ dst, int* __restrict__ cnt) {
  int e = blockIdx.x * 256 + threadIdx.x;
  if (e < NE) atomicAdd(&cnt[dst[e]], 1);
}

// ---------------- scatter layer1: agg1[dst] += x[src]  (128 f32) ----------------
// 32 threads per edge, 4 dims each (float4). grid = NE*32/256 = 80000 exact.
__global__ void k_scatter1(const int* __restrict__ src, const int* __restrict__ dst,
                           const float* __restrict__ x, float* __restrict__ agg) {
  unsigned t = blockIdx.x * 256 + threadIdx.x;
  int e = t >> 5, q = t & 31;
  int s = src[e], d = dst[e];
  const float4* xp = (const float4*)(x + (size_t)s * DIN);
  float4 v = xp[q];
  float* a = agg + (size_t)d * DIN + q * 4;
  unsafeAtomicAdd(a + 0, v.x);
  unsafeAtomicAdd(a + 1, v.y);
  unsafeAtomicAdd(a + 2, v.z);
  unsafeAtomicAdd(a + 3, v.w);
}

// ---------------- scatter layer2: agg2[dst] += h[src]  (256 bf16 -> f32) ----------------
// 32 threads per edge, 8 dims each (uint4 = 8 bf16). grid = 80000 exact.
__global__ void k_scatter2(const int* __restrict__ src, const int* __restrict__ dst,
                           const bf16_t* __restrict__ h, float* __restrict__ agg) {
  unsigned t = blockIdx.x * 256 + threadIdx.x;
  int e = t >> 5, q = t & 31;
  int s = src[e], d = dst[e];
  const uint4* hp = (const uint4*)(h + (size_t)s * DH);
  uint4 v = hp[q];
  float* a = agg + (size_t)d * DH + q * 8;
  unsafeAtomicAdd(a + 0, bf2f(v.x & 0xffffu));
  unsafeAtomicAdd(a + 1, bf2f(v.x >> 16));
  unsafeAtomicAdd(a + 2, bf2f(v.y & 0xffffu));
  unsafeAtomicAdd(a + 3, bf2f(v.y >> 16));
  unsafeAtomicAdd(a + 4, bf2f(v.z & 0xffffu));
  unsafeAtomicAdd(a + 5, bf2f(v.z >> 16));
  unsafeAtomicAdd(a + 6, bf2f(v.w & 0xffffu));
  unsafeAtomicAdd(a + 7, bf2f(v.w >> 16));
}

// ---------------- weight pack: [K][N] f32 pair -> MFMA b-frag order bf16 ----------------
// layout: [kc][nt][lane][8] ; k = kc*32 + (lane>>4)*8 + j ; n = nt*16 + (lane&15)
__global__ void k_pack1(const float* __restrict__ Wl, const float* __restrict__ Wr,
                        bf16_t* __restrict__ Bp) {
  int t = blockIdx.x * 256 + threadIdx.x;   // 8 kc * 16 nt * 64 lanes = 8192
  if (t >= 8192) return;
  int lane = t & 63, nt = (t >> 6) & 15, kc = t >> 10;
  int n = nt * 16 + (lane & 15);
  int k0 = kc * 32 + (lane >> 4) * 8;
  bf16_t* o = Bp + ((size_t)(kc * 16 + nt) * 64 + lane) * 8;
  for (int j = 0; j < 8; ++j) {
    int k = k0 + j;
    float v = (k < 128) ? Wl[k * 256 + n] : Wr[(k - 128) * 256 + n];
    o[j] = (bf16_t)v;
  }
}
__global__ void k_pack2(const float* __restrict__ Wl, const float* __restrict__ Wr,
                        bf16_t* __restrict__ Bp) {
  int t = blockIdx.x * 256 + threadIdx.x;   // 16 kc * 16 nt * 64 = 16384
  if (t >= 16384) return;
  int lane = t & 63, nt = (t >> 6) & 15, kc = t >> 10;
  int n = nt * 16 + (lane & 15);
  int k0 = kc * 32 + (lane >> 4) * 8;
  bf16_t* o = Bp + ((size_t)(kc * 16 + nt) * 64 + lane) * 8;
  for (int j = 0; j < 8; ++j) {
    int k = k0 + j;
    float v = (k < 256) ? Wl[k * 256 + n] : Wr[(k - 256) * 256 + n];
    o[j] = (bf16_t)v;
  }
}

// ---------------- GEMM1: h = relu([mean|x] @ [W1l;W1r] + b1), K=256 ----------------
__launch_bounds__(256, 2)
__global__ void k_gemm1(const float* __restrict__ x, const float* __restrict__ agg,
                        const int* __restrict__ cnt, const float* __restrict__ b1,
                        const bf16_t* __restrict__ Bp, bf16_t* __restrict__ h) {
  __shared__ unsigned char smem[64 * 512];   // A tile 64 x 256 bf16, XOR-swizzled
  int n0 = blockIdx.x * 64;
  int tid = threadIdx.x;
  {
    int row = tid >> 2, part = tid & 3;
    int node = n0 + row;
    const float4* ap = (const float4*)(agg + (size_t)node * DIN);
    const float4* xp = (const float4*)(x + (size_t)node * DIN);
    float r = 1.0f;
    if (node < NN) r = 1.0f / fmaxf((float)cnt[node], 1.0f);
    unsigned sw = (row & 7) << 4;
#pragma unroll
    for (int i = 0; i < 16; ++i) {
      int fi = i * 4 + part;                 // float4 col index 0..63
      float4 v = {0.f, 0.f, 0.f, 0.f};
      if (node < NN) {
        if (fi < 32) { v = ap[fi]; v.x *= r; v.y *= r; v.z *= r; v.w *= r; }
        else          { v = xp[fi - 32]; }
      }
      unsigned cb = ((unsigned)(fi * 8)) ^ sw;
      bf16_t* dp = (bf16_t*)(smem + row * 512 + cb);
      dp[0] = (bf16_t)v.x; dp[1] = (bf16_t)v.y; dp[2] = (bf16_t)v.z; dp[3] = (bf16_t)v.w;
    }
  }
  __syncthreads();
  int wave = tid >> 6, lane = tid & 63, lhi = lane >> 4, llo = lane & 15;
  f32x4 acc[4][4] = {};
  const bf16x8* bptr = (const bf16x8*)Bp;
#pragma unroll
  for (int kc = 0; kc < 8; ++kc) {
    bf16x8 a[4], b[4];
#pragma unroll
    for (int mi = 0; mi < 4; ++mi) {
      int row = mi * 16 + llo;
      unsigned cb = ((unsigned)((kc * 32 + lhi * 8) * 2)) ^ ((row & 7) << 4);
      a[mi] = *(const bf16x8*)(smem + row * 512 + cb);
    }
#pragma unroll
    for (int ni = 0; ni < 4; ++ni)
      b[ni] = bptr[(kc * 16 + wave * 4 + ni) * 64 + lane];
#pragma unroll
    for (int mi = 0; mi < 4; ++mi)
#pragma unroll
      for (int ni = 0; ni < 4; ++ni)
        acc[mi][ni] = __builtin_amdgcn_mfma_f32_16x16x32_bf16(a[mi], b[ni], acc[mi][ni], 0, 0, 0);
  }
  // epilogue: relu(acc + b1) -> h (bf16)
#pragma unroll
  for (int ni = 0; ni < 4; ++ni) {
    int col = wave * 64 + ni * 16 + llo;
    float bias = b1[col];
#pragma unroll
    for (int mi = 0; mi < 4; ++mi)
#pragma unroll
      for (int j = 0; j < 4; ++j) {
        int node = n0 + mi * 16 + lhi * 4 + j;
        if (node < NN) {
          float v = fmaxf(acc[mi][ni][j] + bias, 0.f);
          h[(size_t)node * DH + col] = (bf16_t)v;
        }
      }
  }
}

// ---------------- GEMM2: out_pool += [mean2|h] @ [W2l;W2r] + b2, K=512, fused pooling ----------------
__launch_bounds__(256, 2)
__global__ void k_gemm2(const bf16_t* __restrict__ h, const float* __restrict__ agg,
                        const int* __restrict__ cnt, const float* __restrict__ b2,
                        const bf16_t* __restrict__ Bp, const int* __restrict__ batch,
                        float* __restrict__ out) {
  __shared__ unsigned char smem[64 * 1024];  // A tile 64 x 512 bf16; reused as f32 pool[64][256]
  __shared__ int sbatch[64];
  int n0 = blockIdx.x * 64;
  int tid = threadIdx.x;
  if (tid < 64) sbatch[tid] = (n0 + tid < NN) ? batch[n0 + tid] : -1;
  {
    int row = tid >> 2, part = tid & 3;
    int node = n0 + row;
    float r = 1.0f;
    if (node < NN) r = 1.0f / fmaxf((float)cnt[node], 1.0f);
    unsigned sw = (row & 7) << 4;
    const float4* ap = (const float4*)(agg + (size_t)node * DH);
#pragma unroll
    for (int i = 0; i < 16; ++i) {
      int fi = i * 4 + part;                 // 0..63 -> cols fi*4 (mean2 half)
      float4 v = {0.f, 0.f, 0.f, 0.f};
      if (node < NN) { v = ap[fi]; v.x *= r; v.y *= r; v.z *= r; v.w *= r; }
      unsigned cb = ((unsigned)(fi * 8)) ^ sw;
      bf16_t* dp = (bf16_t*)(smem + row * 1024 + cb);
      dp[0] = (bf16_t)v.x; dp[1] = (bf16_t)v.y; dp[2] = (bf16_t)v.z; dp[3] = (bf16_t)v.w;
    }
    const uint4* hp = (const uint4*)(h + (size_t)node * DH);
#pragma unroll
    for (int i = 0; i < 8; ++i) {
      int gi = i * 4 + part;                 // 0..31 -> byte cols 512 + gi*16 (h half)
      uint4 v = {0u, 0u, 0u, 0u};
      if (node < NN) v = hp[gi];
      unsigned cb = (512u + (unsigned)(gi * 16)) ^ sw;
      *(uint4*)(smem + row * 1024 + cb) = v;
    }
  }
  __syncthreads();
  int wave = tid >> 6, lane = tid & 63, lhi = lane >> 4, llo = lane & 15;
  f32x4 acc[4][4] = {};
  const bf16x8* bptr = (const bf16x8*)Bp;
#pragma unroll
  for (int kc = 0; kc < 16; ++kc) {
    bf16x8 a[4], b[4];
#pragma unroll
    for (int mi = 0; mi < 4; ++mi) {
      int row = mi * 16 + llo;
      unsigned cb = ((unsigned)((kc * 32 + lhi * 8) * 2)) ^ ((row & 7) << 4);
      a[mi] = *(const bf16x8*)(smem + row * 1024 + cb);
    }
#pragma unroll
    for (int ni = 0; ni < 4; ++ni)
      b[ni] = bptr[(kc * 16 + wave * 4 + ni) * 64 + lane];
#pragma unroll
    for (int mi = 0; mi < 4; ++mi)
#pragma unroll
      for (int ni = 0; ni < 4; ++ni)
        acc[mi][ni] = __builtin_amdgcn_mfma_f32_16x16x32_bf16(a[mi], b[ni], acc[mi][ni], 0, 0, 0);
  }
  __syncthreads();                           // all reads of A done; reuse smem as pool
  float* pool = (float*)smem;                // [64][256]
#pragma unroll
  for (int ni = 0; ni < 4; ++ni) {
    int col = wave * 64 + ni * 16 + llo;
    float bias = b2[col];
#pragma unroll
    for (int mi = 0; mi < 4; ++mi)
#pragma unroll
      for (int j = 0; j < 4; ++j) {
        int row = mi * 16 + lhi * 4 + j;
        pool[row * 256 + col] = acc[mi][ni][j] + bias;
      }
  }
  __syncthreads();
  // segmented per-column reduction over sorted batch ids, few atomics per block
  {
    int col = tid;                           // 0..255
    float s = 0.f; int cur = -1;
    for (int n = 0; n < 64; ++n) {
      int g = sbatch[n];
      if (g < 0) break;
      if (g != cur) {
        if (cur >= 0) unsafeAtomicAdd(&out[(size_t)cur * DOUT + col], s);
        cur = g; s = 0.f;
      }
      s += pool[n * 256 + col];
    }
    if (cur >= 0) unsafeAtomicAdd(&out[(size_t)cur * DOUT + col], s);
  }
}

extern "C" void kernel_launch(void* const* d_in, const int* in_sizes, int n_in,
                              void* d_out, int out_size, void* d_ws, size_t ws_size,
                              hipStream_t stream) {
  const float* x   = (const float*)d_in[0];
  const int*   ei  = (const int*)d_in[1];     // [2][NE] int32
  const int*   bat = (const int*)d_in[2];     // [NN] int32 (sorted)
  const float* W1l = (const float*)d_in[3];
  const float* b1  = (const float*)d_in[4];
  const float* W1r = (const float*)d_in[5];
  const float* W2l = (const float*)d_in[6];
  const float* b2  = (const float*)d_in[7];
  const float* W2r = (const float*)d_in[8];
  const int* src = ei;
  const int* dst = ei + NE;

  char* ws = (char*)d_ws;
  size_t off = 0;
  int* cnt = (int*)(ws + off);      off += ((size_t)NN * 4 + 255) & ~(size_t)255;
  bf16_t* Bp1 = (bf16_t*)(ws + off); off += (size_t)256 * 256 * 2;
  bf16_t* Bp2 = (bf16_t*)(ws + off); off += (size_t)512 * 256 * 2;
  float* agg = (float*)(ws + off);   off += (size_t)NN * 256 * 4;  // agg1 (N*128) and agg2 (N*256) share this
  bf16_t* h = (bf16_t*)(ws + off);   off += (size_t)NN * 256 * 2;

  hipMemsetAsync(cnt, 0, (size_t)NN * 4, stream);
  hipMemsetAsync(agg, 0, (size_t)NN * DIN * 4, stream);
  k_pack1<<<32, 256, 0, stream>>>(W1l, W1r, Bp1);
  k_pack2<<<64, 256, 0, stream>>>(W2l, W2r, Bp2);
  k_count<<<(NE + 255) / 256, 256, 0, stream>>>(dst, cnt);
  k_scatter1<<<NE * 32 / 256, 256, 0, stream>>>(src, dst, x, agg);
  k_gemm1<<<(NN + 63) / 64, 256, 0, stream>>>(x, agg, cnt, b1, Bp1, h);
  hipMemsetAsync(agg, 0, (size_t)NN * DH * 4, stream);
  k_scatter2<<<NE * 32 / 256, 256, 0, stream>>>(src, dst, h, agg);
  hipMemsetAsync(d_out, 0, (size_t)out_size * 4, stream);
  k_gemm2<<<(NN + 63) / 64, 256, 0, stream>>>(h, agg, cnt, b2, Bp2, bat, (float*)d_out);
}

// Round 2
// 322.645 us; speedup vs baseline: 17.8747x; 17.8747x over previous
//
#include <hip/hip_runtime.h>

#define NN 100000   // nodes
#define NE 640000   // edges
#define DIN 128
#define DH 256
#define DOUT 256
#define NG 256      // graphs
#define NB1 ((NN + 255) / 256)   // 391 blocks for scan

typedef __bf16 bf16_t;
typedef __bf16 bf16x8 __attribute__((ext_vector_type(8)));
typedef __bf16 bf16x4 __attribute__((ext_vector_type(4)));
typedef float f32x4 __attribute__((ext_vector_type(4)));

__device__ __forceinline__ float bf2f(unsigned u) {
  union { unsigned i; float f; } c; c.i = u << 16; return c.f;
}

// ---------------- degree count ----------------
__global__ void k_count(const int* __restrict__ dst, int* __restrict__ cnt) {
  int e = blockIdx.x * 256 + threadIdx.x;
  if (e < NE) atomicAdd(&cnt[dst[e]], 1);
}

// ---------------- prefix scan (3 kernels): rowptr = exclusive_scan(cnt) ----------------
__global__ void k_scan1(const int* __restrict__ cnt, int* __restrict__ rowptr,
                        int* __restrict__ part) {
  __shared__ int s[256];
  int t = threadIdx.x, i = blockIdx.x * 256 + t;
  int v = (i < NN) ? cnt[i] : 0;
  s[t] = v; __syncthreads();
#pragma unroll
  for (int off = 1; off < 256; off <<= 1) {
    int u = (t >= off) ? s[t - off] : 0;
    __syncthreads();
    s[t] += u;
    __syncthreads();
  }
  if (i < NN) rowptr[i] = s[t] - v;          // block-local exclusive
  if (t == 255) part[blockIdx.x] = s[255];   // block total
}

__global__ void k_scan2(int* __restrict__ part) {  // single block, in-place exclusive scan
  __shared__ int s[512];
  int t = threadIdx.x;
  int v = (t < NB1) ? part[t] : 0;
  s[t] = v; __syncthreads();
#pragma unroll
  for (int off = 1; off < 512; off <<= 1) {
    int u = (t >= off) ? s[t - off] : 0;
    __syncthreads();
    s[t] += u;
    __syncthreads();
  }
  if (t < NB1) part[t] = s[t] - v;
}

__global__ void k_scan3(int* __restrict__ rowptr, const int* __restrict__ part) {
  int i = blockIdx.x * 256 + threadIdx.x;
  if (i < NN) rowptr[i] += part[i >> 8];
  if (i == 0) rowptr[NN] = NE;
}

// ---------------- bucket edges by dst: col[rowptr[d] + fill[d]++] = src ----------------
__global__ void k_bucket(const int* __restrict__ src, const int* __restrict__ dst,
                         const int* __restrict__ rowptr, int* __restrict__ fill,
                         int* __restrict__ col) {
  int e = blockIdx.x * 256 + threadIdx.x;
  if (e < NE) {
    int d = dst[e];
    int p = rowptr[d] + atomicAdd(&fill[d], 1);
    col[p] = src[e];
  }
}

// ---------------- gather-mean layer1: aggb1[n] = bf16(mean_{s in N(n)} x[s]), 128 dims ----------------
// 32 lanes per node, 4 f32 dims each. grid = NN*32/256 = 12500.
__global__ void k_agg1(const int* __restrict__ rowptr, const int* __restrict__ col,
                       const float* __restrict__ x, bf16_t* __restrict__ aggb) {
  unsigned t = blockIdx.x * 256 + threadIdx.x;
  int n = t >> 5, q = t & 31;
  if (n >= NN) return;
  int e0 = rowptr[n], e1 = rowptr[n + 1];
  float4 acc = {0.f, 0.f, 0.f, 0.f};
  for (int e = e0; e < e1; ++e) {
    int s = col[e];
    float4 v = ((const float4*)(x + (size_t)s * DIN))[q];
    acc.x += v.x; acc.y += v.y; acc.z += v.z; acc.w += v.w;
  }
  float r = (e1 > e0) ? 1.0f / (float)(e1 - e0) : 0.f;
  bf16x4 o;
  o[0] = (bf16_t)(acc.x * r); o[1] = (bf16_t)(acc.y * r);
  o[2] = (bf16_t)(acc.z * r); o[3] = (bf16_t)(acc.w * r);
  *(bf16x4*)(aggb + (size_t)n * DIN + q * 4) = o;
}

// ---------------- gather-mean layer2: aggb2[n] = bf16(mean h[s]), 256 dims ----------------
// 32 lanes per node, 8 bf16 dims each. grid = 12500.
__global__ void k_agg2(const int* __restrict__ rowptr, const int* __restrict__ col,
                       const bf16_t* __restrict__ h, bf16_t* __restrict__ aggb) {
  unsigned t = blockIdx.x * 256 + threadIdx.x;
  int n = t >> 5, q = t & 31;
  if (n >= NN) return;
  int e0 = rowptr[n], e1 = rowptr[n + 1];
  float a0 = 0, a1 = 0, a2 = 0, a3 = 0, a4 = 0, a5 = 0, a6 = 0, a7 = 0;
  for (int e = e0; e < e1; ++e) {
    int s = col[e];
    uint4 v = ((const uint4*)(h + (size_t)s * DH))[q];
    a0 += bf2f(v.x & 0xffffu); a1 += bf2f(v.x >> 16);
    a2 += bf2f(v.y & 0xffffu); a3 += bf2f(v.y >> 16);
    a4 += bf2f(v.z & 0xffffu); a5 += bf2f(v.z >> 16);
    a6 += bf2f(v.w & 0xffffu); a7 += bf2f(v.w >> 16);
  }
  float r = (e1 > e0) ? 1.0f / (float)(e1 - e0) : 0.f;
  bf16x8 o;
  o[0] = (bf16_t)(a0 * r); o[1] = (bf16_t)(a1 * r);
  o[2] = (bf16_t)(a2 * r); o[3] = (bf16_t)(a3 * r);
  o[4] = (bf16_t)(a4 * r); o[5] = (bf16_t)(a5 * r);
  o[6] = (bf16_t)(a6 * r); o[7] = (bf16_t)(a7 * r);
  *(bf16x8*)(aggb + (size_t)n * DH + q * 8) = o;
}

// ---------------- weight pack: [K][N] f32 pair -> MFMA b-frag order bf16 ----------------
// layout: [kc][nt][lane][8] ; k = kc*32 + (lane>>4)*8 + j ; n = nt*16 + (lane&15)
__global__ void k_pack1(const float* __restrict__ Wl, const float* __restrict__ Wr,
                        bf16_t* __restrict__ Bp) {
  int t = blockIdx.x * 256 + threadIdx.x;   // 8 kc * 16 nt * 64 lanes = 8192
  if (t >= 8192) return;
  int lane = t & 63, nt = (t >> 6) & 15, kc = t >> 10;
  int n = nt * 16 + (lane & 15);
  int k0 = kc * 32 + (lane >> 4) * 8;
  bf16_t* o = Bp + ((size_t)(kc * 16 + nt) * 64 + lane) * 8;
  for (int j = 0; j < 8; ++j) {
    int k = k0 + j;
    float v = (k < 128) ? Wl[k * 256 + n] : Wr[(k - 128) * 256 + n];
    o[j] = (bf16_t)v;
  }
}
__global__ void k_pack2(const float* __restrict__ Wl, const float* __restrict__ Wr,
                        bf16_t* __restrict__ Bp) {
  int t = blockIdx.x * 256 + threadIdx.x;   // 16 kc * 16 nt * 64 = 16384
  if (t >= 16384) return;
  int lane = t & 63, nt = (t >> 6) & 15, kc = t >> 10;
  int n = nt * 16 + (lane & 15);
  int k0 = kc * 32 + (lane >> 4) * 8;
  bf16_t* o = Bp + ((size_t)(kc * 16 + nt) * 64 + lane) * 8;
  for (int j = 0; j < 8; ++j) {
    int k = k0 + j;
    float v = (k < 256) ? Wl[k * 256 + n] : Wr[(k - 256) * 256 + n];
    o[j] = (bf16_t)v;
  }
}

// ---------------- GEMM1: h = relu([mean|x] @ [W1l;W1r] + b1), K=256 ----------------
__launch_bounds__(256, 2)
__global__ void k_gemm1(const float* __restrict__ x, const bf16_t* __restrict__ aggb,
                        const float* __restrict__ b1,
                        const bf16_t* __restrict__ Bp, bf16_t* __restrict__ h) {
  __shared__ unsigned char smem[64 * 512];   // A tile 64 x 256 bf16, XOR-swizzled
  int n0 = blockIdx.x * 64;
  int tid = threadIdx.x;
  {
    int row = tid >> 2, part = tid & 3;
    int node = n0 + row;
    unsigned sw = (row & 7) << 4;
    const uint4* ap = (const uint4*)(aggb + (size_t)node * DIN);   // 16 uint4 (bf16 mean)
    const float4* xp = (const float4*)(x + (size_t)node * DIN);    // 32 float4
#pragma unroll
    for (int i = 0; i < 4; ++i) {
      int mi = i * 4 + part;                 // 0..15
      uint4 v = {0u, 0u, 0u, 0u};
      if (node < NN) v = ap[mi];
      *(uint4*)(smem + row * 512 + (((unsigned)(mi * 16)) ^ sw)) = v;
    }
#pragma unroll
    for (int i = 0; i < 4; ++i) {
      int gi = i * 4 + part;                 // 0..15
      float4 va = {0,0,0,0}, vb = {0,0,0,0};
      if (node < NN) { va = xp[gi * 2]; vb = xp[gi * 2 + 1]; }
      bf16x8 w;
      w[0] = (bf16_t)va.x; w[1] = (bf16_t)va.y; w[2] = (bf16_t)va.z; w[3] = (bf16_t)va.w;
      w[4] = (bf16_t)vb.x; w[5] = (bf16_t)vb.y; w[6] = (bf16_t)vb.z; w[7] = (bf16_t)vb.w;
      *(bf16x8*)(smem + row * 512 + ((unsigned)(256 + gi * 16) ^ sw)) = w;
    }
  }
  __syncthreads();
  int wave = tid >> 6, lane = tid & 63, lhi = lane >> 4, llo = lane & 15;
  f32x4 acc[4][4] = {};
  const bf16x8* bptr = (const bf16x8*)Bp;
#pragma unroll
  for (int kc = 0; kc < 8; ++kc) {
    bf16x8 a[4], b[4];
#pragma unroll
    for (int mi = 0; mi < 4; ++mi) {
      int row = mi * 16 + llo;
      unsigned cb = ((unsigned)((kc * 32 + lhi * 8) * 2)) ^ ((row & 7) << 4);
      a[mi] = *(const bf16x8*)(smem + row * 512 + cb);
    }
#pragma unroll
    for (int ni = 0; ni < 4; ++ni)
      b[ni] = bptr[(kc * 16 + wave * 4 + ni) * 64 + lane];
#pragma unroll
    for (int mi = 0; mi < 4; ++mi)
#pragma unroll
      for (int ni = 0; ni < 4; ++ni)
        acc[mi][ni] = __builtin_amdgcn_mfma_f32_16x16x32_bf16(a[mi], b[ni], acc[mi][ni], 0, 0, 0);
  }
  // epilogue: relu(acc + b1) -> h (bf16)
#pragma unroll
  for (int ni = 0; ni < 4; ++ni) {
    int col = wave * 64 + ni * 16 + llo;
    float bias = b1[col];
#pragma unroll
    for (int mi = 0; mi < 4; ++mi)
#pragma unroll
      for (int j = 0; j < 4; ++j) {
        int node = n0 + mi * 16 + lhi * 4 + j;
        if (node < NN) {
          float v = fmaxf(acc[mi][ni][j] + bias, 0.f);
          h[(size_t)node * DH + col] = (bf16_t)v;
        }
      }
  }
}

// ---------------- GEMM2: out_pool += [mean2|h] @ [W2l;W2r] + b2, K=512, fused pooling ----------------
__launch_bounds__(256, 2)
__global__ void k_gemm2(const bf16_t* __restrict__ h, const bf16_t* __restrict__ aggb,
                        const float* __restrict__ b2,
                        const bf16_t* __restrict__ Bp, const int* __restrict__ batch,
                        float* __restrict__ out) {
  __shared__ unsigned char smem[64 * 1024];  // A tile 64 x 512 bf16; reused as f32 pool[64][256]
  __shared__ int sbatch[64];
  int n0 = blockIdx.x * 64;
  int tid = threadIdx.x;
  if (tid < 64) sbatch[tid] = (n0 + tid < NN) ? batch[n0 + tid] : -1;
  {
    int row = tid >> 2, part = tid & 3;
    int node = n0 + row;
    unsigned sw = (row & 7) << 4;
    const uint4* ap = (const uint4*)(aggb + (size_t)node * DH);   // 32 uint4 (bf16 mean2)
    const uint4* hp = (const uint4*)(h + (size_t)node * DH);      // 32 uint4
#pragma unroll
    for (int i = 0; i < 8; ++i) {
      int mi = i * 4 + part;                 // 0..31
      uint4 v = {0u, 0u, 0u, 0u};
      if (node < NN) v = ap[mi];
      *(uint4*)(smem + row * 1024 + (((unsigned)(mi * 16)) ^ sw)) = v;
    }
#pragma unroll
    for (int i = 0; i < 8; ++i) {
      int gi = i * 4 + part;                 // 0..31
      uint4 v = {0u, 0u, 0u, 0u};
      if (node < NN) v = hp[gi];
      *(uint4*)(smem + row * 1024 + ((unsigned)(512 + gi * 16) ^ sw)) = v;
    }
  }
  __syncthreads();
  int wave = tid >> 6, lane = tid & 63, lhi = lane >> 4, llo = lane & 15;
  f32x4 acc[4][4] = {};
  const bf16x8* bptr = (const bf16x8*)Bp;
#pragma unroll
  for (int kc = 0; kc < 16; ++kc) {
    bf16x8 a[4], b[4];
#pragma unroll
    for (int mi = 0; mi < 4; ++mi) {
      int row = mi * 16 + llo;
      unsigned cb = ((unsigned)((kc * 32 + lhi * 8) * 2)) ^ ((row & 7) << 4);
      a[mi] = *(const bf16x8*)(smem + row * 1024 + cb);
    }
#pragma unroll
    for (int ni = 0; ni < 4; ++ni)
      b[ni] = bptr[(kc * 16 + wave * 4 + ni) * 64 + lane];
#pragma unroll
    for (int mi = 0; mi < 4; ++mi)
#pragma unroll
      for (int ni = 0; ni < 4; ++ni)
        acc[mi][ni] = __builtin_amdgcn_mfma_f32_16x16x32_bf16(a[mi], b[ni], acc[mi][ni], 0, 0, 0);
  }
  __syncthreads();                           // all reads of A done; reuse smem as pool
  float* pool = (float*)smem;                // [64][256]
#pragma unroll
  for (int ni = 0; ni < 4; ++ni) {
    int col = wave * 64 + ni * 16 + llo;
    float bias = b2[col];
#pragma unroll
    for (int mi = 0; mi < 4; ++mi)
#pragma unroll
      for (int j = 0; j < 4; ++j) {
        int row = mi * 16 + lhi * 4 + j;
        pool[row * 256 + col] = acc[mi][ni][j] + bias;
      }
  }
  __syncthreads();
  // segmented per-column reduction over sorted batch ids, few atomics per block
  {
    int col = tid;                           // 0..255
    float s = 0.f; int cur = -1;
    for (int n = 0; n < 64; ++n) {
      int g = sbatch[n];
      if (g < 0) break;
      if (g != cur) {
        if (cur >= 0) unsafeAtomicAdd(&out[(size_t)cur * DOUT + col], s);
        cur = g; s = 0.f;
      }
      s += pool[n * 256 + col];
    }
    if (cur >= 0) unsafeAtomicAdd(&out[(size_t)cur * DOUT + col], s);
  }
}

extern "C" void kernel_launch(void* const* d_in, const int* in_sizes, int n_in,
                              void* d_out, int out_size, void* d_ws, size_t ws_size,
                              hipStream_t stream) {
  const float* x   = (const float*)d_in[0];
  const int*   ei  = (const int*)d_in[1];     // [2][NE] int32
  const int*   bat = (const int*)d_in[2];     // [NN] int32 (sorted)
  const float* W1l = (const float*)d_in[3];
  const float* b1  = (const float*)d_in[4];
  const float* W1r = (const float*)d_in[5];
  const float* W2l = (const float*)d_in[6];
  const float* b2  = (const float*)d_in[7];
  const float* W2r = (const float*)d_in[8];
  const int* src = ei;
  const int* dst = ei + NE;

  char* ws = (char*)d_ws;
  size_t off = 0;
  int* cnt     = (int*)(ws + off); off += ((size_t)NN * 4 + 255) & ~(size_t)255;
  int* rowptr  = (int*)(ws + off); off += ((size_t)(NN + 1) * 4 + 255) & ~(size_t)255;
  int* part    = (int*)(ws + off); off += 512 * 4;
  int* fill    = (int*)(ws + off); off += ((size_t)NN * 4 + 255) & ~(size_t)255;
  int* col     = (int*)(ws + off); off += (size_t)NE * 4;
  bf16_t* Bp1  = (bf16_t*)(ws + off); off += (size_t)256 * 256 * 2;
  bf16_t* Bp2  = (bf16_t*)(ws + off); off += (size_t)512 * 256 * 2;
  bf16_t* ag1  = (bf16_t*)(ws + off); off += (size_t)NN * DIN * 2;
  bf16_t* ag2  = (bf16_t*)(ws + off); off += (size_t)NN * DH * 2;
  bf16_t* h    = (bf16_t*)(ws + off); off += (size_t)NN * DH * 2;

  hipMemsetAsync(cnt, 0, (size_t)NN * 4, stream);
  hipMemsetAsync(fill, 0, (size_t)NN * 4, stream);
  hipMemsetAsync(d_out, 0, (size_t)out_size * 4, stream);
  k_pack1<<<32, 256, 0, stream>>>(W1l, W1r, Bp1);
  k_pack2<<<64, 256, 0, stream>>>(W2l, W2r, Bp2);
  k_count<<<(NE + 255) / 256, 256, 0, stream>>>(dst, cnt);
  k_scan1<<<NB1, 256, 0, stream>>>(cnt, rowptr, part);
  k_scan2<<<1, 512, 0, stream>>>(part);
  k_scan3<<<NB1, 256, 0, stream>>>(rowptr, part);
  k_bucket<<<(NE + 255) / 256, 256, 0, stream>>>(src, dst, rowptr, fill, col);
  k_agg1<<<NN * 32 / 256, 256, 0, stream>>>(rowptr, col, x, ag1);
  k_gemm1<<<(NN + 63) / 64, 256, 0, stream>>>(x, ag1, b1, Bp1, h);
  k_agg2<<<NN * 32 / 256, 256, 0, stream>>>(rowptr, col, h, ag2);
  k_gemm2<<<(NN + 63) / 64, 256, 0, stream>>>(h, ag2, b2, Bp2, bat, (float*)d_out);
}

// Round 3
// 302.994 us; speedup vs baseline: 19.0340x; 1.0649x over previous
//
#include <hip/hip_runtime.h>

#define NN 100000   // nodes
#define NE 640000   // edges
#define DIN 128
#define DH 256
#define DOUT 256
#define NG 256      // graphs
#define NB1 ((NN + 255) / 256)   // 391 blocks for scan

#define EB 2048                      // edge-pool blocks
#define CHE ((NE + EB - 1) / EB)     // 313 edges/block
#define NBL 1024                     // node-pool blocks
#define CHN ((NN + NBL - 1) / NBL)   // 98 nodes/block

typedef __bf16 bf16_t;
typedef __bf16 bf16x8 __attribute__((ext_vector_type(8)));
typedef __bf16 bf16x4 __attribute__((ext_vector_type(4)));
typedef float f32x4 __attribute__((ext_vector_type(4)));

__device__ __forceinline__ float bf2f(unsigned u) {
  union { unsigned i; float f; } c; c.i = u << 16; return c.f;
}

// ---------------- degree count ----------------
__global__ void k_count(const int* __restrict__ dst, int* __restrict__ cnt) {
  int e = blockIdx.x * 256 + threadIdx.x;
  if (e < NE) atomicAdd(&cnt[dst[e]], 1);
}

// ---------------- prefix scan (3 kernels): rowptr = exclusive_scan(cnt) ----------------
__global__ void k_scan1(const int* __restrict__ cnt, int* __restrict__ rowptr,
                        int* __restrict__ part) {
  __shared__ int s[256];
  int t = threadIdx.x, i = blockIdx.x * 256 + t;
  int v = (i < NN) ? cnt[i] : 0;
  s[t] = v; __syncthreads();
#pragma unroll
  for (int off = 1; off < 256; off <<= 1) {
    int u = (t >= off) ? s[t - off] : 0;
    __syncthreads();
    s[t] += u;
    __syncthreads();
  }
  if (i < NN) rowptr[i] = s[t] - v;          // block-local exclusive
  if (t == 255) part[blockIdx.x] = s[255];   // block total
}

__global__ void k_scan2(int* __restrict__ part) {  // single block, in-place exclusive scan
  __shared__ int s[512];
  int t = threadIdx.x;
  int v = (t < NB1) ? part[t] : 0;
  s[t] = v; __syncthreads();
#pragma unroll
  for (int off = 1; off < 512; off <<= 1) {
    int u = (t >= off) ? s[t - off] : 0;
    __syncthreads();
    s[t] += u;
    __syncthreads();
  }
  if (t < NB1) part[t] = s[t] - v;
}

__global__ void k_scan3(int* __restrict__ rowptr, const int* __restrict__ part) {
  int i = blockIdx.x * 256 + threadIdx.x;
  if (i < NN) rowptr[i] += part[i >> 8];
  if (i == 0) rowptr[NN] = NE;
}

// ---------------- graph start index: gstart[g] = first node with batch >= g ----------------
__global__ void k_gstart(const int* __restrict__ batch, int* __restrict__ gstart) {
  int n = blockIdx.x * 256 + threadIdx.x;
  if (n >= NN) return;
  int b = batch[n];
  int prev = (n == 0) ? -1 : batch[n - 1];
  for (int g = prev + 1; g <= b; ++g) gstart[g] = n;
  if (n == NN - 1) {
    for (int g = b + 1; g <= NG; ++g) gstart[g] = NN;
  }
}

// ---------------- bucket edges by dst: col/wedge/gedge in CSR (graph-sorted) order ----------------
__global__ void k_bucket(const int* __restrict__ src, const int* __restrict__ dst,
                         const int* __restrict__ rowptr, const int* __restrict__ cnt,
                         const int* __restrict__ batch, int* __restrict__ fill,
                         int* __restrict__ col, float* __restrict__ wedge,
                         int* __restrict__ gedge) {
  int e = blockIdx.x * 256 + threadIdx.x;
  if (e < NE) {
    int d = dst[e];
    int p = rowptr[d] + atomicAdd(&fill[d], 1);
    col[p] = src[e];
    wedge[p] = 1.0f / (float)cnt[d];
    gedge[p] = batch[d];
  }
}

// ---------------- gather-mean layer1: aggb1[n] = bf16(mean_{s in N(n)} x[s]), 128 dims ----------------
__global__ void k_agg1(const int* __restrict__ rowptr, const int* __restrict__ col,
                       const float* __restrict__ x, bf16_t* __restrict__ aggb) {
  unsigned t = blockIdx.x * 256 + threadIdx.x;
  int n = t >> 5, q = t & 31;
  if (n >= NN) return;
  int e0 = rowptr[n], e1 = rowptr[n + 1];
  float4 acc = {0.f, 0.f, 0.f, 0.f};
  for (int e = e0; e < e1; ++e) {
    int s = col[e];
    float4 v = ((const float4*)(x + (size_t)s * DIN))[q];
    acc.x += v.x; acc.y += v.y; acc.z += v.z; acc.w += v.w;
  }
  float r = (e1 > e0) ? 1.0f / (float)(e1 - e0) : 0.f;
  bf16x4 o;
  o[0] = (bf16_t)(acc.x * r); o[1] = (bf16_t)(acc.y * r);
  o[2] = (bf16_t)(acc.z * r); o[3] = (bf16_t)(acc.w * r);
  *(bf16x4*)(aggb + (size_t)n * DIN + q * 4) = o;
}

// ---------------- weight pack layer1: [K][N] f32 pair -> MFMA b-frag order bf16 ----------------
__global__ void k_pack1(const float* __restrict__ Wl, const float* __restrict__ Wr,
                        bf16_t* __restrict__ Bp) {
  int t = blockIdx.x * 256 + threadIdx.x;   // 8 kc * 16 nt * 64 lanes = 8192
  if (t >= 8192) return;
  int lane = t & 63, nt = (t >> 6) & 15, kc = t >> 10;
  int n = nt * 16 + (lane & 15);
  int k0 = kc * 32 + (lane >> 4) * 8;
  bf16_t* o = Bp + ((size_t)(kc * 16 + nt) * 64 + lane) * 8;
  for (int j = 0; j < 8; ++j) {
    int k = k0 + j;
    float v = (k < 128) ? Wl[k * 256 + n] : Wr[(k - 128) * 256 + n];
    o[j] = (bf16_t)v;
  }
}

// ---------------- GEMM1: h = relu([mean|x] @ [W1l;W1r] + b1), K=256 ----------------
__launch_bounds__(256, 4)
__global__ void k_gemm1(const float* __restrict__ x, const bf16_t* __restrict__ aggb,
                        const float* __restrict__ b1,
                        const bf16_t* __restrict__ Bp, bf16_t* __restrict__ h) {
  __shared__ unsigned char smem[64 * 512];   // A tile 64 x 256 bf16, XOR-swizzled
  int n0 = blockIdx.x * 64;
  int tid = threadIdx.x;
  {
    int row = tid >> 2, part = tid & 3;
    int node = n0 + row;
    unsigned sw = (row & 7) << 4;
    const uint4* ap = (const uint4*)(aggb + (size_t)node * DIN);   // 16 uint4 (bf16 mean)
    const float4* xp = (const float4*)(x + (size_t)node * DIN);    // 32 float4
#pragma unroll
    for (int i = 0; i < 4; ++i) {
      int mi = i * 4 + part;                 // 0..15
      uint4 v = {0u, 0u, 0u, 0u};
      if (node < NN) v = ap[mi];
      *(uint4*)(smem + row * 512 + (((unsigned)(mi * 16)) ^ sw)) = v;
    }
#pragma unroll
    for (int i = 0; i < 4; ++i) {
      int gi = i * 4 + part;                 // 0..15
      float4 va = {0,0,0,0}, vb = {0,0,0,0};
      if (node < NN) { va = xp[gi * 2]; vb = xp[gi * 2 + 1]; }
      bf16x8 w;
      w[0] = (bf16_t)va.x; w[1] = (bf16_t)va.y; w[2] = (bf16_t)va.z; w[3] = (bf16_t)va.w;
      w[4] = (bf16_t)vb.x; w[5] = (bf16_t)vb.y; w[6] = (bf16_t)vb.z; w[7] = (bf16_t)vb.w;
      *(bf16x8*)(smem + row * 512 + ((unsigned)(256 + gi * 16) ^ sw)) = w;
    }
  }
  __syncthreads();
  int wave = tid >> 6, lane = tid & 63, lhi = lane >> 4, llo = lane & 15;
  f32x4 acc[4][4] = {};
  const bf16x8* bptr = (const bf16x8*)Bp;
#pragma unroll
  for (int kc = 0; kc < 8; ++kc) {
    bf16x8 a[4], b[4];
#pragma unroll
    for (int mi = 0; mi < 4; ++mi) {
      int row = mi * 16 + llo;
      unsigned cb = ((unsigned)((kc * 32 + lhi * 8) * 2)) ^ ((row & 7) << 4);
      a[mi] = *(const bf16x8*)(smem + row * 512 + cb);
    }
#pragma unroll
    for (int ni = 0; ni < 4; ++ni)
      b[ni] = bptr[(kc * 16 + wave * 4 + ni) * 64 + lane];
#pragma unroll
    for (int mi = 0; mi < 4; ++mi)
#pragma unroll
      for (int ni = 0; ni < 4; ++ni)
        acc[mi][ni] = __builtin_amdgcn_mfma_f32_16x16x32_bf16(a[mi], b[ni], acc[mi][ni], 0, 0, 0);
  }
  // epilogue: relu(acc + b1) -> h (bf16)
#pragma unroll
  for (int ni = 0; ni < 4; ++ni) {
    int col = wave * 64 + ni * 16 + llo;
    float bias = b1[col];
#pragma unroll
    for (int mi = 0; mi < 4; ++mi)
#pragma unroll
      for (int j = 0; j < 4; ++j) {
        int node = n0 + mi * 16 + lhi * 4 + j;
        if (node < NN) {
          float v = fmaxf(acc[mi][ni][j] + bias, 0.f);
          h[(size_t)node * DH + col] = (bf16_t)v;
        }
      }
  }
}

// ---------------- pool over edges: Y1[g] += (1/c_dst) * h[src], CSR order is graph-sorted ----------------
__global__ void k_poolE(const int* __restrict__ col, const float* __restrict__ wedge,
                        const int* __restrict__ gedge, const bf16_t* __restrict__ h,
                        float* __restrict__ Y1) {
  __shared__ float gbuf[16][256];
  int tid = threadIdx.x;
  int c0 = blockIdx.x * CHE;
  int c1 = (c0 + CHE < NE) ? c0 + CHE : NE;
  if (c0 >= c1) return;                       // uniform across block
  int gmin = gedge[c0], gmax = gedge[c1 - 1];
  bool ldsok = (gmax - gmin) < 16;
  for (int i = tid; i < 16 * 256; i += 256) ((float*)gbuf)[i] = 0.f;
  __syncthreads();
  int slot = tid >> 5, q = tid & 31;
  float a0 = 0, a1 = 0, a2 = 0, a3 = 0, a4 = 0, a5 = 0, a6 = 0, a7 = 0;
  int curg = -1;
#define FLUSH1()                                                        \
  do { if (curg >= 0) {                                                 \
    if (ldsok) { float* gp = &gbuf[curg - gmin][q * 8];                 \
      atomicAdd(gp + 0, a0); atomicAdd(gp + 1, a1);                     \
      atomicAdd(gp + 2, a2); atomicAdd(gp + 3, a3);                     \
      atomicAdd(gp + 4, a4); atomicAdd(gp + 5, a5);                     \
      atomicAdd(gp + 6, a6); atomicAdd(gp + 7, a7);                     \
    } else { float* yp = Y1 + (size_t)curg * 256 + q * 8;               \
      unsafeAtomicAdd(yp + 0, a0); unsafeAtomicAdd(yp + 1, a1);         \
      unsafeAtomicAdd(yp + 2, a2); unsafeAtomicAdd(yp + 3, a3);         \
      unsafeAtomicAdd(yp + 4, a4); unsafeAtomicAdd(yp + 5, a5);         \
      unsafeAtomicAdd(yp + 6, a6); unsafeAtomicAdd(yp + 7, a7); }       \
    a0 = a1 = a2 = a3 = a4 = a5 = a6 = a7 = 0.f; } } while (0)
  for (int e = c0 + slot; e < c1; e += 8) {
    int g = gedge[e];
    if (g != curg) { FLUSH1(); curg = g; }
    int s = col[e];
    float w = wedge[e];
    uint4 v = ((const uint4*)(h + (size_t)s * DH))[q];
    a0 += w * bf2f(v.x & 0xffffu); a1 += w * bf2f(v.x >> 16);
    a2 += w * bf2f(v.y & 0xffffu); a3 += w * bf2f(v.y >> 16);
    a4 += w * bf2f(v.z & 0xffffu); a5 += w * bf2f(v.z >> 16);
    a6 += w * bf2f(v.w & 0xffffu); a7 += w * bf2f(v.w >> 16);
  }
  FLUSH1();
#undef FLUSH1
  __syncthreads();
  if (ldsok) {
    int ng = gmax - gmin + 1;
    for (int gi = 0; gi < ng; ++gi)
      unsafeAtomicAdd(&Y1[(size_t)(gmin + gi) * 256 + tid], gbuf[gi][tid]);
  }
}

// ---------------- pool over nodes: Y2[g] += h[n], batch sorted ----------------
__global__ void k_poolN(const int* __restrict__ batch, const bf16_t* __restrict__ h,
                        float* __restrict__ Y2) {
  __shared__ float gbuf[16][256];
  int tid = threadIdx.x;
  int n0 = blockIdx.x * CHN;
  int n1 = (n0 + CHN < NN) ? n0 + CHN : NN;
  if (n0 >= n1) return;
  int gmin = batch[n0], gmax = batch[n1 - 1];
  bool ldsok = (gmax - gmin) < 16;
  for (int i = tid; i < 16 * 256; i += 256) ((float*)gbuf)[i] = 0.f;
  __syncthreads();
  int slot = tid >> 5, q = tid & 31;
  float a0 = 0, a1 = 0, a2 = 0, a3 = 0, a4 = 0, a5 = 0, a6 = 0, a7 = 0;
  int curg = -1;
#define FLUSH2()                                                        \
  do { if (curg >= 0) {                                                 \
    if (ldsok) { float* gp = &gbuf[curg - gmin][q * 8];                 \
      atomicAdd(gp + 0, a0); atomicAdd(gp + 1, a1);                     \
      atomicAdd(gp + 2, a2); atomicAdd(gp + 3, a3);                     \
      atomicAdd(gp + 4, a4); atomicAdd(gp + 5, a5);                     \
      atomicAdd(gp + 6, a6); atomicAdd(gp + 7, a7);                     \
    } else { float* yp = Y2 + (size_t)curg * 256 + q * 8;               \
      unsafeAtomicAdd(yp + 0, a0); unsafeAtomicAdd(yp + 1, a1);         \
      unsafeAtomicAdd(yp + 2, a2); unsafeAtomicAdd(yp + 3, a3);         \
      unsafeAtomicAdd(yp + 4, a4); unsafeAtomicAdd(yp + 5, a5);         \
      unsafeAtomicAdd(yp + 6, a6); unsafeAtomicAdd(yp + 7, a7); }       \
    a0 = a1 = a2 = a3 = a4 = a5 = a6 = a7 = 0.f; } } while (0)
  for (int n = n0 + slot; n < n1; n += 8) {
    int g = batch[n];
    if (g != curg) { FLUSH2(); curg = g; }
    uint4 v = ((const uint4*)(h + (size_t)n * DH))[q];
    a0 += bf2f(v.x & 0xffffu); a1 += bf2f(v.x >> 16);
    a2 += bf2f(v.y & 0xffffu); a3 += bf2f(v.y >> 16);
    a4 += bf2f(v.z & 0xffffu); a5 += bf2f(v.z >> 16);
    a6 += bf2f(v.w & 0xffffu); a7 += bf2f(v.w >> 16);
  }
  FLUSH2();
#undef FLUSH2
  __syncthreads();
  if (ldsok) {
    int ng = gmax - gmin + 1;
    for (int gi = 0; gi < ng; ++gi)
      unsafeAtomicAdd(&Y2[(size_t)(gmin + gi) * 256 + tid], gbuf[gi][tid]);
  }
}

// ---------------- final: out[g] = Y1[g]@W2l + Y2[g]@W2r + cnt_g*b2 (f32) ----------------
__global__ void k_out(const float* __restrict__ Y1, const float* __restrict__ Y2,
                      const float* __restrict__ W2l, const float* __restrict__ W2r,
                      const float* __restrict__ b2, const int* __restrict__ gstart,
                      float* __restrict__ out) {
  __shared__ float y1s[256], y2s[256];
  int g = blockIdx.x, t = threadIdx.x;
  y1s[t] = Y1[(size_t)g * 256 + t];
  y2s[t] = Y2[(size_t)g * 256 + t];
  __syncthreads();
  float cntf = (float)(gstart[g + 1] - gstart[g]);
  float s = b2[t] * cntf;
#pragma unroll 4
  for (int k = 0; k < 256; ++k) {
    s += y1s[k] * W2l[k * 256 + t];
    s += y2s[k] * W2r[k * 256 + t];
  }
  out[(size_t)g * 256 + t] = s;
}

extern "C" void kernel_launch(void* const* d_in, const int* in_sizes, int n_in,
                              void* d_out, int out_size, void* d_ws, size_t ws_size,
                              hipStream_t stream) {
  const float* x   = (const float*)d_in[0];
  const int*   ei  = (const int*)d_in[1];     // [2][NE] int32
  const int*   bat = (const int*)d_in[2];     // [NN] int32 (sorted)
  const float* W1l = (const float*)d_in[3];
  const float* b1  = (const float*)d_in[4];
  const float* W1r = (const float*)d_in[5];
  const float* W2l = (const float*)d_in[6];
  const float* b2  = (const float*)d_in[7];
  const float* W2r = (const float*)d_in[8];
  const int* src = ei;
  const int* dst = ei + NE;

  char* ws = (char*)d_ws;
  size_t off = 0;
  int* cnt     = (int*)(ws + off); off += ((size_t)NN * 4 + 255) & ~(size_t)255;
  int* rowptr  = (int*)(ws + off); off += ((size_t)(NN + 1) * 4 + 255) & ~(size_t)255;
  int* part    = (int*)(ws + off); off += 512 * 4;
  int* fill    = (int*)(ws + off); off += ((size_t)NN * 4 + 255) & ~(size_t)255;
  int* gstart  = (int*)(ws + off); off += ((size_t)(NG + 1) * 4 + 255) & ~(size_t)255;
  int* col     = (int*)(ws + off); off += (size_t)NE * 4;
  float* wedge = (float*)(ws + off); off += (size_t)NE * 4;
  int* gedge   = (int*)(ws + off); off += (size_t)NE * 4;
  bf16_t* Bp1  = (bf16_t*)(ws + off); off += (size_t)256 * 256 * 2;
  float* Y1    = (float*)(ws + off); off += (size_t)NG * 256 * 4;
  float* Y2    = (float*)(ws + off); off += (size_t)NG * 256 * 4;
  bf16_t* ag1  = (bf16_t*)(ws + off); off += (size_t)NN * DIN * 2;
  bf16_t* h    = (bf16_t*)(ws + off); off += (size_t)NN * DH * 2;

  hipMemsetAsync(cnt, 0, (size_t)NN * 4, stream);
  hipMemsetAsync(fill, 0, (size_t)NN * 4, stream);
  hipMemsetAsync(Y1, 0, (size_t)NG * 256 * 4 * 2, stream);   // Y1 and Y2 contiguous
  k_pack1<<<32, 256, 0, stream>>>(W1l, W1r, Bp1);
  k_gstart<<<NB1, 256, 0, stream>>>(bat, gstart);
  k_count<<<(NE + 255) / 256, 256, 0, stream>>>(dst, cnt);
  k_scan1<<<NB1, 256, 0, stream>>>(cnt, rowptr, part);
  k_scan2<<<1, 512, 0, stream>>>(part);
  k_scan3<<<NB1, 256, 0, stream>>>(rowptr, part);
  k_bucket<<<(NE + 255) / 256, 256, 0, stream>>>(src, dst, rowptr, cnt, bat, fill,
                                                 col, wedge, gedge);
  k_agg1<<<NN * 32 / 256, 256, 0, stream>>>(rowptr, col, x, ag1);
  k_gemm1<<<(NN + 63) / 64, 256, 0, stream>>>(x, ag1, b1, Bp1, h);
  k_poolE<<<EB, 256, 0, stream>>>(col, wedge, gedge, h, Y1);
  k_poolN<<<NBL, 256, 0, stream>>>(bat, h, Y2);
  k_out<<<NG, 256, 0, stream>>>(Y1, Y2, W2l, W2r, b2, gstart, (float*)d_out);
}

// Round 4
// 297.426 us; speedup vs baseline: 19.3903x; 1.0187x over previous
//
#include <hip/hip_runtime.h>

#define NN 100000   // nodes
#define NE 640000   // edges
#define DIN 128
#define DH 256
#define DOUT 256
#define NG 256      // graphs
#define NB1 ((NN + 255) / 256)   // 391 blocks for scan

#define EB 2048                      // edge-pool blocks
#define CHE ((NE + EB - 1) / EB)     // 313 edges/block
#define NBL 1024                     // node-pool blocks
#define CHN ((NN + NBL - 1) / NBL)   // 98 nodes/block

typedef __bf16 bf16_t;
typedef __bf16 bf16x8 __attribute__((ext_vector_type(8)));
typedef float f32x4 __attribute__((ext_vector_type(4)));
typedef float f32v2 __attribute__((ext_vector_type(2)));

__device__ __forceinline__ float bf2f(unsigned u) {
  union { unsigned i; float f; } c; c.i = u << 16; return c.f;
}

// ---------------- fp8 e4m3 pack/unpack (HW path; consistent-roundtrip) ----------------
#if __has_builtin(__builtin_amdgcn_cvt_pk_fp8_f32) && __has_builtin(__builtin_amdgcn_cvt_pk_f32_fp8)
#define USE_HW_FP8 1
#else
#define USE_HW_FP8 0
#endif

#if !USE_HW_FP8
__device__ __forceinline__ unsigned f32_to_fp8_1(float f) {  // f >= 0 (post-relu)
  if (f < 0.015625f) {                       // subnormal region, step 2^-9
    int m = (int)rintf(f * 512.0f);          // 0..8 (8 == 2^-6 encodes as 0x08)
    return (unsigned)m;
  }
  unsigned bits = __float_as_uint(f);
  unsigned rb = bits + 0xFFFFFu + ((bits >> 20) & 1u);   // RNE to 3-bit mantissa
  unsigned e = rb >> 23;
  return (((e - 120u) << 3) | ((rb >> 20) & 7u)) & 0xffu;
}
__device__ __forceinline__ float fp8_to_f32_1(unsigned b) {
  unsigned s = b >> 7, e = (b >> 3) & 15u, m = b & 7u;
  float v = (e == 0) ? (float)m * 0.001953125f
                     : __uint_as_float(((e + 120u) << 23) | (m << 20));
  return s ? -v : v;
}
#endif

__device__ __forceinline__ unsigned pack4_fp8(float v0, float v1, float v2, float v3) {
#if USE_HW_FP8
  int u = __builtin_amdgcn_cvt_pk_fp8_f32(v0, v1, 0, false);
  u = __builtin_amdgcn_cvt_pk_fp8_f32(v2, v3, u, true);
  return (unsigned)u;
#else
  return f32_to_fp8_1(v0) | (f32_to_fp8_1(v1) << 8) |
         (f32_to_fp8_1(v2) << 16) | (f32_to_fp8_1(v3) << 24);
#endif
}

__device__ __forceinline__ void unpack8_fp8(uint2 v, float* o) {
#if USE_HW_FP8
  f32v2 a = __builtin_amdgcn_cvt_pk_f32_fp8((int)v.x, false);
  f32v2 b = __builtin_amdgcn_cvt_pk_f32_fp8((int)v.x, true);
  f32v2 c = __builtin_amdgcn_cvt_pk_f32_fp8((int)v.y, false);
  f32v2 d = __builtin_amdgcn_cvt_pk_f32_fp8((int)v.y, true);
  o[0] = a[0]; o[1] = a[1]; o[2] = b[0]; o[3] = b[1];
  o[4] = c[0]; o[5] = c[1]; o[6] = d[0]; o[7] = d[1];
#else
  o[0] = fp8_to_f32_1(v.x & 0xffu);         o[1] = fp8_to_f32_1((v.x >> 8) & 0xffu);
  o[2] = fp8_to_f32_1((v.x >> 16) & 0xffu); o[3] = fp8_to_f32_1(v.x >> 24);
  o[4] = fp8_to_f32_1(v.y & 0xffu);         o[5] = fp8_to_f32_1((v.y >> 8) & 0xffu);
  o[6] = fp8_to_f32_1((v.y >> 16) & 0xffu); o[7] = fp8_to_f32_1(v.y >> 24);
#endif
}

// hf8 row layout: byte p (0..255) holds dim c = (p&~63) | ((p&3)<<4) | ((p>>2)&15)
__device__ __forceinline__ int fp8dim(int p) {
  return (p & ~63) | ((p & 3) << 4) | ((p >> 2) & 15);
}

// ---------------- x -> bf16 cast ----------------
__global__ void k_xcast(const float* __restrict__ x, bf16_t* __restrict__ xb) {
  size_t i = ((size_t)blockIdx.x * 256 + threadIdx.x) * 8;
  if (i >= (size_t)NN * DIN) return;
  float4 a = *(const float4*)(x + i), b = *(const float4*)(x + i + 4);
  bf16x8 o;
  o[0] = (bf16_t)a.x; o[1] = (bf16_t)a.y; o[2] = (bf16_t)a.z; o[3] = (bf16_t)a.w;
  o[4] = (bf16_t)b.x; o[5] = (bf16_t)b.y; o[6] = (bf16_t)b.z; o[7] = (bf16_t)b.w;
  *(bf16x8*)(xb + i) = o;
}

// ---------------- degree count ----------------
__global__ void k_count(const int* __restrict__ dst, int* __restrict__ cnt) {
  int e = blockIdx.x * 256 + threadIdx.x;
  if (e < NE) atomicAdd(&cnt[dst[e]], 1);
}

// ---------------- prefix scan (3 kernels): rowptr = exclusive_scan(cnt) ----------------
__global__ void k_scan1(const int* __restrict__ cnt, int* __restrict__ rowptr,
                        int* __restrict__ part) {
  __shared__ int s[256];
  int t = threadIdx.x, i = blockIdx.x * 256 + t;
  int v = (i < NN) ? cnt[i] : 0;
  s[t] = v; __syncthreads();
#pragma unroll
  for (int off = 1; off < 256; off <<= 1) {
    int u = (t >= off) ? s[t - off] : 0;
    __syncthreads();
    s[t] += u;
    __syncthreads();
  }
  if (i < NN) rowptr[i] = s[t] - v;
  if (t == 255) part[blockIdx.x] = s[255];
}

__global__ void k_scan2(int* __restrict__ part) {
  __shared__ int s[512];
  int t = threadIdx.x;
  int v = (t < NB1) ? part[t] : 0;
  s[t] = v; __syncthreads();
#pragma unroll
  for (int off = 1; off < 512; off <<= 1) {
    int u = (t >= off) ? s[t - off] : 0;
    __syncthreads();
    s[t] += u;
    __syncthreads();
  }
  if (t < NB1) part[t] = s[t] - v;
}

__global__ void k_scan3(int* __restrict__ rowptr, const int* __restrict__ part) {
  int i = blockIdx.x * 256 + threadIdx.x;
  if (i < NN) rowptr[i] += part[i >> 8];
  if (i == 0) rowptr[NN] = NE;
}

// ---------------- graph start index ----------------
__global__ void k_gstart(const int* __restrict__ batch, int* __restrict__ gstart) {
  int n = blockIdx.x * 256 + threadIdx.x;
  if (n >= NN) return;
  int b = batch[n];
  int prev = (n == 0) ? -1 : batch[n - 1];
  for (int g = prev + 1; g <= b; ++g) gstart[g] = n;
  if (n == NN - 1) {
    for (int g = b + 1; g <= NG; ++g) gstart[g] = NN;
  }
}

// ---------------- bucket edges by dst ----------------
__global__ void k_bucket(const int* __restrict__ src, const int* __restrict__ dst,
                         const int* __restrict__ rowptr, int* __restrict__ fill,
                         int* __restrict__ col, int* __restrict__ dstE) {
  int e = blockIdx.x * 256 + threadIdx.x;
  if (e < NE) {
    int d = dst[e];
    int p = rowptr[d] + atomicAdd(&fill[d], 1);
    col[p] = src[e];
    dstE[p] = d;
  }
}

// ---------------- gather-mean layer1 (bf16 x): 16 lanes/node, 8 dims each ----------------
__global__ void k_agg1(const int* __restrict__ rowptr, const int* __restrict__ col,
                       const bf16_t* __restrict__ xb, bf16_t* __restrict__ ag1) {
  unsigned t = blockIdx.x * 256 + threadIdx.x;
  int n = t >> 4, q = t & 15;
  if (n >= NN) return;
  int e0 = rowptr[n], e1 = rowptr[n + 1];
  float a0 = 0, a1 = 0, a2 = 0, a3 = 0, a4 = 0, a5 = 0, a6 = 0, a7 = 0;
  for (int e = e0; e < e1; ++e) {
    int s = col[e];
    uint4 v = ((const uint4*)(xb + (size_t)s * DIN))[q];
    a0 += bf2f(v.x & 0xffffu); a1 += bf2f(v.x >> 16);
    a2 += bf2f(v.y & 0xffffu); a3 += bf2f(v.y >> 16);
    a4 += bf2f(v.z & 0xffffu); a5 += bf2f(v.z >> 16);
    a6 += bf2f(v.w & 0xffffu); a7 += bf2f(v.w >> 16);
  }
  float r = (e1 > e0) ? __builtin_amdgcn_rcpf((float)(e1 - e0)) : 0.f;
  bf16x8 o;
  o[0] = (bf16_t)(a0 * r); o[1] = (bf16_t)(a1 * r);
  o[2] = (bf16_t)(a2 * r); o[3] = (bf16_t)(a3 * r);
  o[4] = (bf16_t)(a4 * r); o[5] = (bf16_t)(a5 * r);
  o[6] = (bf16_t)(a6 * r); o[7] = (bf16_t)(a7 * r);
  ((bf16x8*)(ag1 + (size_t)n * DIN))[q] = o;
}

// ---------------- weight pack layer1 ----------------
__global__ void k_pack1(const float* __restrict__ Wl, const float* __restrict__ Wr,
                        bf16_t* __restrict__ Bp) {
  int t = blockIdx.x * 256 + threadIdx.x;   // 8 kc * 16 nt * 64 lanes = 8192
  if (t >= 8192) return;
  int lane = t & 63, nt = (t >> 6) & 15, kc = t >> 10;
  int n = nt * 16 + (lane & 15);
  int k0 = kc * 32 + (lane >> 4) * 8;
  bf16_t* o = Bp + ((size_t)(kc * 16 + nt) * 64 + lane) * 8;
  for (int j = 0; j < 8; ++j) {
    int k = k0 + j;
    float v = (k < 128) ? Wl[k * 256 + n] : Wr[(k - 128) * 256 + n];
    o[j] = (bf16_t)v;
  }
}

// ---------------- GEMM1: hf8 = fp8(relu([mean|x] @ [W1l;W1r] + b1)), K=256 ----------------
__launch_bounds__(256, 4)
__global__ void k_gemm1(const bf16_t* __restrict__ xb, const bf16_t* __restrict__ ag1,
                        const float* __restrict__ b1,
                        const bf16_t* __restrict__ Bp, unsigned char* __restrict__ hf8) {
  __shared__ unsigned char smem[64 * 512];   // A tile 64 x 256 bf16, XOR-swizzled
  int n0 = blockIdx.x * 64;
  int tid = threadIdx.x;
  {
    int row = tid >> 2, part = tid & 3;
    int node = n0 + row;
    unsigned sw = (row & 7) << 4;
    const uint4* ap = (const uint4*)(ag1 + (size_t)node * DIN);   // 16 uint4 mean
    const uint4* xp = (const uint4*)(xb + (size_t)node * DIN);    // 16 uint4 x
#pragma unroll
    for (int i = 0; i < 4; ++i) {
      int mi = i * 4 + part;                 // 0..15
      uint4 va = {0u, 0u, 0u, 0u}, vx = {0u, 0u, 0u, 0u};
      if (node < NN) { va = ap[mi]; vx = xp[mi]; }
      *(uint4*)(smem + row * 512 + (((unsigned)(mi * 16)) ^ sw)) = va;
      *(uint4*)(smem + row * 512 + ((unsigned)(256 + mi * 16) ^ sw)) = vx;
    }
  }
  __syncthreads();
  int wave = tid >> 6, lane = tid & 63, lhi = lane >> 4, llo = lane & 15;
  f32x4 acc[4][4] = {};
  const bf16x8* bptr = (const bf16x8*)Bp;
#pragma unroll
  for (int kc = 0; kc < 8; ++kc) {
    bf16x8 a[4], b[4];
#pragma unroll
    for (int mi = 0; mi < 4; ++mi) {
      int row = mi * 16 + llo;
      unsigned cb = ((unsigned)((kc * 32 + lhi * 8) * 2)) ^ ((row & 7) << 4);
      a[mi] = *(const bf16x8*)(smem + row * 512 + cb);
    }
#pragma unroll
    for (int ni = 0; ni < 4; ++ni)
      b[ni] = bptr[(kc * 16 + wave * 4 + ni) * 64 + lane];
#pragma unroll
    for (int mi = 0; mi < 4; ++mi)
#pragma unroll
      for (int ni = 0; ni < 4; ++ni)
        acc[mi][ni] = __builtin_amdgcn_mfma_f32_16x16x32_bf16(a[mi], b[ni], acc[mi][ni], 0, 0, 0);
  }
  // epilogue: relu(acc + b1) -> fp8, packed 4/thread per row (cols llo+16*ni), coalesced
  float bias[4];
#pragma unroll
  for (int ni = 0; ni < 4; ++ni) bias[ni] = b1[wave * 64 + ni * 16 + llo];
#pragma unroll
  for (int mi = 0; mi < 4; ++mi)
#pragma unroll
    for (int j = 0; j < 4; ++j) {
      int node = n0 + mi * 16 + lhi * 4 + j;
      if (node < NN) {
        float v0 = fmaxf(acc[mi][0][j] + bias[0], 0.f);
        float v1 = fmaxf(acc[mi][1][j] + bias[1], 0.f);
        float v2 = fmaxf(acc[mi][2][j] + bias[2], 0.f);
        float v3 = fmaxf(acc[mi][3][j] + bias[3], 0.f);
        unsigned u = pack4_fp8(v0, v1, v2, v3);
        *(unsigned*)(hf8 + (size_t)node * 256 + wave * 64 + llo * 4) = u;
      }
    }
}

// ---------------- pool over edges: Y1[g] += (1/c_dst) * h[src] ----------------
__global__ void k_poolE(const int* __restrict__ col, const int* __restrict__ dstE,
                        const int* __restrict__ cnt, const int* __restrict__ batch,
                        const unsigned char* __restrict__ hf8, float* __restrict__ Y1) {
  int tid = threadIdx.x;
  int c0 = blockIdx.x * CHE;
  int c1 = (c0 + CHE < NE) ? c0 + CHE : NE;
  if (c0 >= c1) return;
  int slot = tid >> 5, q = tid & 31;
  float a[8] = {0, 0, 0, 0, 0, 0, 0, 0};
  int curg = -1;
  for (int e = c0 + slot; e < c1; e += 8) {
    int d = dstE[e];
    int g = batch[d];
    if (g != curg) {
      if (curg >= 0) {
#pragma unroll
        for (int j = 0; j < 8; ++j) {
          unsafeAtomicAdd(&Y1[(size_t)curg * 256 + fp8dim(q * 8 + j)], a[j]);
          a[j] = 0.f;
        }
      }
      curg = g;
    }
    float w = __builtin_amdgcn_rcpf((float)cnt[d]);
    int s = col[e];
    uint2 v = *(const uint2*)(hf8 + (size_t)s * 256 + q * 8);
    float o[8];
    unpack8_fp8(v, o);
#pragma unroll
    for (int j = 0; j < 8; ++j) a[j] += w * o[j];
  }
  if (curg >= 0) {
#pragma unroll
    for (int j = 0; j < 8; ++j)
      unsafeAtomicAdd(&Y1[(size_t)curg * 256 + fp8dim(q * 8 + j)], a[j]);
  }
}

// ---------------- pool over nodes: Y2[g] += h[n] ----------------
__global__ void k_poolN(const int* __restrict__ batch, const unsigned char* __restrict__ hf8,
                        float* __restrict__ Y2) {
  int tid = threadIdx.x;
  int n0 = blockIdx.x * CHN;
  int n1 = (n0 + CHN < NN) ? n0 + CHN : NN;
  if (n0 >= n1) return;
  int slot = tid >> 5, q = tid & 31;
  float a[8] = {0, 0, 0, 0, 0, 0, 0, 0};
  int curg = -1;
  for (int n = n0 + slot; n < n1; n += 8) {
    int g = batch[n];
    if (g != curg) {
      if (curg >= 0) {
#pragma unroll
        for (int j = 0; j < 8; ++j) {
          unsafeAtomicAdd(&Y2[(size_t)curg * 256 + fp8dim(q * 8 + j)], a[j]);
          a[j] = 0.f;
        }
      }
      curg = g;
    }
    uint2 v = *(const uint2*)(hf8 + (size_t)n * 256 + q * 8);
    float o[8];
    unpack8_fp8(v, o);
#pragma unroll
    for (int j = 0; j < 8; ++j) a[j] += o[j];
  }
  if (curg >= 0) {
#pragma unroll
    for (int j = 0; j < 8; ++j)
      unsafeAtomicAdd(&Y2[(size_t)curg * 256 + fp8dim(q * 8 + j)], a[j]);
  }
}

// ---------------- final: out[g] = Y1[g]@W2l + Y2[g]@W2r + cnt_g*b2 (f32) ----------------
__global__ void k_out(const float* __restrict__ Y1, const float* __restrict__ Y2,
                      const float* __restrict__ W2l, const float* __restrict__ W2r,
                      const float* __restrict__ b2, const int* __restrict__ gstart,
                      float* __restrict__ out) {
  __shared__ float y1s[256], y2s[256];
  int g = blockIdx.x, t = threadIdx.x;
  y1s[t] = Y1[(size_t)g * 256 + t];
  y2s[t] = Y2[(size_t)g * 256 + t];
  __syncthreads();
  float cntf = (float)(gstart[g + 1] - gstart[g]);
  float s = b2[t] * cntf;
#pragma unroll 4
  for (int k = 0; k < 256; ++k) {
    s += y1s[k] * W2l[k * 256 + t];
    s += y2s[k] * W2r[k * 256 + t];
  }
  out[(size_t)g * 256 + t] = s;
}

extern "C" void kernel_launch(void* const* d_in, const int* in_sizes, int n_in,
                              void* d_out, int out_size, void* d_ws, size_t ws_size,
                              hipStream_t stream) {
  const float* x   = (const float*)d_in[0];
  const int*   ei  = (const int*)d_in[1];     // [2][NE] int32
  const int*   bat = (const int*)d_in[2];     // [NN] int32 (sorted)
  const float* W1l = (const float*)d_in[3];
  const float* b1  = (const float*)d_in[4];
  const float* W1r = (const float*)d_in[5];
  const float* W2l = (const float*)d_in[6];
  const float* b2  = (const float*)d_in[7];
  const float* W2r = (const float*)d_in[8];
  const int* src = ei;
  const int* dst = ei + NE;

  char* ws = (char*)d_ws;
  size_t off = 0;
  int* cnt     = (int*)(ws + off); off += ((size_t)NN * 4 + 255) & ~(size_t)255;
  int* rowptr  = (int*)(ws + off); off += ((size_t)(NN + 1) * 4 + 255) & ~(size_t)255;
  int* part    = (int*)(ws + off); off += 512 * 4;
  int* fill    = (int*)(ws + off); off += ((size_t)NN * 4 + 255) & ~(size_t)255;
  int* gstart  = (int*)(ws + off); off += ((size_t)(NG + 1) * 4 + 255) & ~(size_t)255;
  int* col     = (int*)(ws + off); off += (size_t)NE * 4;
  int* dstE    = (int*)(ws + off); off += (size_t)NE * 4;
  bf16_t* Bp1  = (bf16_t*)(ws + off); off += (size_t)256 * 256 * 2;
  float* Y1    = (float*)(ws + off); off += (size_t)NG * 256 * 4;
  float* Y2    = (float*)(ws + off); off += (size_t)NG * 256 * 4;
  bf16_t* xb   = (bf16_t*)(ws + off); off += (size_t)NN * DIN * 2;
  bf16_t* ag1  = (bf16_t*)(ws + off); off += (size_t)NN * DIN * 2;
  unsigned char* hf8 = (unsigned char*)(ws + off); off += (size_t)NN * DH;

  hipMemsetAsync(cnt, 0, (size_t)NN * 4, stream);
  hipMemsetAsync(fill, 0, (size_t)NN * 4, stream);
  hipMemsetAsync(Y1, 0, (size_t)NG * 256 * 4 * 2, stream);   // Y1,Y2 contiguous
  k_xcast<<<NN * DIN / 8 / 256, 256, 0, stream>>>(x, xb);
  k_pack1<<<32, 256, 0, stream>>>(W1l, W1r, Bp1);
  k_gstart<<<NB1, 256, 0, stream>>>(bat, gstart);
  k_count<<<(NE + 255) / 256, 256, 0, stream>>>(dst, cnt);
  k_scan1<<<NB1, 256, 0, stream>>>(cnt, rowptr, part);
  k_scan2<<<1, 512, 0, stream>>>(part);
  k_scan3<<<NB1, 256, 0, stream>>>(rowptr, part);
  k_bucket<<<(NE + 255) / 256, 256, 0, stream>>>(src, dst, rowptr, fill, col, dstE);
  k_agg1<<<(NN * 16 + 255) / 256, 256, 0, stream>>>(rowptr, col, xb, ag1);
  k_gemm1<<<(NN + 63) / 64, 256, 0, stream>>>(xb, ag1, b1, Bp1, hf8);
  k_poolE<<<EB, 256, 0, stream>>>(col, dstE, cnt, bat, hf8, Y1);
  k_poolN<<<NBL, 256, 0, stream>>>(bat, hf8, Y2);
  k_out<<<NG, 256, 0, stream>>>(Y1, Y2, W2l, W2r, b2, gstart, (float*)d_out);
}

// Round 5
// 284.708 us; speedup vs baseline: 20.2565x; 1.0447x over previous
//
#include <hip/hip_runtime.h>

#define NN 100000   // nodes
#define NE 640000   // edges
#define DIN 128
#define DH 256
#define DOUT 256
#define NG 256      // graphs
#define NB1 ((NN + 255) / 256)   // 391 blocks for scan

#define EB 2048                      // edge-pool blocks
#define CHE ((NE + EB - 1) / EB)     // 313 edges/block
#define NBL 1024                     // node-pool blocks
#define CHN ((NN + NBL - 1) / NBL)   // 98 nodes/block

typedef __bf16 bf16_t;
typedef __bf16 bf16x8 __attribute__((ext_vector_type(8)));
typedef float f32x4 __attribute__((ext_vector_type(4)));
typedef float f32v2 __attribute__((ext_vector_type(2)));

__device__ __forceinline__ float bf2f(unsigned u) {
  union { unsigned i; float f; } c; c.i = u << 16; return c.f;
}

// ---------------- fp8 e4m3 pack/unpack (HW path; consistent-roundtrip) ----------------
#if __has_builtin(__builtin_amdgcn_cvt_pk_fp8_f32) && __has_builtin(__builtin_amdgcn_cvt_pk_f32_fp8)
#define USE_HW_FP8 1
#else
#define USE_HW_FP8 0
#endif

#if !USE_HW_FP8
__device__ __forceinline__ unsigned f32_to_fp8_1(float f) {  // signed e4m3fn
  unsigned sg = (__float_as_uint(f) >> 31) << 7;
  float af = fabsf(f);
  unsigned body;
  if (af < 0.015625f) {                      // subnormal region, step 2^-9
    body = (unsigned)(int)rintf(af * 512.0f);
  } else {
    unsigned bits = __float_as_uint(af);
    unsigned rb = bits + 0x7FFFFu + ((bits >> 20) & 1u);   // RNE to 3-bit mantissa
    unsigned e = rb >> 23;
    body = ((e - 120u) << 3) | ((rb >> 20) & 7u);
  }
  return (sg | body) & 0xffu;
}
__device__ __forceinline__ float fp8_to_f32_1(unsigned b) {
  unsigned s = b >> 7, e = (b >> 3) & 15u, m = b & 7u;
  float v = (e == 0) ? (float)m * 0.001953125f
                     : __uint_as_float(((e + 120u) << 23) | (m << 20));
  return s ? -v : v;
}
#endif

__device__ __forceinline__ unsigned pack4_fp8(float v0, float v1, float v2, float v3) {
#if USE_HW_FP8
  int u = __builtin_amdgcn_cvt_pk_fp8_f32(v0, v1, 0, false);
  u = __builtin_amdgcn_cvt_pk_fp8_f32(v2, v3, u, true);
  return (unsigned)u;
#else
  return f32_to_fp8_1(v0) | (f32_to_fp8_1(v1) << 8) |
         (f32_to_fp8_1(v2) << 16) | (f32_to_fp8_1(v3) << 24);
#endif
}

__device__ __forceinline__ void unpack8_fp8(uint2 v, float* o) {
#if USE_HW_FP8
  f32v2 a = __builtin_amdgcn_cvt_pk_f32_fp8((int)v.x, false);
  f32v2 b = __builtin_amdgcn_cvt_pk_f32_fp8((int)v.x, true);
  f32v2 c = __builtin_amdgcn_cvt_pk_f32_fp8((int)v.y, false);
  f32v2 d = __builtin_amdgcn_cvt_pk_f32_fp8((int)v.y, true);
  o[0] = a[0]; o[1] = a[1]; o[2] = b[0]; o[3] = b[1];
  o[4] = c[0]; o[5] = c[1]; o[6] = d[0]; o[7] = d[1];
#else
  o[0] = fp8_to_f32_1(v.x & 0xffu);         o[1] = fp8_to_f32_1((v.x >> 8) & 0xffu);
  o[2] = fp8_to_f32_1((v.x >> 16) & 0xffu); o[3] = fp8_to_f32_1(v.x >> 24);
  o[4] = fp8_to_f32_1(v.y & 0xffu);         o[5] = fp8_to_f32_1((v.y >> 8) & 0xffu);
  o[6] = fp8_to_f32_1((v.y >> 16) & 0xffu); o[7] = fp8_to_f32_1(v.y >> 24);
#endif
}

// hf8 row layout: byte p (0..255) holds dim c = (p&~63) | ((p&3)<<4) | ((p>>2)&15)
__device__ __forceinline__ int fp8dim(int p) {
  return (p & ~63) | ((p & 3) << 4) | ((p >> 2) & 15);
}

// ---------------- x -> bf16 + fp8 cast ----------------
__global__ void k_xcast(const float* __restrict__ x, bf16_t* __restrict__ xb,
                        unsigned char* __restrict__ xf8) {
  size_t i = ((size_t)blockIdx.x * 256 + threadIdx.x) * 8;
  if (i >= (size_t)NN * DIN) return;
  float4 a = *(const float4*)(x + i), b = *(const float4*)(x + i + 4);
  bf16x8 o;
  o[0] = (bf16_t)a.x; o[1] = (bf16_t)a.y; o[2] = (bf16_t)a.z; o[3] = (bf16_t)a.w;
  o[4] = (bf16_t)b.x; o[5] = (bf16_t)b.y; o[6] = (bf16_t)b.z; o[7] = (bf16_t)b.w;
  *(bf16x8*)(xb + i) = o;
  uint2 p;
  p.x = pack4_fp8(a.x, a.y, a.z, a.w);
  p.y = pack4_fp8(b.x, b.y, b.z, b.w);
  *(uint2*)(xf8 + i) = p;
}

// ---------------- degree count ----------------
__global__ void k_count(const int* __restrict__ dst, int* __restrict__ cnt) {
  int e = blockIdx.x * 256 + threadIdx.x;
  if (e < NE) atomicAdd(&cnt[dst[e]], 1);
}

// ---------------- prefix scan (3 kernels): rowptr = exclusive_scan(cnt) ----------------
__global__ void k_scan1(const int* __restrict__ cnt, int* __restrict__ rowptr,
                        int* __restrict__ part) {
  __shared__ int s[256];
  int t = threadIdx.x, i = blockIdx.x * 256 + t;
  int v = (i < NN) ? cnt[i] : 0;
  s[t] = v; __syncthreads();
#pragma unroll
  for (int off = 1; off < 256; off <<= 1) {
    int u = (t >= off) ? s[t - off] : 0;
    __syncthreads();
    s[t] += u;
    __syncthreads();
  }
  if (i < NN) rowptr[i] = s[t] - v;
  if (t == 255) part[blockIdx.x] = s[255];
}

__global__ void k_scan2(int* __restrict__ part) {
  __shared__ int s[512];
  int t = threadIdx.x;
  int v = (t < NB1) ? part[t] : 0;
  s[t] = v; __syncthreads();
#pragma unroll
  for (int off = 1; off < 512; off <<= 1) {
    int u = (t >= off) ? s[t - off] : 0;
    __syncthreads();
    s[t] += u;
    __syncthreads();
  }
  if (t < NB1) part[t] = s[t] - v;
}

__global__ void k_scan3(int* __restrict__ rowptr, const int* __restrict__ part) {
  int i = blockIdx.x * 256 + threadIdx.x;
  if (i < NN) rowptr[i] += part[i >> 8];
  if (i == 0) rowptr[NN] = NE;
}

// ---------------- graph start index ----------------
__global__ void k_gstart(const int* __restrict__ batch, int* __restrict__ gstart) {
  int n = blockIdx.x * 256 + threadIdx.x;
  if (n >= NN) return;
  int b = batch[n];
  int prev = (n == 0) ? -1 : batch[n - 1];
  for (int g = prev + 1; g <= b; ++g) gstart[g] = n;
  if (n == NN - 1) {
    for (int g = b + 1; g <= NG; ++g) gstart[g] = NN;
  }
}

// ---------------- bucket edges by dst ----------------
__global__ void k_bucket(const int* __restrict__ src, const int* __restrict__ dst,
                         const int* __restrict__ rowptr, int* __restrict__ fill,
                         int* __restrict__ col, int* __restrict__ dstE) {
  int e = blockIdx.x * 256 + threadIdx.x;
  if (e < NE) {
    int d = dst[e];
    int p = rowptr[d] + atomicAdd(&fill[d], 1);
    col[p] = src[e];
    dstE[p] = d;
  }
}

// ---------------- gather-mean layer1 (fp8 x): 16 lanes/node, 8 dims each ----------------
__global__ void k_agg1(const int* __restrict__ rowptr, const int* __restrict__ col,
                       const unsigned char* __restrict__ xf8, bf16_t* __restrict__ ag1) {
  unsigned t = blockIdx.x * 256 + threadIdx.x;
  int n = t >> 4, q = t & 15;
  if (n >= NN) return;
  int e0 = rowptr[n], e1 = rowptr[n + 1];
  float a[8] = {0, 0, 0, 0, 0, 0, 0, 0};
  for (int e = e0; e < e1; ++e) {
    int s = col[e];
    uint2 v = ((const uint2*)(xf8 + (size_t)s * DIN))[q];
    float o[8];
    unpack8_fp8(v, o);
#pragma unroll
    for (int j = 0; j < 8; ++j) a[j] += o[j];
  }
  float r = (e1 > e0) ? __builtin_amdgcn_rcpf((float)(e1 - e0)) : 0.f;
  bf16x8 o;
#pragma unroll
  for (int j = 0; j < 8; ++j) o[j] = (bf16_t)(a[j] * r);
  ((bf16x8*)(ag1 + (size_t)n * DIN))[q] = o;
}

// ---------------- weight pack layer1 ----------------
__global__ void k_pack1(const float* __restrict__ Wl, const float* __restrict__ Wr,
                        bf16_t* __restrict__ Bp) {
  int t = blockIdx.x * 256 + threadIdx.x;   // 8 kc * 16 nt * 64 lanes = 8192
  if (t >= 8192) return;
  int lane = t & 63, nt = (t >> 6) & 15, kc = t >> 10;
  int n = nt * 16 + (lane & 15);
  int k0 = kc * 32 + (lane >> 4) * 8;
  bf16_t* o = Bp + ((size_t)(kc * 16 + nt) * 64 + lane) * 8;
  for (int j = 0; j < 8; ++j) {
    int k = k0 + j;
    float v = (k < 128) ? Wl[k * 256 + n] : Wr[(k - 128) * 256 + n];
    o[j] = (bf16_t)v;
  }
}

// ---------------- GEMM1: hf8 = fp8(relu([mean|x] @ [W1l;W1r] + b1)), K=256 ----------------
__launch_bounds__(256, 4)
__global__ void k_gemm1(const bf16_t* __restrict__ xb, const bf16_t* __restrict__ ag1,
                        const float* __restrict__ b1,
                        const bf16_t* __restrict__ Bp, unsigned char* __restrict__ hf8) {
  __shared__ unsigned char smem[64 * 512];   // A tile 64 x 256 bf16, XOR-swizzled
  int n0 = blockIdx.x * 64;
  int tid = threadIdx.x;
  {
    int row = tid >> 2, part = tid & 3;
    int node = n0 + row;
    unsigned sw = (row & 7) << 4;
    const uint4* ap = (const uint4*)(ag1 + (size_t)node * DIN);   // 16 uint4 mean
    const uint4* xp = (const uint4*)(xb + (size_t)node * DIN);    // 16 uint4 x
#pragma unroll
    for (int i = 0; i < 4; ++i) {
      int mi = i * 4 + part;                 // 0..15
      uint4 va = {0u, 0u, 0u, 0u}, vx = {0u, 0u, 0u, 0u};
      if (node < NN) { va = ap[mi]; vx = xp[mi]; }
      *(uint4*)(smem + row * 512 + (((unsigned)(mi * 16)) ^ sw)) = va;
      *(uint4*)(smem + row * 512 + ((unsigned)(256 + mi * 16) ^ sw)) = vx;
    }
  }
  __syncthreads();
  int wave = tid >> 6, lane = tid & 63, lhi = lane >> 4, llo = lane & 15;
  f32x4 acc[4][4] = {};
  const bf16x8* bptr = (const bf16x8*)Bp;
#pragma unroll
  for (int kc = 0; kc < 8; ++kc) {
    bf16x8 a[4], b[4];
#pragma unroll
    for (int mi = 0; mi < 4; ++mi) {
      int row = mi * 16 + llo;
      unsigned cb = ((unsigned)((kc * 32 + lhi * 8) * 2)) ^ ((row & 7) << 4);
      a[mi] = *(const bf16x8*)(smem + row * 512 + cb);
    }
#pragma unroll
    for (int ni = 0; ni < 4; ++ni)
      b[ni] = bptr[(kc * 16 + wave * 4 + ni) * 64 + lane];
#pragma unroll
    for (int mi = 0; mi < 4; ++mi)
#pragma unroll
      for (int ni = 0; ni < 4; ++ni)
        acc[mi][ni] = __builtin_amdgcn_mfma_f32_16x16x32_bf16(a[mi], b[ni], acc[mi][ni], 0, 0, 0);
  }
  // epilogue: relu(acc + b1) -> fp8, packed 4/thread per row (cols llo+16*ni), coalesced
  float bias[4];
#pragma unroll
  for (int ni = 0; ni < 4; ++ni) bias[ni] = b1[wave * 64 + ni * 16 + llo];
#pragma unroll
  for (int mi = 0; mi < 4; ++mi)
#pragma unroll
    for (int j = 0; j < 4; ++j) {
      int node = n0 + mi * 16 + lhi * 4 + j;
      if (node < NN) {
        float v0 = fmaxf(acc[mi][0][j] + bias[0], 0.f);
        float v1 = fmaxf(acc[mi][1][j] + bias[1], 0.f);
        float v2 = fmaxf(acc[mi][2][j] + bias[2], 0.f);
        float v3 = fmaxf(acc[mi][3][j] + bias[3], 0.f);
        unsigned u = pack4_fp8(v0, v1, v2, v3);
        *(unsigned*)(hf8 + (size_t)node * 256 + wave * 64 + llo * 4) = u;
      }
    }
}

// ---------------- pool over edges: Y1[g] += (1/c_dst) * h[src], LDS-buffered ----------------
__global__ void k_poolE(const int* __restrict__ col, const int* __restrict__ dstE,
                        const int* __restrict__ cnt, const int* __restrict__ batch,
                        const unsigned char* __restrict__ hf8, float* __restrict__ Y1) {
  __shared__ float gbuf[16][256];
  int tid = threadIdx.x;
  int c0 = blockIdx.x * CHE;
  int c1 = (c0 + CHE < NE) ? c0 + CHE : NE;
  if (c0 >= c1) return;                       // uniform across block
  int gmin = batch[dstE[c0]], gmax = batch[dstE[c1 - 1]];
  bool ldsok = (gmax - gmin) < 16;
  for (int i = tid; i < 16 * 256; i += 256) ((float*)gbuf)[i] = 0.f;
  __syncthreads();
  int slot = tid >> 5, q = tid & 31;
  float a[8] = {0, 0, 0, 0, 0, 0, 0, 0};
  int curg = -1;
#define FLUSH1()                                                         \
  do { if (curg >= 0) {                                                  \
    if (ldsok) { float* gp = &gbuf[curg - gmin][q * 8];                  \
      _Pragma("unroll")                                                  \
      for (int j = 0; j < 8; ++j) { atomicAdd(gp + j, a[j]); a[j] = 0.f; } \
    } else {                                                             \
      _Pragma("unroll")                                                  \
      for (int j = 0; j < 8; ++j) {                                      \
        unsafeAtomicAdd(&Y1[(size_t)curg * 256 + fp8dim(q * 8 + j)], a[j]); \
        a[j] = 0.f; } } } } while (0)
  for (int e = c0 + slot; e < c1; e += 8) {
    int d = dstE[e];
    int g = batch[d];
    if (g != curg) { FLUSH1(); curg = g; }
    float w = __builtin_amdgcn_rcpf((float)cnt[d]);
    int s = col[e];
    uint2 v = *(const uint2*)(hf8 + (size_t)s * 256 + q * 8);
    float o[8];
    unpack8_fp8(v, o);
#pragma unroll
    for (int j = 0; j < 8; ++j) a[j] += w * o[j];
  }
  FLUSH1();
#undef FLUSH1
  __syncthreads();
  if (ldsok) {
    int ng = gmax - gmin + 1;
    int dimt = fp8dim(tid);
    for (int gi = 0; gi < ng; ++gi)
      unsafeAtomicAdd(&Y1[(size_t)(gmin + gi) * 256 + dimt], gbuf[gi][tid]);
  }
}

// ---------------- pool over nodes: Y2[g] += h[n], LDS-buffered ----------------
__global__ void k_poolN(const int* __restrict__ batch, const unsigned char* __restrict__ hf8,
                        float* __restrict__ Y2) {
  __shared__ float gbuf[16][256];
  int tid = threadIdx.x;
  int n0 = blockIdx.x * CHN;
  int n1 = (n0 + CHN < NN) ? n0 + CHN : NN;
  if (n0 >= n1) return;
  int gmin = batch[n0], gmax = batch[n1 - 1];
  bool ldsok = (gmax - gmin) < 16;
  for (int i = tid; i < 16 * 256; i += 256) ((float*)gbuf)[i] = 0.f;
  __syncthreads();
  int slot = tid >> 5, q = tid & 31;
  float a[8] = {0, 0, 0, 0, 0, 0, 0, 0};
  int curg = -1;
#define FLUSH2()                                                         \
  do { if (curg >= 0) {                                                  \
    if (ldsok) { float* gp = &gbuf[curg - gmin][q * 8];                  \
      _Pragma("unroll")                                                  \
      for (int j = 0; j < 8; ++j) { atomicAdd(gp + j, a[j]); a[j] = 0.f; } \
    } else {                                                             \
      _Pragma("unroll")                                                  \
      for (int j = 0; j < 8; ++j) {                                      \
        unsafeAtomicAdd(&Y2[(size_t)curg * 256 + fp8dim(q * 8 + j)], a[j]); \
        a[j] = 0.f; } } } } while (0)
  for (int n = n0 + slot; n < n1; n += 8) {
    int g = batch[n];
    if (g != curg) { FLUSH2(); curg = g; }
    uint2 v = *(const uint2*)(hf8 + (size_t)n * 256 + q * 8);
    float o[8];
    unpack8_fp8(v, o);
#pragma unroll
    for (int j = 0; j < 8; ++j) a[j] += o[j];
  }
  FLUSH2();
#undef FLUSH2
  __syncthreads();
  if (ldsok) {
    int ng = gmax - gmin + 1;
    int dimt = fp8dim(tid);
    for (int gi = 0; gi < ng; ++gi)
      unsafeAtomicAdd(&Y2[(size_t)(gmin + gi) * 256 + dimt], gbuf[gi][tid]);
  }
}

// ---------------- final: out[g] = Y1[g]@W2l + Y2[g]@W2r + cnt_g*b2 (f32) ----------------
__global__ void k_out(const float* __restrict__ Y1, const float* __restrict__ Y2,
                      const float* __restrict__ W2l, const float* __restrict__ W2r,
                      const float* __restrict__ b2, const int* __restrict__ gstart,
                      float* __restrict__ out) {
  __shared__ float y1s[256], y2s[256];
  int g = blockIdx.x, t = threadIdx.x;
  y1s[t] = Y1[(size_t)g * 256 + t];
  y2s[t] = Y2[(size_t)g * 256 + t];
  __syncthreads();
  float cntf = (float)(gstart[g + 1] - gstart[g]);
  float s = b2[t] * cntf;
#pragma unroll 4
  for (int k = 0; k < 256; ++k) {
    s += y1s[k] * W2l[k * 256 + t];
    s += y2s[k] * W2r[k * 256 + t];
  }
  out[(size_t)g * 256 + t] = s;
}

extern "C" void kernel_launch(void* const* d_in, const int* in_sizes, int n_in,
                              void* d_out, int out_size, void* d_ws, size_t ws_size,
                              hipStream_t stream) {
  const float* x   = (const float*)d_in[0];
  const int*   ei  = (const int*)d_in[1];     // [2][NE] int32
  const int*   bat = (const int*)d_in[2];     // [NN] int32 (sorted)
  const float* W1l = (const float*)d_in[3];
  const float* b1  = (const float*)d_in[4];
  const float* W1r = (const float*)d_in[5];
  const float* W2l = (const float*)d_in[6];
  const float* b2  = (const float*)d_in[7];
  const float* W2r = (const float*)d_in[8];
  const int* src = ei;
  const int* dst = ei + NE;

  char* ws = (char*)d_ws;
  size_t off = 0;
  int* cnt     = (int*)(ws + off); off += ((size_t)NN * 4 + 255) & ~(size_t)255;
  int* rowptr  = (int*)(ws + off); off += ((size_t)(NN + 1) * 4 + 255) & ~(size_t)255;
  int* part    = (int*)(ws + off); off += 512 * 4;
  int* fill    = (int*)(ws + off); off += ((size_t)NN * 4 + 255) & ~(size_t)255;
  int* gstart  = (int*)(ws + off); off += ((size_t)(NG + 1) * 4 + 255) & ~(size_t)255;
  int* col     = (int*)(ws + off); off += (size_t)NE * 4;
  int* dstE    = (int*)(ws + off); off += (size_t)NE * 4;
  bf16_t* Bp1  = (bf16_t*)(ws + off); off += (size_t)256 * 256 * 2;
  float* Y1    = (float*)(ws + off); off += (size_t)NG * 256 * 4;
  float* Y2    = (float*)(ws + off); off += (size_t)NG * 256 * 4;
  bf16_t* xb   = (bf16_t*)(ws + off); off += (size_t)NN * DIN * 2;
  unsigned char* xf8 = (unsigned char*)(ws + off); off += (size_t)NN * DIN;
  bf16_t* ag1  = (bf16_t*)(ws + off); off += (size_t)NN * DIN * 2;
  unsigned char* hf8 = (unsigned char*)(ws + off); off += (size_t)NN * DH;

  hipMemsetAsync(cnt, 0, (size_t)NN * 4, stream);
  hipMemsetAsync(fill, 0, (size_t)NN * 4, stream);
  hipMemsetAsync(Y1, 0, (size_t)NG * 256 * 4 * 2, stream);   // Y1,Y2 contiguous
  k_xcast<<<NN * DIN / 8 / 256, 256, 0, stream>>>(x, xb, xf8);
  k_pack1<<<32, 256, 0, stream>>>(W1l, W1r, Bp1);
  k_gstart<<<NB1, 256, 0, stream>>>(bat, gstart);
  k_count<<<(NE + 255) / 256, 256, 0, stream>>>(dst, cnt);
  k_scan1<<<NB1, 256, 0, stream>>>(cnt, rowptr, part);
  k_scan2<<<1, 512, 0, stream>>>(part);
  k_scan3<<<NB1, 256, 0, stream>>>(rowptr, part);
  k_bucket<<<(NE + 255) / 256, 256, 0, stream>>>(src, dst, rowptr, fill, col, dstE);
  k_agg1<<<(NN * 16 + 255) / 256, 256, 0, stream>>>(rowptr, col, xf8, ag1);
  k_gemm1<<<(NN + 63) / 64, 256, 0, stream>>>(xb, ag1, b1, Bp1, hf8);
  k_poolE<<<EB, 256, 0, stream>>>(col, dstE, cnt, bat, hf8, Y1);
  k_poolN<<<NBL, 256, 0, stream>>>(bat, hf8, Y2);
  k_out<<<NG, 256, 0, stream>>>(Y1, Y2, W2l, W2r, b2, gstart, (float*)d_out);
}

// Round 6
// 273.694 us; speedup vs baseline: 21.0717x; 1.0402x over previous
//
#include <hip/hip_runtime.h>

#define NN 100000   // nodes
#define NE 640000   // edges
#define DIN 128
#define DH 256
#define DOUT 256
#define NG 256      // graphs
#define NB1 ((NN + 255) / 256)   // 391 blocks for scan

#define PB 2048                      // fused-pool blocks
#define PCH ((NN + PB - 1) / PB)     // 49 nodes/block
#define GSP 16                       // graphs per LDS slab

typedef __bf16 bf16_t;
typedef __bf16 bf16x8 __attribute__((ext_vector_type(8)));
typedef float f32x4 __attribute__((ext_vector_type(4)));
typedef float f32v2 __attribute__((ext_vector_type(2)));

__device__ __forceinline__ float bf2f(unsigned u) {
  union { unsigned i; float f; } c; c.i = u << 16; return c.f;
}

// ---------------- fp8 e4m3 pack/unpack (HW path; consistent-roundtrip) ----------------
#if __has_builtin(__builtin_amdgcn_cvt_pk_fp8_f32) && __has_builtin(__builtin_amdgcn_cvt_pk_f32_fp8)
#define USE_HW_FP8 1
#else
#define USE_HW_FP8 0
#endif

#if !USE_HW_FP8
__device__ __forceinline__ unsigned f32_to_fp8_1(float f) {  // signed e4m3fn
  unsigned sg = (__float_as_uint(f) >> 31) << 7;
  float af = fabsf(f);
  unsigned body;
  if (af < 0.015625f) {                      // subnormal region, step 2^-9
    body = (unsigned)(int)rintf(af * 512.0f);
  } else {
    unsigned bits = __float_as_uint(af);
    unsigned rb = bits + 0x7FFFFu + ((bits >> 20) & 1u);   // RNE to 3-bit mantissa
    unsigned e = rb >> 23;
    body = ((e - 120u) << 3) | ((rb >> 20) & 7u);
  }
  return (sg | body) & 0xffu;
}
__device__ __forceinline__ float fp8_to_f32_1(unsigned b) {
  unsigned s = b >> 7, e = (b >> 3) & 15u, m = b & 7u;
  float v = (e == 0) ? (float)m * 0.001953125f
                     : __uint_as_float(((e + 120u) << 23) | (m << 20));
  return s ? -v : v;
}
#endif

__device__ __forceinline__ unsigned pack4_fp8(float v0, float v1, float v2, float v3) {
#if USE_HW_FP8
  int u = __builtin_amdgcn_cvt_pk_fp8_f32(v0, v1, 0, false);
  u = __builtin_amdgcn_cvt_pk_fp8_f32(v2, v3, u, true);
  return (unsigned)u;
#else
  return f32_to_fp8_1(v0) | (f32_to_fp8_1(v1) << 8) |
         (f32_to_fp8_1(v2) << 16) | (f32_to_fp8_1(v3) << 24);
#endif
}

__device__ __forceinline__ void unpack8_fp8(uint2 v, float* o) {
#if USE_HW_FP8
  f32v2 a = __builtin_amdgcn_cvt_pk_f32_fp8((int)v.x, false);
  f32v2 b = __builtin_amdgcn_cvt_pk_f32_fp8((int)v.x, true);
  f32v2 c = __builtin_amdgcn_cvt_pk_f32_fp8((int)v.y, false);
  f32v2 d = __builtin_amdgcn_cvt_pk_f32_fp8((int)v.y, true);
  o[0] = a[0]; o[1] = a[1]; o[2] = b[0]; o[3] = b[1];
  o[4] = c[0]; o[5] = c[1]; o[6] = d[0]; o[7] = d[1];
#else
  o[0] = fp8_to_f32_1(v.x & 0xffu);         o[1] = fp8_to_f32_1((v.x >> 8) & 0xffu);
  o[2] = fp8_to_f32_1((v.x >> 16) & 0xffu); o[3] = fp8_to_f32_1(v.x >> 24);
  o[4] = fp8_to_f32_1(v.y & 0xffu);         o[5] = fp8_to_f32_1((v.y >> 8) & 0xffu);
  o[6] = fp8_to_f32_1((v.y >> 16) & 0xffu); o[7] = fp8_to_f32_1(v.y >> 24);
#endif
}

__device__ __forceinline__ void unpack16_fp8(uint4 v, float* o) {
  uint2 lo, hi;
  lo.x = v.x; lo.y = v.y; hi.x = v.z; hi.y = v.w;
  unpack8_fp8(lo, o);
  unpack8_fp8(hi, o + 8);
}

// hf8 row layout: byte p (0..255) holds dim c = (p&~63) | ((p&3)<<4) | ((p>>2)&15)
__device__ __forceinline__ int fp8dim(int p) {
  return (p & ~63) | ((p & 3) << 4) | ((p >> 2) & 15);
}

// ---------------- x -> bf16 + fp8 cast ----------------
__global__ void k_xcast(const float* __restrict__ x, bf16_t* __restrict__ xb,
                        unsigned char* __restrict__ xf8) {
  size_t i = ((size_t)blockIdx.x * 256 + threadIdx.x) * 8;
  if (i >= (size_t)NN * DIN) return;
  float4 a = *(const float4*)(x + i), b = *(const float4*)(x + i + 4);
  bf16x8 o;
  o[0] = (bf16_t)a.x; o[1] = (bf16_t)a.y; o[2] = (bf16_t)a.z; o[3] = (bf16_t)a.w;
  o[4] = (bf16_t)b.x; o[5] = (bf16_t)b.y; o[6] = (bf16_t)b.z; o[7] = (bf16_t)b.w;
  *(bf16x8*)(xb + i) = o;
  uint2 p;
  p.x = pack4_fp8(a.x, a.y, a.z, a.w);
  p.y = pack4_fp8(b.x, b.y, b.z, b.w);
  *(uint2*)(xf8 + i) = p;
}

// ---------------- degree count ----------------
__global__ void k_count(const int* __restrict__ dst, int* __restrict__ cnt) {
  int e = blockIdx.x * 256 + threadIdx.x;
  if (e < NE) atomicAdd(&cnt[dst[e]], 1);
}

// ---------------- prefix scan (3 kernels): rowptr = exclusive_scan(cnt) ----------------
__global__ void k_scan1(const int* __restrict__ cnt, int* __restrict__ rowptr,
                        int* __restrict__ part) {
  __shared__ int s[256];
  int t = threadIdx.x, i = blockIdx.x * 256 + t;
  int v = (i < NN) ? cnt[i] : 0;
  s[t] = v; __syncthreads();
#pragma unroll
  for (int off = 1; off < 256; off <<= 1) {
    int u = (t >= off) ? s[t - off] : 0;
    __syncthreads();
    s[t] += u;
    __syncthreads();
  }
  if (i < NN) rowptr[i] = s[t] - v;
  if (t == 255) part[blockIdx.x] = s[255];
}

__global__ void k_scan2(int* __restrict__ part) {
  __shared__ int s[512];
  int t = threadIdx.x;
  int v = (t < NB1) ? part[t] : 0;
  s[t] = v; __syncthreads();
#pragma unroll
  for (int off = 1; off < 512; off <<= 1) {
    int u = (t >= off) ? s[t - off] : 0;
    __syncthreads();
    s[t] += u;
    __syncthreads();
  }
  if (t < NB1) part[t] = s[t] - v;
}

__global__ void k_scan3(int* __restrict__ rowptr, const int* __restrict__ part) {
  int i = blockIdx.x * 256 + threadIdx.x;
  if (i < NN) rowptr[i] += part[i >> 8];
  if (i == 0) rowptr[NN] = NE;
}

// ---------------- graph start index ----------------
__global__ void k_gstart(const int* __restrict__ batch, int* __restrict__ gstart) {
  int n = blockIdx.x * 256 + threadIdx.x;
  if (n >= NN) return;
  int b = batch[n];
  int prev = (n == 0) ? -1 : batch[n - 1];
  for (int g = prev + 1; g <= b; ++g) gstart[g] = n;
  if (n == NN - 1) {
    for (int g = b + 1; g <= NG; ++g) gstart[g] = NN;
  }
}

// ---------------- bucket edges by dst (col only) ----------------
__global__ void k_bucket(const int* __restrict__ src, const int* __restrict__ dst,
                         const int* __restrict__ rowptr, int* __restrict__ fill,
                         int* __restrict__ col) {
  int e = blockIdx.x * 256 + threadIdx.x;
  if (e < NE) {
    int d = dst[e];
    int p = rowptr[d] + atomicAdd(&fill[d], 1);
    col[p] = src[e];
  }
}

// ---------------- gather-mean layer1 (fp8 x): 16 lanes/node, unroll-2 ----------------
__global__ void k_agg1(const int* __restrict__ rowptr, const int* __restrict__ col,
                       const unsigned char* __restrict__ xf8, bf16_t* __restrict__ ag1) {
  unsigned t = blockIdx.x * 256 + threadIdx.x;
  int n = t >> 4, q = t & 15;
  if (n >= NN) return;
  int e0 = rowptr[n], e1 = rowptr[n + 1];
  float a[8] = {0, 0, 0, 0, 0, 0, 0, 0};
  int e = e0;
  for (; e + 1 < e1; e += 2) {
    int s0 = col[e], s1 = col[e + 1];
    uint2 v0 = ((const uint2*)(xf8 + (size_t)s0 * DIN))[q];
    uint2 v1 = ((const uint2*)(xf8 + (size_t)s1 * DIN))[q];
    float o0[8], o1[8];
    unpack8_fp8(v0, o0);
    unpack8_fp8(v1, o1);
#pragma unroll
    for (int j = 0; j < 8; ++j) a[j] += o0[j] + o1[j];
  }
  if (e < e1) {
    int s0 = col[e];
    uint2 v0 = ((const uint2*)(xf8 + (size_t)s0 * DIN))[q];
    float o0[8];
    unpack8_fp8(v0, o0);
#pragma unroll
    for (int j = 0; j < 8; ++j) a[j] += o0[j];
  }
  float r = (e1 > e0) ? __builtin_amdgcn_rcpf((float)(e1 - e0)) : 0.f;
  bf16x8 o;
#pragma unroll
  for (int j = 0; j < 8; ++j) o[j] = (bf16_t)(a[j] * r);
  ((bf16x8*)(ag1 + (size_t)n * DIN))[q] = o;
}

// ---------------- weight pack layer1 ----------------
__global__ void k_pack1(const float* __restrict__ Wl, const float* __restrict__ Wr,
                        bf16_t* __restrict__ Bp) {
  int t = blockIdx.x * 256 + threadIdx.x;   // 8 kc * 16 nt * 64 lanes = 8192
  if (t >= 8192) return;
  int lane = t & 63, nt = (t >> 6) & 15, kc = t >> 10;
  int n = nt * 16 + (lane & 15);
  int k0 = kc * 32 + (lane >> 4) * 8;
  bf16_t* o = Bp + ((size_t)(kc * 16 + nt) * 64 + lane) * 8;
  for (int j = 0; j < 8; ++j) {
    int k = k0 + j;
    float v = (k < 128) ? Wl[k * 256 + n] : Wr[(k - 128) * 256 + n];
    o[j] = (bf16_t)v;
  }
}

// ---------------- GEMM1: hf8 = fp8(relu([mean|x] @ [W1l;W1r] + b1)), K=256 ----------------
__launch_bounds__(256, 4)
__global__ void k_gemm1(const bf16_t* __restrict__ xb, const bf16_t* __restrict__ ag1,
                        const float* __restrict__ b1,
                        const bf16_t* __restrict__ Bp, unsigned char* __restrict__ hf8) {
  __shared__ unsigned char smem[64 * 512];   // A tile 64 x 256 bf16, XOR-swizzled
  int n0 = blockIdx.x * 64;
  int tid = threadIdx.x;
  {
    int row = tid >> 2, part = tid & 3;
    int node = n0 + row;
    unsigned sw = (row & 7) << 4;
    const uint4* ap = (const uint4*)(ag1 + (size_t)node * DIN);   // 16 uint4 mean
    const uint4* xp = (const uint4*)(xb + (size_t)node * DIN);    // 16 uint4 x
#pragma unroll
    for (int i = 0; i < 4; ++i) {
      int mi = i * 4 + part;                 // 0..15
      uint4 va = {0u, 0u, 0u, 0u}, vx = {0u, 0u, 0u, 0u};
      if (node < NN) { va = ap[mi]; vx = xp[mi]; }
      *(uint4*)(smem + row * 512 + (((unsigned)(mi * 16)) ^ sw)) = va;
      *(uint4*)(smem + row * 512 + ((unsigned)(256 + mi * 16) ^ sw)) = vx;
    }
  }
  __syncthreads();
  int wave = tid >> 6, lane = tid & 63, lhi = lane >> 4, llo = lane & 15;
  f32x4 acc[4][4] = {};
  const bf16x8* bptr = (const bf16x8*)Bp;
#pragma unroll
  for (int kc = 0; kc < 8; ++kc) {
    bf16x8 a[4], b[4];
#pragma unroll
    for (int mi = 0; mi < 4; ++mi) {
      int row = mi * 16 + llo;
      unsigned cb = ((unsigned)((kc * 32 + lhi * 8) * 2)) ^ ((row & 7) << 4);
      a[mi] = *(const bf16x8*)(smem + row * 512 + cb);
    }
#pragma unroll
    for (int ni = 0; ni < 4; ++ni)
      b[ni] = bptr[(kc * 16 + wave * 4 + ni) * 64 + lane];
#pragma unroll
    for (int mi = 0; mi < 4; ++mi)
#pragma unroll
      for (int ni = 0; ni < 4; ++ni)
        acc[mi][ni] = __builtin_amdgcn_mfma_f32_16x16x32_bf16(a[mi], b[ni], acc[mi][ni], 0, 0, 0);
  }
  // epilogue: relu(acc + b1) -> fp8, packed 4/thread per row (cols llo+16*ni), coalesced
  float bias[4];
#pragma unroll
  for (int ni = 0; ni < 4; ++ni) bias[ni] = b1[wave * 64 + ni * 16 + llo];
#pragma unroll
  for (int mi = 0; mi < 4; ++mi)
#pragma unroll
    for (int j = 0; j < 4; ++j) {
      int node = n0 + mi * 16 + lhi * 4 + j;
      if (node < NN) {
        float v0 = fmaxf(acc[mi][0][j] + bias[0], 0.f);
        float v1 = fmaxf(acc[mi][1][j] + bias[1], 0.f);
        float v2 = fmaxf(acc[mi][2][j] + bias[2], 0.f);
        float v3 = fmaxf(acc[mi][3][j] + bias[3], 0.f);
        unsigned u = pack4_fp8(v0, v1, v2, v3);
        *(unsigned*)(hf8 + (size_t)node * 256 + wave * 64 + llo * 4) = u;
      }
    }
}

// ---------------- fused pool, node-major: Y1[g] += mean2[n], Y2[g] += h[n] ----------------
// 16 groups/block x 16 lanes; each group owns a CONTIGUOUS node sub-range so the
// graph id is monotone -> register accumulation, LDS slab flush on graph change.
__global__ void k_poolEN(const int* __restrict__ rowptr, const int* __restrict__ col,
                         const int* __restrict__ batch, const unsigned char* __restrict__ hf8,
                         float* __restrict__ Y1, float* __restrict__ Y2) {
  __shared__ float g1[GSP][256];
  __shared__ float g2[GSP][256];
  int tid = threadIdx.x;
  int n0 = blockIdx.x * PCH;
  int n1 = (n0 + PCH < NN) ? n0 + PCH : NN;
  if (n0 >= n1) return;
  int gmin = batch[n0], gmax = batch[n1 - 1];
  bool ldsok = (gmax - gmin) < GSP;
  for (int i = tid; i < GSP * 256; i += 256) { (&g1[0][0])[i] = 0.f; (&g2[0][0])[i] = 0.f; }
  __syncthreads();
  int grp = tid >> 4, q = tid & 15;
  const int per = (PCH + 15) >> 4;          // nodes per group (ceil)
  int a0 = n0 + grp * per;
  int a1 = a0 + per; if (a1 > n1) a1 = n1;
  float acc1[16], acc2[16];
#pragma unroll
  for (int j = 0; j < 16; ++j) { acc1[j] = 0.f; acc2[j] = 0.f; }
  int curg = -1;
#define PFLUSH()                                                          \
  do { if (curg >= 0) {                                                   \
    if (ldsok) { int gi = curg - gmin;                                    \
      _Pragma("unroll")                                                   \
      for (int j = 0; j < 16; ++j) {                                      \
        int dm = fp8dim(q * 16 + j);                                      \
        atomicAdd(&g1[gi][dm], acc1[j]); atomicAdd(&g2[gi][dm], acc2[j]); \
        acc1[j] = 0.f; acc2[j] = 0.f; }                                   \
    } else {                                                              \
      _Pragma("unroll")                                                   \
      for (int j = 0; j < 16; ++j) {                                      \
        int dm = fp8dim(q * 16 + j);                                      \
        unsafeAtomicAdd(&Y1[(size_t)curg * 256 + dm], acc1[j]);           \
        unsafeAtomicAdd(&Y2[(size_t)curg * 256 + dm], acc2[j]);           \
        acc1[j] = 0.f; acc2[j] = 0.f; } } } } while (0)
  for (int n = a0; n < a1; ++n) {
    int g = batch[n];
    if (g != curg) { PFLUSH(); curg = g; }
    uint4 hv = *(const uint4*)(hf8 + (size_t)n * 256 + q * 16);   // own row (sequential)
    int e0 = rowptr[n], e1 = rowptr[n + 1];
    float na[16];
#pragma unroll
    for (int j = 0; j < 16; ++j) na[j] = 0.f;
    int e = e0;
    for (; e + 1 < e1; e += 2) {                                  // neighbor gather, 2 in flight
      int s0 = col[e], s1 = col[e + 1];
      uint4 v0 = *(const uint4*)(hf8 + (size_t)s0 * 256 + q * 16);
      uint4 v1 = *(const uint4*)(hf8 + (size_t)s1 * 256 + q * 16);
      float o0[16], o1[16];
      unpack16_fp8(v0, o0);
      unpack16_fp8(v1, o1);
#pragma unroll
      for (int j = 0; j < 16; ++j) na[j] += o0[j] + o1[j];
    }
    if (e < e1) {
      int s0 = col[e];
      uint4 v0 = *(const uint4*)(hf8 + (size_t)s0 * 256 + q * 16);
      float o0[16];
      unpack16_fp8(v0, o0);
#pragma unroll
      for (int j = 0; j < 16; ++j) na[j] += o0[j];
    }
    float rdeg = (e1 > e0) ? __builtin_amdgcn_rcpf((float)(e1 - e0)) : 0.f;
    float ho[16];
    unpack16_fp8(hv, ho);
#pragma unroll
    for (int j = 0; j < 16; ++j) { acc1[j] += rdeg * na[j]; acc2[j] += ho[j]; }
  }
  PFLUSH();
#undef PFLUSH
  __syncthreads();
  if (ldsok) {
    int ng = gmax - gmin + 1;
    for (int gi = 0; gi < ng; ++gi) {
      unsafeAtomicAdd(&Y1[(size_t)(gmin + gi) * 256 + tid], g1[gi][tid]);
      unsafeAtomicAdd(&Y2[(size_t)(gmin + gi) * 256 + tid], g2[gi][tid]);
    }
  }
}

// ---------------- final: out[g] = Y1[g]@W2l + Y2[g]@W2r + cnt_g*b2 (f32) ----------------
__global__ void k_out(const float* __restrict__ Y1, const float* __restrict__ Y2,
                      const float* __restrict__ W2l, const float* __restrict__ W2r,
                      const float* __restrict__ b2, const int* __restrict__ gstart,
                      float* __restrict__ out) {
  __shared__ float y1s[256], y2s[256];
  int g = blockIdx.x, t = threadIdx.x;
  y1s[t] = Y1[(size_t)g * 256 + t];
  y2s[t] = Y2[(size_t)g * 256 + t];
  __syncthreads();
  float cntf = (float)(gstart[g + 1] - gstart[g]);
  float s = b2[t] * cntf;
#pragma unroll 4
  for (int k = 0; k < 256; ++k) {
    s += y1s[k] * W2l[k * 256 + t];
    s += y2s[k] * W2r[k * 256 + t];
  }
  out[(size_t)g * 256 + t] = s;
}

extern "C" void kernel_launch(void* const* d_in, const int* in_sizes, int n_in,
                              void* d_out, int out_size, void* d_ws, size_t ws_size,
                              hipStream_t stream) {
  const float* x   = (const float*)d_in[0];
  const int*   ei  = (const int*)d_in[1];     // [2][NE] int32
  const int*   bat = (const int*)d_in[2];     // [NN] int32 (sorted)
  const float* W1l = (const float*)d_in[3];
  const float* b1  = (const float*)d_in[4];
  const float* W1r = (const float*)d_in[5];
  const float* W2l = (const float*)d_in[6];
  const float* b2  = (const float*)d_in[7];
  const float* W2r = (const float*)d_in[8];
  const int* src = ei;
  const int* dst = ei + NE;

  char* ws = (char*)d_ws;
  size_t off = 0;
  int* cnt     = (int*)(ws + off); off += ((size_t)NN * 4 + 255) & ~(size_t)255;
  int* rowptr  = (int*)(ws + off); off += ((size_t)(NN + 1) * 4 + 255) & ~(size_t)255;
  int* part    = (int*)(ws + off); off += 512 * 4;
  int* fill    = (int*)(ws + off); off += ((size_t)NN * 4 + 255) & ~(size_t)255;
  int* gstart  = (int*)(ws + off); off += ((size_t)(NG + 1) * 4 + 255) & ~(size_t)255;
  int* col     = (int*)(ws + off); off += (size_t)NE * 4;
  bf16_t* Bp1  = (bf16_t*)(ws + off); off += (size_t)256 * 256 * 2;
  float* Y1    = (float*)(ws + off); off += (size_t)NG * 256 * 4;
  float* Y2    = (float*)(ws + off); off += (size_t)NG * 256 * 4;
  bf16_t* xb   = (bf16_t*)(ws + off); off += (size_t)NN * DIN * 2;
  unsigned char* xf8 = (unsigned char*)(ws + off); off += (size_t)NN * DIN;
  bf16_t* ag1  = (bf16_t*)(ws + off); off += (size_t)NN * DIN * 2;
  unsigned char* hf8 = (unsigned char*)(ws + off); off += (size_t)NN * DH;

  hipMemsetAsync(cnt, 0, (size_t)NN * 4, stream);
  hipMemsetAsync(fill, 0, (size_t)NN * 4, stream);
  hipMemsetAsync(Y1, 0, (size_t)NG * 256 * 4 * 2, stream);   // Y1,Y2 contiguous
  k_xcast<<<NN * DIN / 8 / 256, 256, 0, stream>>>(x, xb, xf8);
  k_pack1<<<32, 256, 0, stream>>>(W1l, W1r, Bp1);
  k_gstart<<<NB1, 256, 0, stream>>>(bat, gstart);
  k_count<<<(NE + 255) / 256, 256, 0, stream>>>(dst, cnt);
  k_scan1<<<NB1, 256, 0, stream>>>(cnt, rowptr, part);
  k_scan2<<<1, 512, 0, stream>>>(part);
  k_scan3<<<NB1, 256, 0, stream>>>(rowptr, part);
  k_bucket<<<(NE + 255) / 256, 256, 0, stream>>>(src, dst, rowptr, fill, col);
  k_agg1<<<(NN * 16 + 255) / 256, 256, 0, stream>>>(rowptr, col, xf8, ag1);
  k_gemm1<<<(NN + 63) / 64, 256, 0, stream>>>(xb, ag1, b1, Bp1, hf8);
  k_poolEN<<<PB, 256, 0, stream>>>(rowptr, col, bat, hf8, Y1, Y2);
  k_out<<<NG, 256, 0, stream>>>(Y1, Y2, W2l, W2r, b2, gstart, (float*)d_out);
}

// Round 7
// 232.867 us; speedup vs baseline: 24.7660x; 1.1753x over previous
//
#include <hip/hip_runtime.h>

#define NN 100000   // nodes
#define NE 640000   // edges
#define DIN 128
#define DH 256
#define DOUT 256
#define NG 256      // graphs
#define NB1 ((NN + 255) / 256)   // 391 blocks for scan

// edge pool geometry: wave per chunk
#define PECH 157                          // edges per wave
#define CPE (4 * PECH)                    // edges per block (628)
#define PEB ((NE + CPE - 1) / CPE)        // 1020 blocks
#define GSP 8                             // graphs per LDS slab

typedef __bf16 bf16_t;
typedef __bf16 bf16x8 __attribute__((ext_vector_type(8)));
typedef __bf16 bf16x2 __attribute__((ext_vector_type(2)));
typedef float f32x4 __attribute__((ext_vector_type(4)));
typedef float f32v2 __attribute__((ext_vector_type(2)));

// ---------------- fp8 e4m3 pack/unpack (HW path; consistent-roundtrip) ----------------
#if __has_builtin(__builtin_amdgcn_cvt_pk_fp8_f32) && __has_builtin(__builtin_amdgcn_cvt_pk_f32_fp8)
#define USE_HW_FP8 1
#else
#define USE_HW_FP8 0
#endif

#if !USE_HW_FP8
__device__ __forceinline__ unsigned f32_to_fp8_1(float f) {  // signed e4m3fn
  unsigned sg = (__float_as_uint(f) >> 31) << 7;
  float af = fabsf(f);
  unsigned body;
  if (af < 0.015625f) {
    body = (unsigned)(int)rintf(af * 512.0f);
  } else {
    unsigned bits = __float_as_uint(af);
    unsigned rb = bits + 0x7FFFFu + ((bits >> 20) & 1u);
    unsigned e = rb >> 23;
    body = ((e - 120u) << 3) | ((rb >> 20) & 7u);
  }
  return (sg | body) & 0xffu;
}
__device__ __forceinline__ float fp8_to_f32_1(unsigned b) {
  unsigned s = b >> 7, e = (b >> 3) & 15u, m = b & 7u;
  float v = (e == 0) ? (float)m * 0.001953125f
                     : __uint_as_float(((e + 120u) << 23) | (m << 20));
  return s ? -v : v;
}
#endif

__device__ __forceinline__ unsigned pack4_fp8(float v0, float v1, float v2, float v3) {
#if USE_HW_FP8
  int u = __builtin_amdgcn_cvt_pk_fp8_f32(v0, v1, 0, false);
  u = __builtin_amdgcn_cvt_pk_fp8_f32(v2, v3, u, true);
  return (unsigned)u;
#else
  return f32_to_fp8_1(v0) | (f32_to_fp8_1(v1) << 8) |
         (f32_to_fp8_1(v2) << 16) | (f32_to_fp8_1(v3) << 24);
#endif
}

__device__ __forceinline__ void unpack4_fp8(unsigned v, float* o) {
#if USE_HW_FP8
  f32v2 a = __builtin_amdgcn_cvt_pk_f32_fp8((int)v, false);
  f32v2 b = __builtin_amdgcn_cvt_pk_f32_fp8((int)v, true);
  o[0] = a[0]; o[1] = a[1]; o[2] = b[0]; o[3] = b[1];
#else
  o[0] = fp8_to_f32_1(v & 0xffu);         o[1] = fp8_to_f32_1((v >> 8) & 0xffu);
  o[2] = fp8_to_f32_1((v >> 16) & 0xffu); o[3] = fp8_to_f32_1(v >> 24);
#endif
}

__device__ __forceinline__ void unpack2_fp8(unsigned v, float* o) {  // low 2 bytes
#if USE_HW_FP8
  f32v2 a = __builtin_amdgcn_cvt_pk_f32_fp8((int)v, false);
  o[0] = a[0]; o[1] = a[1];
#else
  o[0] = fp8_to_f32_1(v & 0xffu); o[1] = fp8_to_f32_1((v >> 8) & 0xffu);
#endif
}

// ---------------- x -> bf16 + fp8 cast (both plain row-major) ----------------
__global__ void k_xcast(const float* __restrict__ x, bf16_t* __restrict__ xb,
                        unsigned char* __restrict__ xf8) {
  size_t i = ((size_t)blockIdx.x * 256 + threadIdx.x) * 8;
  if (i >= (size_t)NN * DIN) return;
  float4 a = *(const float4*)(x + i), b = *(const float4*)(x + i + 4);
  bf16x8 o;
  o[0] = (bf16_t)a.x; o[1] = (bf16_t)a.y; o[2] = (bf16_t)a.z; o[3] = (bf16_t)a.w;
  o[4] = (bf16_t)b.x; o[5] = (bf16_t)b.y; o[6] = (bf16_t)b.z; o[7] = (bf16_t)b.w;
  *(bf16x8*)(xb + i) = o;
  uint2 p;
  p.x = pack4_fp8(a.x, a.y, a.z, a.w);
  p.y = pack4_fp8(b.x, b.y, b.z, b.w);
  *(uint2*)(xf8 + i) = p;
}

// ---------------- degree count ----------------
__global__ void k_count(const int* __restrict__ dst, int* __restrict__ cnt) {
  int e = blockIdx.x * 256 + threadIdx.x;
  if (e < NE) atomicAdd(&cnt[dst[e]], 1);
}

// ---------------- prefix scan (3 kernels): rowptr = exclusive_scan(cnt) ----------------
__global__ void k_scan1(const int* __restrict__ cnt, int* __restrict__ rowptr,
                        int* __restrict__ part) {
  __shared__ int s[256];
  int t = threadIdx.x, i = blockIdx.x * 256 + t;
  int v = (i < NN) ? cnt[i] : 0;
  s[t] = v; __syncthreads();
#pragma unroll
  for (int off = 1; off < 256; off <<= 1) {
    int u = (t >= off) ? s[t - off] : 0;
    __syncthreads();
    s[t] += u;
    __syncthreads();
  }
  if (i < NN) rowptr[i] = s[t] - v;
  if (t == 255) part[blockIdx.x] = s[255];
}

__global__ void k_scan2(int* __restrict__ part) {
  __shared__ int s[512];
  int t = threadIdx.x;
  int v = (t < NB1) ? part[t] : 0;
  s[t] = v; __syncthreads();
#pragma unroll
  for (int off = 1; off < 512; off <<= 1) {
    int u = (t >= off) ? s[t - off] : 0;
    __syncthreads();
    s[t] += u;
    __syncthreads();
  }
  if (t < NB1) part[t] = s[t] - v;
}

__global__ void k_scan3(int* __restrict__ rowptr, const int* __restrict__ part) {
  int i = blockIdx.x * 256 + threadIdx.x;
  if (i < NN) rowptr[i] += part[i >> 8];
  if (i == 0) rowptr[NN] = NE;
}

// ---------------- graph start index + per-edge (graph,deg) metadata ----------------
__global__ void k_gstart2(const int* __restrict__ batch, const int* __restrict__ rowptr,
                          int* __restrict__ gstart, unsigned* __restrict__ wg) {
  int n = blockIdx.x * 256 + threadIdx.x;
  if (n >= NN) return;
  int b = batch[n];
  int prev = (n == 0) ? -1 : batch[n - 1];
  for (int g = prev + 1; g <= b; ++g) gstart[g] = n;
  if (n == NN - 1) {
    for (int g = b + 1; g <= NG; ++g) gstart[g] = NN;
  }
  int e0 = rowptr[n], e1 = rowptr[n + 1];
  unsigned val = ((unsigned)b << 16) | (unsigned)(e1 - e0);
  for (int e = e0; e < e1; ++e) wg[e] = val;
}

// ---------------- bucket edges by dst (col only) ----------------
__global__ void k_bucket(const int* __restrict__ src, const int* __restrict__ dst,
                         const int* __restrict__ rowptr, int* __restrict__ fill,
                         int* __restrict__ col) {
  int e = blockIdx.x * 256 + threadIdx.x;
  if (e < NE) {
    int d = dst[e];
    int p = rowptr[d] + atomicAdd(&fill[d], 1);
    col[p] = src[e];
  }
}

// ---------------- gather-mean layer1: one WAVE per node, 2B/lane, unroll-4 ----------------
__global__ void k_agg1(const int* __restrict__ rowptr, const int* __restrict__ col,
                       const unsigned char* __restrict__ xf8, bf16_t* __restrict__ ag1) {
  int w = (blockIdx.x * 256 + threadIdx.x) >> 6;
  int lane = threadIdx.x & 63;
  if (w >= NN) return;
  w = __builtin_amdgcn_readfirstlane(w);
  int e0 = rowptr[w], e1 = rowptr[w + 1];
  float a0 = 0.f, a1 = 0.f;
  int e = e0;
  for (; e + 4 <= e1; e += 4) {
    int s0 = col[e], s1 = col[e + 1], s2 = col[e + 2], s3 = col[e + 3];
    unsigned v0 = *(const unsigned short*)(xf8 + (size_t)s0 * DIN + lane * 2);
    unsigned v1 = *(const unsigned short*)(xf8 + (size_t)s1 * DIN + lane * 2);
    unsigned v2 = *(const unsigned short*)(xf8 + (size_t)s2 * DIN + lane * 2);
    unsigned v3 = *(const unsigned short*)(xf8 + (size_t)s3 * DIN + lane * 2);
    float o[2];
    unpack2_fp8(v0, o); a0 += o[0]; a1 += o[1];
    unpack2_fp8(v1, o); a0 += o[0]; a1 += o[1];
    unpack2_fp8(v2, o); a0 += o[0]; a1 += o[1];
    unpack2_fp8(v3, o); a0 += o[0]; a1 += o[1];
  }
  for (; e < e1; ++e) {
    int s0 = col[e];
    unsigned v0 = *(const unsigned short*)(xf8 + (size_t)s0 * DIN + lane * 2);
    float o[2];
    unpack2_fp8(v0, o); a0 += o[0]; a1 += o[1];
  }
  float r = (e1 > e0) ? __builtin_amdgcn_rcpf((float)(e1 - e0)) : 0.f;
  bf16x2 ov;
  ov[0] = (bf16_t)(a0 * r); ov[1] = (bf16_t)(a1 * r);
  ((bf16x2*)ag1)[(size_t)w * 64 + lane] = ov;
}

// ---------------- weight pack layer1 ----------------
__global__ void k_pack1(const float* __restrict__ Wl, const float* __restrict__ Wr,
                        bf16_t* __restrict__ Bp) {
  int t = blockIdx.x * 256 + threadIdx.x;   // 8 kc * 16 nt * 64 lanes = 8192
  if (t >= 8192) return;
  int lane = t & 63, nt = (t >> 6) & 15, kc = t >> 10;
  int n = nt * 16 + (lane & 15);
  int k0 = kc * 32 + (lane >> 4) * 8;
  bf16_t* o = Bp + ((size_t)(kc * 16 + nt) * 64 + lane) * 8;
  for (int j = 0; j < 8; ++j) {
    int k = k0 + j;
    float v = (k < 128) ? Wl[k * 256 + n] : Wr[(k - 128) * 256 + n];
    o[j] = (bf16_t)v;
  }
}

// ---------------- GEMM1: hf8 = fp8(relu([mean|x] @ [W1l;W1r] + b1)), K=256 ----------------
__launch_bounds__(256, 4)
__global__ void k_gemm1(const bf16_t* __restrict__ xb, const bf16_t* __restrict__ ag1,
                        const float* __restrict__ b1,
                        const bf16_t* __restrict__ Bp, unsigned char* __restrict__ hf8) {
  __shared__ unsigned char smem[64 * 512];   // A tile 64 x 256 bf16, XOR-swizzled
  int n0 = blockIdx.x * 64;
  int tid = threadIdx.x;
  {
    int row = tid >> 2, part = tid & 3;
    int node = n0 + row;
    unsigned sw = (row & 7) << 4;
    const uint4* ap = (const uint4*)(ag1 + (size_t)node * DIN);
    const uint4* xp = (const uint4*)(xb + (size_t)node * DIN);
#pragma unroll
    for (int i = 0; i < 4; ++i) {
      int mi = i * 4 + part;                 // 0..15
      uint4 va = {0u, 0u, 0u, 0u}, vx = {0u, 0u, 0u, 0u};
      if (node < NN) { va = ap[mi]; vx = xp[mi]; }
      *(uint4*)(smem + row * 512 + (((unsigned)(mi * 16)) ^ sw)) = va;
      *(uint4*)(smem + row * 512 + ((unsigned)(256 + mi * 16) ^ sw)) = vx;
    }
  }
  __syncthreads();
  int wave = tid >> 6, lane = tid & 63, lhi = lane >> 4, llo = lane & 15;
  f32x4 acc[4][4] = {};
  const bf16x8* bptr = (const bf16x8*)Bp;
#pragma unroll
  for (int kc = 0; kc < 8; ++kc) {
    bf16x8 a[4], b[4];
#pragma unroll
    for (int mi = 0; mi < 4; ++mi) {
      int row = mi * 16 + llo;
      unsigned cb = ((unsigned)((kc * 32 + lhi * 8) * 2)) ^ ((row & 7) << 4);
      a[mi] = *(const bf16x8*)(smem + row * 512 + cb);
    }
#pragma unroll
    for (int ni = 0; ni < 4; ++ni)
      b[ni] = bptr[(kc * 16 + wave * 4 + ni) * 64 + lane];
#pragma unroll
    for (int mi = 0; mi < 4; ++mi)
#pragma unroll
      for (int ni = 0; ni < 4; ++ni)
        acc[mi][ni] = __builtin_amdgcn_mfma_f32_16x16x32_bf16(a[mi], b[ni], acc[mi][ni], 0, 0, 0);
  }
  float bias[4];
#pragma unroll
  for (int ni = 0; ni < 4; ++ni) bias[ni] = b1[wave * 64 + ni * 16 + llo];
#pragma unroll
  for (int mi = 0; mi < 4; ++mi)
#pragma unroll
    for (int j = 0; j < 4; ++j) {
      int node = n0 + mi * 16 + lhi * 4 + j;
      if (node < NN) {
        float v0 = fmaxf(acc[mi][0][j] + bias[0], 0.f);
        float v1 = fmaxf(acc[mi][1][j] + bias[1], 0.f);
        float v2 = fmaxf(acc[mi][2][j] + bias[2], 0.f);
        float v3 = fmaxf(acc[mi][3][j] + bias[3], 0.f);
        unsigned u = pack4_fp8(v0, v1, v2, v3);
        *(unsigned*)(hf8 + (size_t)node * 256 + wave * 64 + llo * 4) = u;
      }
    }
}

// ---------------- edge pool: Y1[g] += (1/deg_dst) * h[src]; wave/chunk, unroll-8 ----------------
__global__ void k_poolE2(const int* __restrict__ col, const unsigned* __restrict__ wg,
                         const unsigned char* __restrict__ hf8, float* __restrict__ Y1) {
  __shared__ float gbuf[GSP][256];
  int tid = threadIdx.x;
  int c0 = blockIdx.x * CPE;
  int c1 = (c0 + CPE < NE) ? c0 + CPE : NE;
  if (c0 >= c1) return;
  int gmin = (int)(wg[c0] >> 16), gmax = (int)(wg[c1 - 1] >> 16);
  bool ldsok = (gmax - gmin) < GSP;
  for (int i = tid; i < GSP * 256; i += 256) (&gbuf[0][0])[i] = 0.f;
  __syncthreads();
  int wv = tid >> 6, lane = tid & 63;
  int e0 = __builtin_amdgcn_readfirstlane(c0 + wv * PECH);
  int e1 = e0 + PECH; if (e1 > c1) e1 = c1;
  int dmb = ((lane >> 4) << 6) | (lane & 15);
  float acc[4] = {0.f, 0.f, 0.f, 0.f};
  int curg = -1;
#define EFLUSH() do { if (curg >= 0) {                                        \
    if (ldsok) { float* gp = gbuf[curg - gmin];                               \
      atomicAdd(gp + (dmb | 0),  acc[0]); atomicAdd(gp + (dmb | 16), acc[1]); \
      atomicAdd(gp + (dmb | 32), acc[2]); atomicAdd(gp + (dmb | 48), acc[3]); \
    } else { float* yp = Y1 + (size_t)curg * 256;                             \
      unsafeAtomicAdd(yp + (dmb | 0),  acc[0]);                               \
      unsafeAtomicAdd(yp + (dmb | 16), acc[1]);                               \
      unsafeAtomicAdd(yp + (dmb | 32), acc[2]);                               \
      unsafeAtomicAdd(yp + (dmb | 48), acc[3]); }                             \
    acc[0] = acc[1] = acc[2] = acc[3] = 0.f; } } while (0)
  if (e0 < e1) {
    int e = e0;
    for (; e + 8 <= e1; e += 8) {
      int cv[8]; unsigned wvv[8]; unsigned hv[8];
#pragma unroll
      for (int i = 0; i < 8; ++i) { cv[i] = col[e + i]; wvv[i] = wg[e + i]; }
#pragma unroll
      for (int i = 0; i < 8; ++i)
        hv[i] = *(const unsigned*)(hf8 + (size_t)cv[i] * 256 + lane * 4);
#pragma unroll
      for (int i = 0; i < 8; ++i) {
        int g = (int)(wvv[i] >> 16);
        if (g != curg) { EFLUSH(); curg = g; }
        float w = __builtin_amdgcn_rcpf((float)(wvv[i] & 0xffffu));
        float o[4]; unpack4_fp8(hv[i], o);
        acc[0] += w * o[0]; acc[1] += w * o[1];
        acc[2] += w * o[2]; acc[3] += w * o[3];
      }
    }
    for (; e < e1; ++e) {
      int c = col[e]; unsigned wv2 = wg[e];
      unsigned hvv = *(const unsigned*)(hf8 + (size_t)c * 256 + lane * 4);
      int g = (int)(wv2 >> 16);
      if (g != curg) { EFLUSH(); curg = g; }
      float w = __builtin_amdgcn_rcpf((float)(wv2 & 0xffffu));
      float o[4]; unpack4_fp8(hvv, o);
      acc[0] += w * o[0]; acc[1] += w * o[1];
      acc[2] += w * o[2]; acc[3] += w * o[3];
    }
    EFLUSH();
  }
#undef EFLUSH
  __syncthreads();
  if (ldsok) {
    int ng = gmax - gmin + 1;
    for (int gi = 0; gi < ng; ++gi)
      unsafeAtomicAdd(&Y1[(size_t)(gmin + gi) * 256 + tid], gbuf[gi][tid]);
  }
}

// ---------------- final: out[g] = Y1[g]@W2l + (sum_{n in g} h[n])@W2r + cnt_g*b2 ----------------
__global__ void k_out(const float* __restrict__ Y1, const unsigned char* __restrict__ hf8,
                      const float* __restrict__ W2l, const float* __restrict__ W2r,
                      const float* __restrict__ b2, const int* __restrict__ gstart,
                      float* __restrict__ out) {
  __shared__ float y1s[256], y2s[256];
  int g = blockIdx.x, t = threadIdx.x;
  int n0 = gstart[g], n1 = gstart[g + 1];
  // phase 1: y2 = sum over graph's (contiguous) node rows, 4 rows in parallel
  int r = t >> 6, wq = t & 63;
  float a[4] = {0.f, 0.f, 0.f, 0.f};
  for (int n = n0 + r; n < n1; n += 4) {
    unsigned v = *(const unsigned*)(hf8 + (size_t)n * 256 + wq * 4);
    float o[4]; unpack4_fp8(v, o);
    a[0] += o[0]; a[1] += o[1]; a[2] += o[2]; a[3] += o[3];
  }
  y2s[t] = 0.f;
  y1s[t] = Y1[(size_t)g * 256 + t];
  __syncthreads();
#pragma unroll
  for (int j = 0; j < 4; ++j) {
    int dm = ((wq >> 4) << 6) | (j << 4) | (wq & 15);
    atomicAdd(&y2s[dm], a[j]);
  }
  __syncthreads();
  float cntf = (float)(n1 - n0);
  float s = b2[t] * cntf;
#pragma unroll 4
  for (int k = 0; k < 256; ++k) {
    s += y1s[k] * W2l[k * 256 + t];
    s += y2s[k] * W2r[k * 256 + t];
  }
  out[(size_t)g * 256 + t] = s;
}

extern "C" void kernel_launch(void* const* d_in, const int* in_sizes, int n_in,
                              void* d_out, int out_size, void* d_ws, size_t ws_size,
                              hipStream_t stream) {
  const float* x   = (const float*)d_in[0];
  const int*   ei  = (const int*)d_in[1];     // [2][NE] int32
  const int*   bat = (const int*)d_in[2];     // [NN] int32 (sorted)
  const float* W1l = (const float*)d_in[3];
  const float* b1  = (const float*)d_in[4];
  const float* W1r = (const float*)d_in[5];
  const float* W2l = (const float*)d_in[6];
  const float* b2  = (const float*)d_in[7];
  const float* W2r = (const float*)d_in[8];
  const int* src = ei;
  const int* dst = ei + NE;

  char* ws = (char*)d_ws;
  size_t off = 0;
  int* cnt     = (int*)(ws + off); off += ((size_t)NN * 4 + 255) & ~(size_t)255;
  int* rowptr  = (int*)(ws + off); off += ((size_t)(NN + 1) * 4 + 255) & ~(size_t)255;
  int* part    = (int*)(ws + off); off += 512 * 4;
  int* fill    = (int*)(ws + off); off += ((size_t)NN * 4 + 255) & ~(size_t)255;
  int* gstart  = (int*)(ws + off); off += ((size_t)(NG + 1) * 4 + 255) & ~(size_t)255;
  int* col     = (int*)(ws + off); off += (size_t)NE * 4;
  unsigned* wg = (unsigned*)(ws + off); off += (size_t)NE * 4;
  bf16_t* Bp1  = (bf16_t*)(ws + off); off += (size_t)256 * 256 * 2;
  float* Y1    = (float*)(ws + off); off += (size_t)NG * 256 * 4;
  bf16_t* xb   = (bf16_t*)(ws + off); off += (size_t)NN * DIN * 2;
  unsigned char* xf8 = (unsigned char*)(ws + off); off += (size_t)NN * DIN;
  bf16_t* ag1  = (bf16_t*)(ws + off); off += (size_t)NN * DIN * 2;
  unsigned char* hf8 = (unsigned char*)(ws + off); off += (size_t)NN * DH;

  hipMemsetAsync(cnt, 0, (size_t)NN * 4, stream);
  hipMemsetAsync(fill, 0, (size_t)NN * 4, stream);
  hipMemsetAsync(Y1, 0, (size_t)NG * 256 * 4, stream);
  k_xcast<<<NN * DIN / 8 / 256, 256, 0, stream>>>(x, xb, xf8);
  k_pack1<<<32, 256, 0, stream>>>(W1l, W1r, Bp1);
  k_count<<<(NE + 255) / 256, 256, 0, stream>>>(dst, cnt);
  k_scan1<<<NB1, 256, 0, stream>>>(cnt, rowptr, part);
  k_scan2<<<1, 512, 0, stream>>>(part);
  k_scan3<<<NB1, 256, 0, stream>>>(rowptr, part);
  k_gstart2<<<NB1, 256, 0, stream>>>(bat, rowptr, gstart, wg);
  k_bucket<<<(NE + 255) / 256, 256, 0, stream>>>(src, dst, rowptr, fill, col);
  k_agg1<<<NN / 4, 256, 0, stream>>>(rowptr, col, xf8, ag1);
  k_gemm1<<<(NN + 63) / 64, 256, 0, stream>>>(xb, ag1, b1, Bp1, hf8);
  k_poolE2<<<PEB, 256, 0, stream>>>(col, wg, hf8, Y1);
  k_out<<<NG, 256, 0, stream>>>(Y1, hf8, W2l, W2r, b2, gstart, (float*)d_out);
}

// Round 8
// 210.589 us; speedup vs baseline: 27.3860x; 1.1058x over previous
//
#include <hip/hip_runtime.h>

#define NN 100000   // nodes
#define NE 640000   // edges
#define DIN 128
#define DH 256
#define DOUT 256
#define NG 256      // graphs
#define NB1 ((NN + 255) / 256)   // 391 blocks for scan

// edge pool geometry: wave per chunk
#define PECH 157                          // edges per wave
#define CPE (4 * PECH)                    // edges per block (628)
#define PEB ((NE + CPE - 1) / CPE)        // 1020 blocks
#define GSP 8                             // graphs per LDS slab

// node pool geometry
#define PNB 1024
#define CHN2 ((NN + PNB - 1) / PNB)       // 98 nodes/block

typedef __bf16 bf16_t;
typedef __bf16 bf16x8 __attribute__((ext_vector_type(8)));
typedef __bf16 bf16x2 __attribute__((ext_vector_type(2)));
typedef float f32x4 __attribute__((ext_vector_type(4)));
typedef float f32v2 __attribute__((ext_vector_type(2)));

// ---------------- fp8 e4m3 pack/unpack (HW path; consistent-roundtrip) ----------------
#if __has_builtin(__builtin_amdgcn_cvt_pk_fp8_f32) && __has_builtin(__builtin_amdgcn_cvt_pk_f32_fp8)
#define USE_HW_FP8 1
#else
#define USE_HW_FP8 0
#endif

#if !USE_HW_FP8
__device__ __forceinline__ unsigned f32_to_fp8_1(float f) {  // signed e4m3fn
  unsigned sg = (__float_as_uint(f) >> 31) << 7;
  float af = fabsf(f);
  unsigned body;
  if (af < 0.015625f) {
    body = (unsigned)(int)rintf(af * 512.0f);
  } else {
    unsigned bits = __float_as_uint(af);
    unsigned rb = bits + 0x7FFFFu + ((bits >> 20) & 1u);
    unsigned e = rb >> 23;
    body = ((e - 120u) << 3) | ((rb >> 20) & 7u);
  }
  return (sg | body) & 0xffu;
}
__device__ __forceinline__ float fp8_to_f32_1(unsigned b) {
  unsigned s = b >> 7, e = (b >> 3) & 15u, m = b & 7u;
  float v = (e == 0) ? (float)m * 0.001953125f
                     : __uint_as_float(((e + 120u) << 23) | (m << 20));
  return s ? -v : v;
}
#endif

__device__ __forceinline__ unsigned pack4_fp8(float v0, float v1, float v2, float v3) {
#if USE_HW_FP8
  int u = __builtin_amdgcn_cvt_pk_fp8_f32(v0, v1, 0, false);
  u = __builtin_amdgcn_cvt_pk_fp8_f32(v2, v3, u, true);
  return (unsigned)u;
#else
  return f32_to_fp8_1(v0) | (f32_to_fp8_1(v1) << 8) |
         (f32_to_fp8_1(v2) << 16) | (f32_to_fp8_1(v3) << 24);
#endif
}

__device__ __forceinline__ void unpack4_fp8(unsigned v, float* o) {
#if USE_HW_FP8
  f32v2 a = __builtin_amdgcn_cvt_pk_f32_fp8((int)v, false);
  f32v2 b = __builtin_amdgcn_cvt_pk_f32_fp8((int)v, true);
  o[0] = a[0]; o[1] = a[1]; o[2] = b[0]; o[3] = b[1];
#else
  o[0] = fp8_to_f32_1(v & 0xffu);         o[1] = fp8_to_f32_1((v >> 8) & 0xffu);
  o[2] = fp8_to_f32_1((v >> 16) & 0xffu); o[3] = fp8_to_f32_1(v >> 24);
#endif
}

__device__ __forceinline__ void unpack2_fp8(unsigned v, float* o) {  // low 2 bytes
#if USE_HW_FP8
  f32v2 a = __builtin_amdgcn_cvt_pk_f32_fp8((int)v, false);
  o[0] = a[0]; o[1] = a[1];
#else
  o[0] = fp8_to_f32_1(v & 0xffu); o[1] = fp8_to_f32_1((v >> 8) & 0xffu);
#endif
}

// ---------------- x -> bf16 + fp8 cast (both plain row-major) ----------------
__global__ void k_xcast(const float* __restrict__ x, bf16_t* __restrict__ xb,
                        unsigned char* __restrict__ xf8) {
  size_t i = ((size_t)blockIdx.x * 256 + threadIdx.x) * 8;
  if (i >= (size_t)NN * DIN) return;
  float4 a = *(const float4*)(x + i), b = *(const float4*)(x + i + 4);
  bf16x8 o;
  o[0] = (bf16_t)a.x; o[1] = (bf16_t)a.y; o[2] = (bf16_t)a.z; o[3] = (bf16_t)a.w;
  o[4] = (bf16_t)b.x; o[5] = (bf16_t)b.y; o[6] = (bf16_t)b.z; o[7] = (bf16_t)b.w;
  *(bf16x8*)(xb + i) = o;
  uint2 p;
  p.x = pack4_fp8(a.x, a.y, a.z, a.w);
  p.y = pack4_fp8(b.x, b.y, b.z, b.w);
  *(uint2*)(xf8 + i) = p;
}

// ---------------- degree count ----------------
__global__ void k_count(const int* __restrict__ dst, int* __restrict__ cnt) {
  int e = blockIdx.x * 256 + threadIdx.x;
  if (e < NE) atomicAdd(&cnt[dst[e]], 1);
}

// ---------------- prefix scan (3 kernels): rowptr = exclusive_scan(cnt) ----------------
__global__ void k_scan1(const int* __restrict__ cnt, int* __restrict__ rowptr,
                        int* __restrict__ part) {
  __shared__ int s[256];
  int t = threadIdx.x, i = blockIdx.x * 256 + t;
  int v = (i < NN) ? cnt[i] : 0;
  s[t] = v; __syncthreads();
#pragma unroll
  for (int off = 1; off < 256; off <<= 1) {
    int u = (t >= off) ? s[t - off] : 0;
    __syncthreads();
    s[t] += u;
    __syncthreads();
  }
  if (i < NN) rowptr[i] = s[t] - v;
  if (t == 255) part[blockIdx.x] = s[255];
}

__global__ void k_scan2(int* __restrict__ part) {
  __shared__ int s[512];
  int t = threadIdx.x;
  int v = (t < NB1) ? part[t] : 0;
  s[t] = v; __syncthreads();
#pragma unroll
  for (int off = 1; off < 512; off <<= 1) {
    int u = (t >= off) ? s[t - off] : 0;
    __syncthreads();
    s[t] += u;
    __syncthreads();
  }
  if (t < NB1) part[t] = s[t] - v;
}

__global__ void k_scan3(int* __restrict__ rowptr, const int* __restrict__ part) {
  int i = blockIdx.x * 256 + threadIdx.x;
  if (i < NN) rowptr[i] += part[i >> 8];
  if (i == 0) rowptr[NN] = NE;
}

// ---------------- graph start index + per-edge (graph,deg) metadata ----------------
__global__ void k_gstart2(const int* __restrict__ batch, const int* __restrict__ rowptr,
                          int* __restrict__ gstart, unsigned* __restrict__ wg) {
  int n = blockIdx.x * 256 + threadIdx.x;
  if (n >= NN) return;
  int b = batch[n];
  int prev = (n == 0) ? -1 : batch[n - 1];
  for (int g = prev + 1; g <= b; ++g) gstart[g] = n;
  if (n == NN - 1) {
    for (int g = b + 1; g <= NG; ++g) gstart[g] = NN;
  }
  int e0 = rowptr[n], e1 = rowptr[n + 1];
  unsigned val = ((unsigned)b << 16) | (unsigned)(e1 - e0);
  for (int e = e0; e < e1; ++e) wg[e] = val;
}

// ---------------- bucket edges by dst (col only) ----------------
__global__ void k_bucket(const int* __restrict__ src, const int* __restrict__ dst,
                         const int* __restrict__ rowptr, int* __restrict__ fill,
                         int* __restrict__ col) {
  int e = blockIdx.x * 256 + threadIdx.x;
  if (e < NE) {
    int d = dst[e];
    int p = rowptr[d] + atomicAdd(&fill[d], 1);
    col[p] = src[e];
  }
}

// ---------------- gather-mean layer1: one WAVE per node, 2B/lane, unroll-4 ----------------
__global__ void k_agg1(const int* __restrict__ rowptr, const int* __restrict__ col,
                       const unsigned char* __restrict__ xf8, bf16_t* __restrict__ ag1) {
  int w = (blockIdx.x * 256 + threadIdx.x) >> 6;
  int lane = threadIdx.x & 63;
  if (w >= NN) return;
  w = __builtin_amdgcn_readfirstlane(w);
  int e0 = rowptr[w], e1 = rowptr[w + 1];
  float a0 = 0.f, a1 = 0.f;
  int e = e0;
  for (; e + 4 <= e1; e += 4) {
    int s0 = col[e], s1 = col[e + 1], s2 = col[e + 2], s3 = col[e + 3];
    unsigned v0 = *(const unsigned short*)(xf8 + (size_t)s0 * DIN + lane * 2);
    unsigned v1 = *(const unsigned short*)(xf8 + (size_t)s1 * DIN + lane * 2);
    unsigned v2 = *(const unsigned short*)(xf8 + (size_t)s2 * DIN + lane * 2);
    unsigned v3 = *(const unsigned short*)(xf8 + (size_t)s3 * DIN + lane * 2);
    float o[2];
    unpack2_fp8(v0, o); a0 += o[0]; a1 += o[1];
    unpack2_fp8(v1, o); a0 += o[0]; a1 += o[1];
    unpack2_fp8(v2, o); a0 += o[0]; a1 += o[1];
    unpack2_fp8(v3, o); a0 += o[0]; a1 += o[1];
  }
  for (; e < e1; ++e) {
    int s0 = col[e];
    unsigned v0 = *(const unsigned short*)(xf8 + (size_t)s0 * DIN + lane * 2);
    float o[2];
    unpack2_fp8(v0, o); a0 += o[0]; a1 += o[1];
  }
  float r = (e1 > e0) ? __builtin_amdgcn_rcpf((float)(e1 - e0)) : 0.f;
  bf16x2 ov;
  ov[0] = (bf16_t)(a0 * r); ov[1] = (bf16_t)(a1 * r);
  ((bf16x2*)ag1)[(size_t)w * 64 + lane] = ov;
}

// ---------------- weight pack layer1 ----------------
__global__ void k_pack1(const float* __restrict__ Wl, const float* __restrict__ Wr,
                        bf16_t* __restrict__ Bp) {
  int t = blockIdx.x * 256 + threadIdx.x;   // 8 kc * 16 nt * 64 lanes = 8192
  if (t >= 8192) return;
  int lane = t & 63, nt = (t >> 6) & 15, kc = t >> 10;
  int n = nt * 16 + (lane & 15);
  int k0 = kc * 32 + (lane >> 4) * 8;
  bf16_t* o = Bp + ((size_t)(kc * 16 + nt) * 64 + lane) * 8;
  for (int j = 0; j < 8; ++j) {
    int k = k0 + j;
    float v = (k < 128) ? Wl[k * 256 + n] : Wr[(k - 128) * 256 + n];
    o[j] = (bf16_t)v;
  }
}

// ---------------- GEMM1: hf8 = fp8(relu([mean|x] @ [W1l;W1r] + b1)), K=256 ----------------
__launch_bounds__(256, 4)
__global__ void k_gemm1(const bf16_t* __restrict__ xb, const bf16_t* __restrict__ ag1,
                        const float* __restrict__ b1,
                        const bf16_t* __restrict__ Bp, unsigned char* __restrict__ hf8) {
  __shared__ unsigned char smem[64 * 512];   // A tile 64 x 256 bf16, XOR-swizzled
  int n0 = blockIdx.x * 64;
  int tid = threadIdx.x;
  {
    int row = tid >> 2, part = tid & 3;
    int node = n0 + row;
    unsigned sw = (row & 7) << 4;
    const uint4* ap = (const uint4*)(ag1 + (size_t)node * DIN);
    const uint4* xp = (const uint4*)(xb + (size_t)node * DIN);
#pragma unroll
    for (int i = 0; i < 4; ++i) {
      int mi = i * 4 + part;                 // 0..15
      uint4 va = {0u, 0u, 0u, 0u}, vx = {0u, 0u, 0u, 0u};
      if (node < NN) { va = ap[mi]; vx = xp[mi]; }
      *(uint4*)(smem + row * 512 + (((unsigned)(mi * 16)) ^ sw)) = va;
      *(uint4*)(smem + row * 512 + ((unsigned)(256 + mi * 16) ^ sw)) = vx;
    }
  }
  __syncthreads();
  int wave = tid >> 6, lane = tid & 63, lhi = lane >> 4, llo = lane & 15;
  f32x4 acc[4][4] = {};
  const bf16x8* bptr = (const bf16x8*)Bp;
#pragma unroll
  for (int kc = 0; kc < 8; ++kc) {
    bf16x8 a[4], b[4];
#pragma unroll
    for (int mi = 0; mi < 4; ++mi) {
      int row = mi * 16 + llo;
      unsigned cb = ((unsigned)((kc * 32 + lhi * 8) * 2)) ^ ((row & 7) << 4);
      a[mi] = *(const bf16x8*)(smem + row * 512 + cb);
    }
#pragma unroll
    for (int ni = 0; ni < 4; ++ni)
      b[ni] = bptr[(kc * 16 + wave * 4 + ni) * 64 + lane];
#pragma unroll
    for (int mi = 0; mi < 4; ++mi)
#pragma unroll
      for (int ni = 0; ni < 4; ++ni)
        acc[mi][ni] = __builtin_amdgcn_mfma_f32_16x16x32_bf16(a[mi], b[ni], acc[mi][ni], 0, 0, 0);
  }
  float bias[4];
#pragma unroll
  for (int ni = 0; ni < 4; ++ni) bias[ni] = b1[wave * 64 + ni * 16 + llo];
#pragma unroll
  for (int mi = 0; mi < 4; ++mi)
#pragma unroll
    for (int j = 0; j < 4; ++j) {
      int node = n0 + mi * 16 + lhi * 4 + j;
      if (node < NN) {
        float v0 = fmaxf(acc[mi][0][j] + bias[0], 0.f);
        float v1 = fmaxf(acc[mi][1][j] + bias[1], 0.f);
        float v2 = fmaxf(acc[mi][2][j] + bias[2], 0.f);
        float v3 = fmaxf(acc[mi][3][j] + bias[3], 0.f);
        unsigned u = pack4_fp8(v0, v1, v2, v3);
        *(unsigned*)(hf8 + (size_t)node * 256 + wave * 64 + llo * 4) = u;
      }
    }
}

// ---------------- edge pool: Y1[g] += (1/deg_dst) * h[src]; wave/chunk, unroll-8 ----------------
__global__ void k_poolE2(const int* __restrict__ col, const unsigned* __restrict__ wg,
                         const unsigned char* __restrict__ hf8, float* __restrict__ Y1) {
  __shared__ float gbuf[GSP][256];
  int tid = threadIdx.x;
  int c0 = blockIdx.x * CPE;
  int c1 = (c0 + CPE < NE) ? c0 + CPE : NE;
  if (c0 >= c1) return;
  int gmin = (int)(wg[c0] >> 16), gmax = (int)(wg[c1 - 1] >> 16);
  bool ldsok = (gmax - gmin) < GSP;
  for (int i = tid; i < GSP * 256; i += 256) (&gbuf[0][0])[i] = 0.f;
  __syncthreads();
  int wv = tid >> 6, lane = tid & 63;
  int e0 = __builtin_amdgcn_readfirstlane(c0 + wv * PECH);
  int e1 = e0 + PECH; if (e1 > c1) e1 = c1;
  int dmb = ((lane >> 4) << 6) | (lane & 15);
  float acc[4] = {0.f, 0.f, 0.f, 0.f};
  int curg = -1;
#define EFLUSH() do { if (curg >= 0) {                                        \
    if (ldsok) { float* gp = gbuf[curg - gmin];                               \
      atomicAdd(gp + (dmb | 0),  acc[0]); atomicAdd(gp + (dmb | 16), acc[1]); \
      atomicAdd(gp + (dmb | 32), acc[2]); atomicAdd(gp + (dmb | 48), acc[3]); \
    } else { float* yp = Y1 + (size_t)curg * 256;                             \
      unsafeAtomicAdd(yp + (dmb | 0),  acc[0]);                               \
      unsafeAtomicAdd(yp + (dmb | 16), acc[1]);                               \
      unsafeAtomicAdd(yp + (dmb | 32), acc[2]);                               \
      unsafeAtomicAdd(yp + (dmb | 48), acc[3]); }                             \
    acc[0] = acc[1] = acc[2] = acc[3] = 0.f; } } while (0)
  if (e0 < e1) {
    int e = e0;
    for (; e + 8 <= e1; e += 8) {
      int cv[8]; unsigned wvv[8]; unsigned hv[8];
#pragma unroll
      for (int i = 0; i < 8; ++i) { cv[i] = col[e + i]; wvv[i] = wg[e + i]; }
#pragma unroll
      for (int i = 0; i < 8; ++i)
        hv[i] = *(const unsigned*)(hf8 + (size_t)cv[i] * 256 + lane * 4);
#pragma unroll
      for (int i = 0; i < 8; ++i) {
        int g = (int)(wvv[i] >> 16);
        if (g != curg) { EFLUSH(); curg = g; }
        float w = __builtin_amdgcn_rcpf((float)(wvv[i] & 0xffffu));
        float o[4]; unpack4_fp8(hv[i], o);
        acc[0] += w * o[0]; acc[1] += w * o[1];
        acc[2] += w * o[2]; acc[3] += w * o[3];
      }
    }
    for (; e < e1; ++e) {
      int c = col[e]; unsigned wv2 = wg[e];
      unsigned hvv = *(const unsigned*)(hf8 + (size_t)c * 256 + lane * 4);
      int g = (int)(wv2 >> 16);
      if (g != curg) { EFLUSH(); curg = g; }
      float w = __builtin_amdgcn_rcpf((float)(wv2 & 0xffffu));
      float o[4]; unpack4_fp8(hvv, o);
      acc[0] += w * o[0]; acc[1] += w * o[1];
      acc[2] += w * o[2]; acc[3] += w * o[3];
    }
    EFLUSH();
  }
#undef EFLUSH
  __syncthreads();
  if (ldsok) {
    int ng = gmax - gmin + 1;
    for (int gi = 0; gi < ng; ++gi)
      unsafeAtomicAdd(&Y1[(size_t)(gmin + gi) * 256 + tid], gbuf[gi][tid]);
  }
}

// ---------------- node pool: Y2[g] += h[n]; wave sub-ranges, LDS slab ----------------
__global__ void k_poolN(const int* __restrict__ batch, const unsigned char* __restrict__ hf8,
                        float* __restrict__ Y2) {
  __shared__ float gbuf[GSP][256];
  int tid = threadIdx.x;
  int n0 = blockIdx.x * CHN2;
  int n1 = (n0 + CHN2 < NN) ? n0 + CHN2 : NN;
  if (n0 >= n1) return;
  int gmin = batch[n0], gmax = batch[n1 - 1];
  bool ldsok = (gmax - gmin) < GSP;
  for (int i = tid; i < GSP * 256; i += 256) (&gbuf[0][0])[i] = 0.f;
  __syncthreads();
  int wv = tid >> 6, lane = tid & 63;
  const int per = (CHN2 + 3) >> 2;          // 25 nodes per wave
  int a0 = n0 + wv * per;
  int a1 = a0 + per; if (a1 > n1) a1 = n1;
  int dmb = ((lane >> 4) << 6) | (lane & 15);
  float acc[4] = {0.f, 0.f, 0.f, 0.f};
  int curg = -1;
#define NFLUSH() do { if (curg >= 0) {                                        \
    if (ldsok) { float* gp = gbuf[curg - gmin];                               \
      atomicAdd(gp + (dmb | 0),  acc[0]); atomicAdd(gp + (dmb | 16), acc[1]); \
      atomicAdd(gp + (dmb | 32), acc[2]); atomicAdd(gp + (dmb | 48), acc[3]); \
    } else { float* yp = Y2 + (size_t)curg * 256;                             \
      unsafeAtomicAdd(yp + (dmb | 0),  acc[0]);                               \
      unsafeAtomicAdd(yp + (dmb | 16), acc[1]);                               \
      unsafeAtomicAdd(yp + (dmb | 32), acc[2]);                               \
      unsafeAtomicAdd(yp + (dmb | 48), acc[3]); }                             \
    acc[0] = acc[1] = acc[2] = acc[3] = 0.f; } } while (0)
  for (int n = a0; n < a1; ++n) {
    int g = batch[n];
    if (g != curg) { NFLUSH(); curg = g; }
    unsigned v = *(const unsigned*)(hf8 + (size_t)n * 256 + lane * 4);
    float o[4]; unpack4_fp8(v, o);
    acc[0] += o[0]; acc[1] += o[1]; acc[2] += o[2]; acc[3] += o[3];
  }
  NFLUSH();
#undef NFLUSH
  __syncthreads();
  if (ldsok) {
    int ng = gmax - gmin + 1;
    for (int gi = 0; gi < ng; ++gi)
      unsafeAtomicAdd(&Y2[(size_t)(gmin + gi) * 256 + tid], gbuf[gi][tid]);
  }
}

// ---------------- final GEMM, split-K: out[g] += y_slice @ W_slice (+bias on ks==0) ----------------
__global__ void k_out2(const float* __restrict__ Y1, const float* __restrict__ Y2,
                       const float* __restrict__ W2l, const float* __restrict__ W2r,
                       const float* __restrict__ b2, const int* __restrict__ gstart,
                       float* __restrict__ out) {
  __shared__ float ys[128];
  int g = blockIdx.x, ks = blockIdx.y, t = threadIdx.x;
  const float* Ysrc = (ks < 2) ? Y1 : Y2;
  const float* Wsrc = (ks < 2) ? W2l : W2r;
  int kbase = (ks & 1) * 128;
  if (t < 128) ys[t] = Ysrc[(size_t)g * 256 + kbase + t];
  __syncthreads();
  float s = 0.f;
  const float* wp = Wsrc + (size_t)kbase * 256 + t;
#pragma unroll 8
  for (int k = 0; k < 128; ++k) s += ys[k] * wp[(size_t)k * 256];
  if (ks == 0) {
    float cntf = (float)(gstart[g + 1] - gstart[g]);
    s += b2[t] * cntf;
  }
  unsafeAtomicAdd(&out[(size_t)g * 256 + t], s);
}

extern "C" void kernel_launch(void* const* d_in, const int* in_sizes, int n_in,
                              void* d_out, int out_size, void* d_ws, size_t ws_size,
                              hipStream_t stream) {
  const float* x   = (const float*)d_in[0];
  const int*   ei  = (const int*)d_in[1];     // [2][NE] int32
  const int*   bat = (const int*)d_in[2];     // [NN] int32 (sorted)
  const float* W1l = (const float*)d_in[3];
  const float* b1  = (const float*)d_in[4];
  const float* W1r = (const float*)d_in[5];
  const float* W2l = (const float*)d_in[6];
  const float* b2  = (const float*)d_in[7];
  const float* W2r = (const float*)d_in[8];
  const int* src = ei;
  const int* dst = ei + NE;

  char* ws = (char*)d_ws;
  size_t off = 0;
  int* cnt     = (int*)(ws + off); off += ((size_t)NN * 4 + 255) & ~(size_t)255;
  int* rowptr  = (int*)(ws + off); off += ((size_t)(NN + 1) * 4 + 255) & ~(size_t)255;
  int* part    = (int*)(ws + off); off += 512 * 4;
  int* fill    = (int*)(ws + off); off += ((size_t)NN * 4 + 255) & ~(size_t)255;
  int* gstart  = (int*)(ws + off); off += ((size_t)(NG + 1) * 4 + 255) & ~(size_t)255;
  int* col     = (int*)(ws + off); off += (size_t)NE * 4;
  unsigned* wg = (unsigned*)(ws + off); off += (size_t)NE * 4;
  bf16_t* Bp1  = (bf16_t*)(ws + off); off += (size_t)256 * 256 * 2;
  float* Y1    = (float*)(ws + off); off += (size_t)NG * 256 * 4;
  float* Y2    = (float*)(ws + off); off += (size_t)NG * 256 * 4;
  bf16_t* xb   = (bf16_t*)(ws + off); off += (size_t)NN * DIN * 2;
  unsigned char* xf8 = (unsigned char*)(ws + off); off += (size_t)NN * DIN;
  bf16_t* ag1  = (bf16_t*)(ws + off); off += (size_t)NN * DIN * 2;
  unsigned char* hf8 = (unsigned char*)(ws + off); off += (size_t)NN * DH;

  hipMemsetAsync(cnt, 0, (size_t)NN * 4, stream);
  hipMemsetAsync(fill, 0, (size_t)NN * 4, stream);
  hipMemsetAsync(Y1, 0, (size_t)NG * 256 * 4 * 2, stream);   // Y1,Y2 contiguous
  hipMemsetAsync(d_out, 0, (size_t)out_size * 4, stream);
  k_xcast<<<NN * DIN / 8 / 256, 256, 0, stream>>>(x, xb, xf8);
  k_pack1<<<32, 256, 0, stream>>>(W1l, W1r, Bp1);
  k_count<<<(NE + 255) / 256, 256, 0, stream>>>(dst, cnt);
  k_scan1<<<NB1, 256, 0, stream>>>(cnt, rowptr, part);
  k_scan2<<<1, 512, 0, stream>>>(part);
  k_scan3<<<NB1, 256, 0, stream>>>(rowptr, part);
  k_gstart2<<<NB1, 256, 0, stream>>>(bat, rowptr, gstart, wg);
  k_bucket<<<(NE + 255) / 256, 256, 0, stream>>>(src, dst, rowptr, fill, col);
  k_agg1<<<NN / 4, 256, 0, stream>>>(rowptr, col, xf8, ag1);
  k_gemm1<<<(NN + 63) / 64, 256, 0, stream>>>(xb, ag1, b1, Bp1, hf8);
  k_poolE2<<<PEB, 256, 0, stream>>>(col, wg, hf8, Y1);
  k_poolN<<<PNB, 256, 0, stream>>>(bat, hf8, Y2);
  k_out2<<<dim3(NG, 4), 256, 0, stream>>>(Y1, Y2, W2l, W2r, b2, gstart, (float*)d_out);
}

// Round 9
// 209.364 us; speedup vs baseline: 27.5462x; 1.0058x over previous
//
#include <hip/hip_runtime.h>

#define NN 100000   // nodes
#define NE 640000   // edges
#define DIN 128
#define DH 256
#define DOUT 256
#define NG 256      // graphs
#define NB1 ((NN + 255) / 256)   // 391 blocks for scan

// edge pool geometry: wave per chunk
#define PECH 157                          // edges per wave
#define CPE (4 * PECH)                    // edges per block (628)
#define PEB ((NE + CPE - 1) / CPE)        // 1020 blocks
#define GSP 8                             // graphs per LDS slab

// node pool geometry
#define PNB 1024
#define CHN2 ((NN + PNB - 1) / PNB)       // 98 nodes/block

// bucket geometry: 8 XCD classes x edge chunks
#define BCH 4096
#define BNB ((NE + BCH - 1) / BCH)        // 157 chunks

typedef __bf16 bf16_t;
typedef __bf16 bf16x8 __attribute__((ext_vector_type(8)));
typedef __bf16 bf16x2 __attribute__((ext_vector_type(2)));
typedef float f32x4 __attribute__((ext_vector_type(4)));
typedef float f32v2 __attribute__((ext_vector_type(2)));

// ---------------- fp8 e4m3 pack/unpack (HW path; consistent-roundtrip) ----------------
#if __has_builtin(__builtin_amdgcn_cvt_pk_fp8_f32) && __has_builtin(__builtin_amdgcn_cvt_pk_f32_fp8)
#define USE_HW_FP8 1
#else
#define USE_HW_FP8 0
#endif

#if !USE_HW_FP8
__device__ __forceinline__ unsigned f32_to_fp8_1(float f) {  // signed e4m3fn
  unsigned sg = (__float_as_uint(f) >> 31) << 7;
  float af = fabsf(f);
  unsigned body;
  if (af < 0.015625f) {
    body = (unsigned)(int)rintf(af * 512.0f);
  } else {
    unsigned bits = __float_as_uint(af);
    unsigned rb = bits + 0x7FFFFu + ((bits >> 20) & 1u);
    unsigned e = rb >> 23;
    body = ((e - 120u) << 3) | ((rb >> 20) & 7u);
  }
  return (sg | body) & 0xffu;
}
__device__ __forceinline__ float fp8_to_f32_1(unsigned b) {
  unsigned s = b >> 7, e = (b >> 3) & 15u, m = b & 7u;
  float v = (e == 0) ? (float)m * 0.001953125f
                     : __uint_as_float(((e + 120u) << 23) | (m << 20));
  return s ? -v : v;
}
#endif

__device__ __forceinline__ unsigned pack4_fp8(float v0, float v1, float v2, float v3) {
#if USE_HW_FP8
  int u = __builtin_amdgcn_cvt_pk_fp8_f32(v0, v1, 0, false);
  u = __builtin_amdgcn_cvt_pk_fp8_f32(v2, v3, u, true);
  return (unsigned)u;
#else
  return f32_to_fp8_1(v0) | (f32_to_fp8_1(v1) << 8) |
         (f32_to_fp8_1(v2) << 16) | (f32_to_fp8_1(v3) << 24);
#endif
}

__device__ __forceinline__ void unpack4_fp8(unsigned v, float* o) {
#if USE_HW_FP8
  f32v2 a = __builtin_amdgcn_cvt_pk_f32_fp8((int)v, false);
  f32v2 b = __builtin_amdgcn_cvt_pk_f32_fp8((int)v, true);
  o[0] = a[0]; o[1] = a[1]; o[2] = b[0]; o[3] = b[1];
#else
  o[0] = fp8_to_f32_1(v & 0xffu);         o[1] = fp8_to_f32_1((v >> 8) & 0xffu);
  o[2] = fp8_to_f32_1((v >> 16) & 0xffu); o[3] = fp8_to_f32_1(v >> 24);
#endif
}

__device__ __forceinline__ void unpack2_fp8(unsigned v, float* o) {  // low 2 bytes
#if USE_HW_FP8
  f32v2 a = __builtin_amdgcn_cvt_pk_f32_fp8((int)v, false);
  o[0] = a[0]; o[1] = a[1];
#else
  o[0] = fp8_to_f32_1(v & 0xffu); o[1] = fp8_to_f32_1((v >> 8) & 0xffu);
#endif
}

// ---------------- x -> bf16 + fp8 cast (both plain row-major) ----------------
__global__ void k_xcast(const float* __restrict__ x, bf16_t* __restrict__ xb,
                        unsigned char* __restrict__ xf8) {
  size_t i = ((size_t)blockIdx.x * 256 + threadIdx.x) * 8;
  if (i >= (size_t)NN * DIN) return;
  float4 a = *(const float4*)(x + i), b = *(const float4*)(x + i + 4);
  bf16x8 o;
  o[0] = (bf16_t)a.x; o[1] = (bf16_t)a.y; o[2] = (bf16_t)a.z; o[3] = (bf16_t)a.w;
  o[4] = (bf16_t)b.x; o[5] = (bf16_t)b.y; o[6] = (bf16_t)b.z; o[7] = (bf16_t)b.w;
  *(bf16x8*)(xb + i) = o;
  uint2 p;
  p.x = pack4_fp8(a.x, a.y, a.z, a.w);
  p.y = pack4_fp8(b.x, b.y, b.z, b.w);
  *(uint2*)(xf8 + i) = p;
}

// ---------------- degree count ----------------
__global__ void k_count(const int* __restrict__ dst, int* __restrict__ cnt) {
  int e = blockIdx.x * 256 + threadIdx.x;
  if (e < NE) atomicAdd(&cnt[dst[e]], 1);
}

// ---------------- prefix scan (3 kernels): rowptr = exclusive_scan(cnt) ----------------
__global__ void k_scan1(const int* __restrict__ cnt, int* __restrict__ rowptr,
                        int* __restrict__ part) {
  __shared__ int s[256];
  int t = threadIdx.x, i = blockIdx.x * 256 + t;
  int v = (i < NN) ? cnt[i] : 0;
  s[t] = v; __syncthreads();
#pragma unroll
  for (int off = 1; off < 256; off <<= 1) {
    int u = (t >= off) ? s[t - off] : 0;
    __syncthreads();
    s[t] += u;
    __syncthreads();
  }
  if (i < NN) rowptr[i] = s[t] - v;
  if (t == 255) part[blockIdx.x] = s[255];
}

__global__ void k_scan2(int* __restrict__ part) {
  __shared__ int s[512];
  int t = threadIdx.x;
  int v = (t < NB1) ? part[t] : 0;
  s[t] = v; __syncthreads();
#pragma unroll
  for (int off = 1; off < 512; off <<= 1) {
    int u = (t >= off) ? s[t - off] : 0;
    __syncthreads();
    s[t] += u;
    __syncthreads();
  }
  if (t < NB1) part[t] = s[t] - v;
}

__global__ void k_scan3(int* __restrict__ rowptr, const int* __restrict__ part) {
  int i = blockIdx.x * 256 + threadIdx.x;
  if (i < NN) rowptr[i] += part[i >> 8];
  if (i == 0) rowptr[NN] = NE;
}

// ---------------- graph start index + per-edge (graph,deg) metadata ----------------
__global__ void k_gstart2(const int* __restrict__ batch, const int* __restrict__ rowptr,
                          int* __restrict__ gstart, unsigned* __restrict__ wg) {
  int n = blockIdx.x * 256 + threadIdx.x;
  if (n >= NN) return;
  int b = batch[n];
  int prev = (n == 0) ? -1 : batch[n - 1];
  for (int g = prev + 1; g <= b; ++g) gstart[g] = n;
  if (n == NN - 1) {
    for (int g = b + 1; g <= NG; ++g) gstart[g] = NN;
  }
  int e0 = rowptr[n], e1 = rowptr[n + 1];
  unsigned val = ((unsigned)b << 16) | (unsigned)(e1 - e0);
  for (int e = e0; e < e1; ++e) wg[e] = val;
}

// ---------------- bucket edges by dst, XCD-class partitioned ----------------
// class = (dst>>4)&7 selects a 16-node (= one 64B line of fill/col-range) group;
// blocks with blockIdx&7==c handle class c. With round-robin block->XCD mapping,
// each col/fill cache line is written by a single XCD -> writes merge in its L2
// (kills the 17x write amplification seen in round 8). Correct regardless of
// the actual XCD mapping: every edge is processed exactly once.
__global__ void k_bucket(const int* __restrict__ src, const int* __restrict__ dst,
                         const int* __restrict__ rowptr, int* __restrict__ fill,
                         int* __restrict__ col) {
  int cls = blockIdx.x & 7;
  int cb = blockIdx.x >> 3;
  int e0 = cb * BCH;
  int e1 = (e0 + BCH < NE) ? e0 + BCH : NE;
  for (int e = e0 + threadIdx.x; e < e1; e += 256) {
    int d = dst[e];
    if (((d >> 4) & 7) == cls) {
      int p = rowptr[d] + atomicAdd(&fill[d], 1);
      col[p] = src[e];
    }
  }
}

// ---------------- gather-mean layer1: one WAVE per node, 2B/lane, unroll-4 ----------------
__global__ void k_agg1(const int* __restrict__ rowptr, const int* __restrict__ col,
                       const unsigned char* __restrict__ xf8, bf16_t* __restrict__ ag1) {
  int w = (blockIdx.x * 256 + threadIdx.x) >> 6;
  int lane = threadIdx.x & 63;
  if (w >= NN) return;
  w = __builtin_amdgcn_readfirstlane(w);
  int e0 = rowptr[w], e1 = rowptr[w + 1];
  float a0 = 0.f, a1 = 0.f;
  int e = e0;
  for (; e + 4 <= e1; e += 4) {
    int s0 = col[e], s1 = col[e + 1], s2 = col[e + 2], s3 = col[e + 3];
    unsigned v0 = *(const unsigned short*)(xf8 + (size_t)s0 * DIN + lane * 2);
    unsigned v1 = *(const unsigned short*)(xf8 + (size_t)s1 * DIN + lane * 2);
    unsigned v2 = *(const unsigned short*)(xf8 + (size_t)s2 * DIN + lane * 2);
    unsigned v3 = *(const unsigned short*)(xf8 + (size_t)s3 * DIN + lane * 2);
    float o[2];
    unpack2_fp8(v0, o); a0 += o[0]; a1 += o[1];
    unpack2_fp8(v1, o); a0 += o[0]; a1 += o[1];
    unpack2_fp8(v2, o); a0 += o[0]; a1 += o[1];
    unpack2_fp8(v3, o); a0 += o[0]; a1 += o[1];
  }
  for (; e < e1; ++e) {
    int s0 = col[e];
    unsigned v0 = *(const unsigned short*)(xf8 + (size_t)s0 * DIN + lane * 2);
    float o[2];
    unpack2_fp8(v0, o); a0 += o[0]; a1 += o[1];
  }
  float r = (e1 > e0) ? __builtin_amdgcn_rcpf((float)(e1 - e0)) : 0.f;
  bf16x2 ov;
  ov[0] = (bf16_t)(a0 * r); ov[1] = (bf16_t)(a1 * r);
  ((bf16x2*)ag1)[(size_t)w * 64 + lane] = ov;
}

// ---------------- weight pack layer1 ----------------
__global__ void k_pack1(const float* __restrict__ Wl, const float* __restrict__ Wr,
                        bf16_t* __restrict__ Bp) {
  int t = blockIdx.x * 256 + threadIdx.x;   // 8 kc * 16 nt * 64 lanes = 8192
  if (t >= 8192) return;
  int lane = t & 63, nt = (t >> 6) & 15, kc = t >> 10;
  int n = nt * 16 + (lane & 15);
  int k0 = kc * 32 + (lane >> 4) * 8;
  bf16_t* o = Bp + ((size_t)(kc * 16 + nt) * 64 + lane) * 8;
  for (int j = 0; j < 8; ++j) {
    int k = k0 + j;
    float v = (k < 128) ? Wl[k * 256 + n] : Wr[(k - 128) * 256 + n];
    o[j] = (bf16_t)v;
  }
}

// ---------------- GEMM1: hf8 = fp8(relu([mean|x] @ [W1l;W1r] + b1)), K=256 ----------------
__launch_bounds__(256, 4)
__global__ void k_gemm1(const bf16_t* __restrict__ xb, const bf16_t* __restrict__ ag1,
                        const float* __restrict__ b1,
                        const bf16_t* __restrict__ Bp, unsigned char* __restrict__ hf8) {
  __shared__ unsigned char smem[64 * 512];   // A tile 64 x 256 bf16, XOR-swizzled
  int n0 = blockIdx.x * 64;
  int tid = threadIdx.x;
  {
    int row = tid >> 2, part = tid & 3;
    int node = n0 + row;
    unsigned sw = (row & 7) << 4;
    const uint4* ap = (const uint4*)(ag1 + (size_t)node * DIN);
    const uint4* xp = (const uint4*)(xb + (size_t)node * DIN);
#pragma unroll
    for (int i = 0; i < 4; ++i) {
      int mi = i * 4 + part;                 // 0..15
      uint4 va = {0u, 0u, 0u, 0u}, vx = {0u, 0u, 0u, 0u};
      if (node < NN) { va = ap[mi]; vx = xp[mi]; }
      *(uint4*)(smem + row * 512 + (((unsigned)(mi * 16)) ^ sw)) = va;
      *(uint4*)(smem + row * 512 + ((unsigned)(256 + mi * 16) ^ sw)) = vx;
    }
  }
  __syncthreads();
  int wave = tid >> 6, lane = tid & 63, lhi = lane >> 4, llo = lane & 15;
  f32x4 acc[4][4] = {};
  const bf16x8* bptr = (const bf16x8*)Bp;
#pragma unroll
  for (int kc = 0; kc < 8; ++kc) {
    bf16x8 a[4], b[4];
#pragma unroll
    for (int mi = 0; mi < 4; ++mi) {
      int row = mi * 16 + llo;
      unsigned cb = ((unsigned)((kc * 32 + lhi * 8) * 2)) ^ ((row & 7) << 4);
      a[mi] = *(const bf16x8*)(smem + row * 512 + cb);
    }
#pragma unroll
    for (int ni = 0; ni < 4; ++ni)
      b[ni] = bptr[(kc * 16 + wave * 4 + ni) * 64 + lane];
#pragma unroll
    for (int mi = 0; mi < 4; ++mi)
#pragma unroll
      for (int ni = 0; ni < 4; ++ni)
        acc[mi][ni] = __builtin_amdgcn_mfma_f32_16x16x32_bf16(a[mi], b[ni], acc[mi][ni], 0, 0, 0);
  }
  float bias[4];
#pragma unroll
  for (int ni = 0; ni < 4; ++ni) bias[ni] = b1[wave * 64 + ni * 16 + llo];
#pragma unroll
  for (int mi = 0; mi < 4; ++mi)
#pragma unroll
    for (int j = 0; j < 4; ++j) {
      int node = n0 + mi * 16 + lhi * 4 + j;
      if (node < NN) {
        float v0 = fmaxf(acc[mi][0][j] + bias[0], 0.f);
        float v1 = fmaxf(acc[mi][1][j] + bias[1], 0.f);
        float v2 = fmaxf(acc[mi][2][j] + bias[2], 0.f);
        float v3 = fmaxf(acc[mi][3][j] + bias[3], 0.f);
        unsigned u = pack4_fp8(v0, v1, v2, v3);
        *(unsigned*)(hf8 + (size_t)node * 256 + wave * 64 + llo * 4) = u;
      }
    }
}

// ---------------- edge pool: Y1[g] += (1/deg_dst) * h[src]; wave/chunk, unroll-8 ----------------
__global__ void k_poolE2(const int* __restrict__ col, const unsigned* __restrict__ wg,
                         const unsigned char* __restrict__ hf8, float* __restrict__ Y1) {
  __shared__ float gbuf[GSP][256];
  int tid = threadIdx.x;
  int c0 = blockIdx.x * CPE;
  int c1 = (c0 + CPE < NE) ? c0 + CPE : NE;
  if (c0 >= c1) return;
  int gmin = (int)(wg[c0] >> 16), gmax = (int)(wg[c1 - 1] >> 16);
  bool ldsok = (gmax - gmin) < GSP;
  for (int i = tid; i < GSP * 256; i += 256) (&gbuf[0][0])[i] = 0.f;
  __syncthreads();
  int wv = tid >> 6, lane = tid & 63;
  int e0 = __builtin_amdgcn_readfirstlane(c0 + wv * PECH);
  int e1 = e0 + PECH; if (e1 > c1) e1 = c1;
  int dmb = ((lane >> 4) << 6) | (lane & 15);
  float acc[4] = {0.f, 0.f, 0.f, 0.f};
  int curg = -1;
#define EFLUSH() do { if (curg >= 0) {                                        \
    if (ldsok) { float* gp = gbuf[curg - gmin];                               \
      atomicAdd(gp + (dmb | 0),  acc[0]); atomicAdd(gp + (dmb | 16), acc[1]); \
      atomicAdd(gp + (dmb | 32), acc[2]); atomicAdd(gp + (dmb | 48), acc[3]); \
    } else { float* yp = Y1 + (size_t)curg * 256;                             \
      unsafeAtomicAdd(yp + (dmb | 0),  acc[0]);                               \
      unsafeAtomicAdd(yp + (dmb | 16), acc[1]);                               \
      unsafeAtomicAdd(yp + (dmb | 32), acc[2]);                               \
      unsafeAtomicAdd(yp + (dmb | 48), acc[3]); }                             \
    acc[0] = acc[1] = acc[2] = acc[3] = 0.f; } } while (0)
  if (e0 < e1) {
    int e = e0;
    for (; e + 8 <= e1; e += 8) {
      int cv[8]; unsigned wvv[8]; unsigned hv[8];
#pragma unroll
      for (int i = 0; i < 8; ++i) { cv[i] = col[e + i]; wvv[i] = wg[e + i]; }
#pragma unroll
      for (int i = 0; i < 8; ++i)
        hv[i] = *(const unsigned*)(hf8 + (size_t)cv[i] * 256 + lane * 4);
#pragma unroll
      for (int i = 0; i < 8; ++i) {
        int g = (int)(wvv[i] >> 16);
        if (g != curg) { EFLUSH(); curg = g; }
        float w = __builtin_amdgcn_rcpf((float)(wvv[i] & 0xffffu));
        float o[4]; unpack4_fp8(hv[i], o);
        acc[0] += w * o[0]; acc[1] += w * o[1];
        acc[2] += w * o[2]; acc[3] += w * o[3];
      }
    }
    for (; e < e1; ++e) {
      int c = col[e]; unsigned wv2 = wg[e];
      unsigned hvv = *(const unsigned*)(hf8 + (size_t)c * 256 + lane * 4);
      int g = (int)(wv2 >> 16);
      if (g != curg) { EFLUSH(); curg = g; }
      float w = __builtin_amdgcn_rcpf((float)(wv2 & 0xffffu));
      float o[4]; unpack4_fp8(hvv, o);
      acc[0] += w * o[0]; acc[1] += w * o[1];
      acc[2] += w * o[2]; acc[3] += w * o[3];
    }
    EFLUSH();
  }
#undef EFLUSH
  __syncthreads();
  if (ldsok) {
    int ng = gmax - gmin + 1;
    for (int gi = 0; gi < ng; ++gi)
      unsafeAtomicAdd(&Y1[(size_t)(gmin + gi) * 256 + tid], gbuf[gi][tid]);
  }
}

// ---------------- node pool: Y2[g] += h[n]; wave sub-ranges, LDS slab ----------------
__global__ void k_poolN(const int* __restrict__ batch, const unsigned char* __restrict__ hf8,
                        float* __restrict__ Y2) {
  __shared__ float gbuf[GSP][256];
  int tid = threadIdx.x;
  int n0 = blockIdx.x * CHN2;
  int n1 = (n0 + CHN2 < NN) ? n0 + CHN2 : NN;
  if (n0 >= n1) return;
  int gmin = batch[n0], gmax = batch[n1 - 1];
  bool ldsok = (gmax - gmin) < GSP;
  for (int i = tid; i < GSP * 256; i += 256) (&gbuf[0][0])[i] = 0.f;
  __syncthreads();
  int wv = tid >> 6, lane = tid & 63;
  const int per = (CHN2 + 3) >> 2;          // 25 nodes per wave
  int a0 = n0 + wv * per;
  int a1 = a0 + per; if (a1 > n1) a1 = n1;
  int dmb = ((lane >> 4) << 6) | (lane & 15);
  float acc[4] = {0.f, 0.f, 0.f, 0.f};
  int curg = -1;
#define NFLUSH() do { if (curg >= 0) {                                        \
    if (ldsok) { float* gp = gbuf[curg - gmin];                               \
      atomicAdd(gp + (dmb | 0),  acc[0]); atomicAdd(gp + (dmb | 16), acc[1]); \
      atomicAdd(gp + (dmb | 32), acc[2]); atomicAdd(gp + (dmb | 48), acc[3]); \
    } else { float* yp = Y2 + (size_t)curg * 256;                             \
      unsafeAtomicAdd(yp + (dmb | 0),  acc[0]);                               \
      unsafeAtomicAdd(yp + (dmb | 16), acc[1]);                               \
      unsafeAtomicAdd(yp + (dmb | 32), acc[2]);                               \
      unsafeAtomicAdd(yp + (dmb | 48), acc[3]); }                             \
    acc[0] = acc[1] = acc[2] = acc[3] = 0.f; } } while (0)
  for (int n = a0; n < a1; ++n) {
    int g = batch[n];
    if (g != curg) { NFLUSH(); curg = g; }
    unsigned v = *(const unsigned*)(hf8 + (size_t)n * 256 + lane * 4);
    float o[4]; unpack4_fp8(v, o);
    acc[0] += o[0]; acc[1] += o[1]; acc[2] += o[2]; acc[3] += o[3];
  }
  NFLUSH();
#undef NFLUSH
  __syncthreads();
  if (ldsok) {
    int ng = gmax - gmin + 1;
    for (int gi = 0; gi < ng; ++gi)
      unsafeAtomicAdd(&Y2[(size_t)(gmin + gi) * 256 + tid], gbuf[gi][tid]);
  }
}

// ---------------- final GEMM, split-K: out[g] += y_slice @ W_slice (+bias on ks==0) ----------------
__global__ void k_out2(const float* __restrict__ Y1, const float* __restrict__ Y2,
                       const float* __restrict__ W2l, const float* __restrict__ W2r,
                       const float* __restrict__ b2, const int* __restrict__ gstart,
                       float* __restrict__ out) {
  __shared__ float ys[128];
  int g = blockIdx.x, ks = blockIdx.y, t = threadIdx.x;
  const float* Ysrc = (ks < 2) ? Y1 : Y2;
  const float* Wsrc = (ks < 2) ? W2l : W2r;
  int kbase = (ks & 1) * 128;
  if (t < 128) ys[t] = Ysrc[(size_t)g * 256 + kbase + t];
  __syncthreads();
  float s = 0.f;
  const float* wp = Wsrc + (size_t)kbase * 256 + t;
#pragma unroll 8
  for (int k = 0; k < 128; ++k) s += ys[k] * wp[(size_t)k * 256];
  if (ks == 0) {
    float cntf = (float)(gstart[g + 1] - gstart[g]);
    s += b2[t] * cntf;
  }
  unsafeAtomicAdd(&out[(size_t)g * 256 + t], s);
}

extern "C" void kernel_launch(void* const* d_in, const int* in_sizes, int n_in,
                              void* d_out, int out_size, void* d_ws, size_t ws_size,
                              hipStream_t stream) {
  const float* x   = (const float*)d_in[0];
  const int*   ei  = (const int*)d_in[1];     // [2][NE] int32
  const int*   bat = (const int*)d_in[2];     // [NN] int32 (sorted)
  const float* W1l = (const float*)d_in[3];
  const float* b1  = (const float*)d_in[4];
  const float* W1r = (const float*)d_in[5];
  const float* W2l = (const float*)d_in[6];
  const float* b2  = (const float*)d_in[7];
  const float* W2r = (const float*)d_in[8];
  const int* src = ei;
  const int* dst = ei + NE;

  char* ws = (char*)d_ws;
  size_t off = 0;
  int* cnt     = (int*)(ws + off); off += ((size_t)NN * 4 + 255) & ~(size_t)255;
  int* rowptr  = (int*)(ws + off); off += ((size_t)(NN + 1) * 4 + 255) & ~(size_t)255;
  int* part    = (int*)(ws + off); off += 512 * 4;
  int* fill    = (int*)(ws + off); off += ((size_t)NN * 4 + 255) & ~(size_t)255;
  int* gstart  = (int*)(ws + off); off += ((size_t)(NG + 1) * 4 + 255) & ~(size_t)255;
  int* col     = (int*)(ws + off); off += (size_t)NE * 4;
  unsigned* wg = (unsigned*)(ws + off); off += (size_t)NE * 4;
  bf16_t* Bp1  = (bf16_t*)(ws + off); off += (size_t)256 * 256 * 2;
  float* Y1    = (float*)(ws + off); off += (size_t)NG * 256 * 4;
  float* Y2    = (float*)(ws + off); off += (size_t)NG * 256 * 4;
  bf16_t* xb   = (bf16_t*)(ws + off); off += (size_t)NN * DIN * 2;
  unsigned char* xf8 = (unsigned char*)(ws + off); off += (size_t)NN * DIN;
  bf16_t* ag1  = (bf16_t*)(ws + off); off += (size_t)NN * DIN * 2;
  unsigned char* hf8 = (unsigned char*)(ws + off); off += (size_t)NN * DH;

  hipMemsetAsync(cnt, 0, (size_t)NN * 4, stream);
  hipMemsetAsync(fill, 0, (size_t)NN * 4, stream);
  hipMemsetAsync(Y1, 0, (size_t)NG * 256 * 4 * 2, stream);   // Y1,Y2 contiguous
  hipMemsetAsync(d_out, 0, (size_t)out_size * 4, stream);
  k_xcast<<<NN * DIN / 8 / 256, 256, 0, stream>>>(x, xb, xf8);
  k_pack1<<<32, 256, 0, stream>>>(W1l, W1r, Bp1);
  k_count<<<(NE + 255) / 256, 256, 0, stream>>>(dst, cnt);
  k_scan1<<<NB1, 256, 0, stream>>>(cnt, rowptr, part);
  k_scan2<<<1, 512, 0, stream>>>(part);
  k_scan3<<<NB1, 256, 0, stream>>>(rowptr, part);
  k_gstart2<<<NB1, 256, 0, stream>>>(bat, rowptr, gstart, wg);
  k_bucket<<<BNB * 8, 256, 0, stream>>>(src, dst, rowptr, fill, col);
  k_agg1<<<NN / 4, 256, 0, stream>>>(rowptr, col, xf8, ag1);
  k_gemm1<<<(NN + 63) / 64, 256, 0, stream>>>(xb, ag1, b1, Bp1, hf8);
  k_poolE2<<<PEB, 256, 0, stream>>>(col, wg, hf8, Y1);
  k_poolN<<<PNB, 256, 0, stream>>>(bat, hf8, Y2);
  k_out2<<<dim3(NG, 4), 256, 0, stream>>>(Y1, Y2, W2l, W2r, b2, gstart, (float*)d_out);
}

// Round 10
// 202.073 us; speedup vs baseline: 28.5401x; 1.0361x over previous
//
#include <hip/hip_runtime.h>

#define NN 100000   // nodes
#define NE 640000   // edges
#define DIN 128
#define DH 256
#define DOUT 256
#define NG 256      // graphs
#define NB1 ((NN + 255) / 256)   // 391 blocks for scan

// edge pool geometry: wave per chunk
#define PECH 157                          // edges per wave
#define CPE (4 * PECH)                    // edges per block (628)
#define PEB ((NE + CPE - 1) / CPE)        // 1020 blocks
#define GSP 8                             // graphs per LDS slab

// node pool geometry
#define PNB 1024
#define CHN2 ((NN + PNB - 1) / PNB)       // 98 nodes/block

// bucket geometry: 8 XCD classes x edge chunks
#define BCH 4096
#define BNB ((NE + BCH - 1) / BCH)        // 157 chunks

// agg1 geometry: 8 nodes per wave
#define ANW 8
#define AGW ((NN + ANW - 1) / ANW)        // 12500 waves
#define AGB ((AGW + 3) / 4)               // 3125 blocks

typedef __bf16 bf16_t;
typedef __bf16 bf16x8 __attribute__((ext_vector_type(8)));
typedef float f32x4 __attribute__((ext_vector_type(4)));
typedef float f32v2 __attribute__((ext_vector_type(2)));

// ---------------- fp8 e4m3 pack/unpack (HW path; consistent-roundtrip) ----------------
#if __has_builtin(__builtin_amdgcn_cvt_pk_fp8_f32) && __has_builtin(__builtin_amdgcn_cvt_pk_f32_fp8)
#define USE_HW_FP8 1
#else
#define USE_HW_FP8 0
#endif

#if !USE_HW_FP8
__device__ __forceinline__ unsigned f32_to_fp8_1(float f) {  // signed e4m3fn
  unsigned sg = (__float_as_uint(f) >> 31) << 7;
  float af = fabsf(f);
  unsigned body;
  if (af < 0.015625f) {
    body = (unsigned)(int)rintf(af * 512.0f);
  } else {
    unsigned bits = __float_as_uint(af);
    unsigned rb = bits + 0x7FFFFu + ((bits >> 20) & 1u);
    unsigned e = rb >> 23;
    body = ((e - 120u) << 3) | ((rb >> 20) & 7u);
  }
  return (sg | body) & 0xffu;
}
__device__ __forceinline__ float fp8_to_f32_1(unsigned b) {
  unsigned s = b >> 7, e = (b >> 3) & 15u, m = b & 7u;
  float v = (e == 0) ? (float)m * 0.001953125f
                     : __uint_as_float(((e + 120u) << 23) | (m << 20));
  return s ? -v : v;
}
#endif

__device__ __forceinline__ unsigned pack4_fp8(float v0, float v1, float v2, float v3) {
#if USE_HW_FP8
  int u = __builtin_amdgcn_cvt_pk_fp8_f32(v0, v1, 0, false);
  u = __builtin_amdgcn_cvt_pk_fp8_f32(v2, v3, u, true);
  return (unsigned)u;
#else
  return f32_to_fp8_1(v0) | (f32_to_fp8_1(v1) << 8) |
         (f32_to_fp8_1(v2) << 16) | (f32_to_fp8_1(v3) << 24);
#endif
}

__device__ __forceinline__ unsigned short pack2_fp8(float v0, float v1) {
#if USE_HW_FP8
  int u = __builtin_amdgcn_cvt_pk_fp8_f32(v0, v1, 0, false);
  return (unsigned short)(u & 0xffff);
#else
  return (unsigned short)(f32_to_fp8_1(v0) | (f32_to_fp8_1(v1) << 8));
#endif
}

__device__ __forceinline__ void unpack4_fp8(unsigned v, float* o) {
#if USE_HW_FP8
  f32v2 a = __builtin_amdgcn_cvt_pk_f32_fp8((int)v, false);
  f32v2 b = __builtin_amdgcn_cvt_pk_f32_fp8((int)v, true);
  o[0] = a[0]; o[1] = a[1]; o[2] = b[0]; o[3] = b[1];
#else
  o[0] = fp8_to_f32_1(v & 0xffu);         o[1] = fp8_to_f32_1((v >> 8) & 0xffu);
  o[2] = fp8_to_f32_1((v >> 16) & 0xffu); o[3] = fp8_to_f32_1(v >> 24);
#endif
}

__device__ __forceinline__ void unpack8_fp8(uint2 v, float* o) {
  unpack4_fp8(v.x, o);
  unpack4_fp8(v.y, o + 4);
}

__device__ __forceinline__ void unpack2_fp8(unsigned v, float* o) {  // low 2 bytes
#if USE_HW_FP8
  f32v2 a = __builtin_amdgcn_cvt_pk_f32_fp8((int)v, false);
  o[0] = a[0]; o[1] = a[1];
#else
  o[0] = fp8_to_f32_1(v & 0xffu); o[1] = fp8_to_f32_1((v >> 8) & 0xffu);
#endif
}

// ---------------- x -> fp8 cast (row-major, 128B rows) ----------------
__global__ void k_xcast(const float* __restrict__ x, unsigned char* __restrict__ xf8) {
  size_t i = ((size_t)blockIdx.x * 256 + threadIdx.x) * 8;
  if (i >= (size_t)NN * DIN) return;
  float4 a = *(const float4*)(x + i), b = *(const float4*)(x + i + 4);
  uint2 p;
  p.x = pack4_fp8(a.x, a.y, a.z, a.w);
  p.y = pack4_fp8(b.x, b.y, b.z, b.w);
  *(uint2*)(xf8 + i) = p;
}

// ---------------- degree count ----------------
__global__ void k_count(const int* __restrict__ dst, int* __restrict__ cnt) {
  int e = blockIdx.x * 256 + threadIdx.x;
  if (e < NE) atomicAdd(&cnt[dst[e]], 1);
}

// ---------------- prefix scan (3 kernels): rowptr = exclusive_scan(cnt) ----------------
__global__ void k_scan1(const int* __restrict__ cnt, int* __restrict__ rowptr,
                        int* __restrict__ part) {
  __shared__ int s[256];
  int t = threadIdx.x, i = blockIdx.x * 256 + t;
  int v = (i < NN) ? cnt[i] : 0;
  s[t] = v; __syncthreads();
#pragma unroll
  for (int off = 1; off < 256; off <<= 1) {
    int u = (t >= off) ? s[t - off] : 0;
    __syncthreads();
    s[t] += u;
    __syncthreads();
  }
  if (i < NN) rowptr[i] = s[t] - v;
  if (t == 255) part[blockIdx.x] = s[255];
}

__global__ void k_scan2(int* __restrict__ part) {
  __shared__ int s[512];
  int t = threadIdx.x;
  int v = (t < NB1) ? part[t] : 0;
  s[t] = v; __syncthreads();
#pragma unroll
  for (int off = 1; off < 512; off <<= 1) {
    int u = (t >= off) ? s[t - off] : 0;
    __syncthreads();
    s[t] += u;
    __syncthreads();
  }
  if (t < NB1) part[t] = s[t] - v;
}

__global__ void k_scan3(int* __restrict__ rowptr, const int* __restrict__ part) {
  int i = blockIdx.x * 256 + threadIdx.x;
  if (i < NN) rowptr[i] += part[i >> 8];
  if (i == 0) rowptr[NN] = NE;
}

// ---------------- graph start index + per-edge (graph,deg) metadata ----------------
__global__ void k_gstart2(const int* __restrict__ batch, const int* __restrict__ rowptr,
                          int* __restrict__ gstart, unsigned* __restrict__ wg) {
  int n = blockIdx.x * 256 + threadIdx.x;
  if (n >= NN) return;
  int b = batch[n];
  int prev = (n == 0) ? -1 : batch[n - 1];
  for (int g = prev + 1; g <= b; ++g) gstart[g] = n;
  if (n == NN - 1) {
    for (int g = b + 1; g <= NG; ++g) gstart[g] = NN;
  }
  int e0 = rowptr[n], e1 = rowptr[n + 1];
  unsigned val = ((unsigned)b << 16) | (unsigned)(e1 - e0);
  for (int e = e0; e < e1; ++e) wg[e] = val;
}

// ---------------- bucket edges by dst, XCD-class partitioned (round-9 version) ----------------
__global__ void k_bucket(const int* __restrict__ src, const int* __restrict__ dst,
                         const int* __restrict__ rowptr, int* __restrict__ fill,
                         int* __restrict__ col) {
  int cls = blockIdx.x & 7;
  int cb = blockIdx.x >> 3;
  int e0 = cb * BCH;
  int e1 = (e0 + BCH < NE) ? e0 + BCH : NE;
  for (int e = e0 + threadIdx.x; e < e1; e += 256) {
    int d = dst[e];
    if (((d >> 4) & 7) == cls) {
      int p = rowptr[d] + atomicAdd(&fill[d], 1);
      col[p] = src[e];
    }
  }
}

// ---------------- gather-mean layer1: node-range edge-major, 8 loads in flight ----------------
// Wave owns nodes [wid*8, wid*8+8): flat loop over their CSR edge span with 8
// back-to-back row loads per iteration; flush (write fp8 mean row) on node change.
// All flush bookkeeping is wave-uniform (rowptr reads are uniform).
__global__ void k_agg1(const int* __restrict__ rowptr, const int* __restrict__ col,
                       const unsigned char* __restrict__ xf8, unsigned char* __restrict__ ag1f8) {
  int wid = (blockIdx.x * 256 + threadIdx.x) >> 6;
  int lane = threadIdx.x & 63;
  int n0 = wid * ANW;
  if (n0 >= NN) return;
  int n1 = n0 + ANW; if (n1 > NN) n1 = NN;
  int e = rowptr[n0];
  int eTot = rowptr[n1];
  int n = n0;
  int estart = e;
  int eend = rowptr[n0 + 1];
  float a0 = 0.f, a1 = 0.f;
#define AFLUSH()                                                              \
  do {                                                                        \
    float r = (eend > estart) ? __builtin_amdgcn_rcpf((float)(eend - estart)) \
                              : 0.f;                                          \
    *(unsigned short*)(ag1f8 + (size_t)n * DIN + lane * 2) =                  \
        pack2_fp8(a0 * r, a1 * r);                                            \
    a0 = 0.f; a1 = 0.f;                                                       \
    estart = eend; n++;                                                       \
    if (n < n1) eend = rowptr[n + 1];                                         \
  } while (0)
  while (e + 8 <= eTot) {
    unsigned v[8];
#pragma unroll
    for (int i = 0; i < 8; ++i) {
      int s = col[e + i];
      v[i] = *(const unsigned short*)(xf8 + (size_t)s * DIN + lane * 2);
    }
#pragma unroll
    for (int i = 0; i < 8; ++i) {
      while (e + i >= eend) AFLUSH();
      float o[2];
      unpack2_fp8(v[i], o);
      a0 += o[0]; a1 += o[1];
    }
    e += 8;
  }
  while (e < eTot) {
    int s = col[e];
    unsigned v = *(const unsigned short*)(xf8 + (size_t)s * DIN + lane * 2);
    while (e >= eend) AFLUSH();
    float o[2];
    unpack2_fp8(v, o);
    a0 += o[0]; a1 += o[1];
    ++e;
  }
  while (n < n1) AFLUSH();   // flush last accumulated node + trailing empty nodes
#undef AFLUSH
}

// ---------------- weight pack layer1 ----------------
__global__ void k_pack1(const float* __restrict__ Wl, const float* __restrict__ Wr,
                        bf16_t* __restrict__ Bp) {
  int t = blockIdx.x * 256 + threadIdx.x;   // 8 kc * 16 nt * 64 lanes = 8192
  if (t >= 8192) return;
  int lane = t & 63, nt = (t >> 6) & 15, kc = t >> 10;
  int n = nt * 16 + (lane & 15);
  int k0 = kc * 32 + (lane >> 4) * 8;
  bf16_t* o = Bp + ((size_t)(kc * 16 + nt) * 64 + lane) * 8;
  for (int j = 0; j < 8; ++j) {
    int k = k0 + j;
    float v = (k < 128) ? Wl[k * 256 + n] : Wr[(k - 128) * 256 + n];
    o[j] = (bf16_t)v;
  }
}

// ---------------- GEMM1: hf8 = fp8(relu([mean|x] @ [W1l;W1r] + b1)), K=256 ----------------
// A operands arrive as fp8 rows (ag1f8 | xf8); staged into LDS as bf16 with decode.
__launch_bounds__(256, 4)
__global__ void k_gemm1(const unsigned char* __restrict__ xf8,
                        const unsigned char* __restrict__ ag1f8,
                        const float* __restrict__ b1,
                        const bf16_t* __restrict__ Bp, unsigned char* __restrict__ hf8) {
  __shared__ unsigned char smem[64 * 512];   // A tile 64 x 256 bf16, XOR-swizzled
  int n0 = blockIdx.x * 64;
  int tid = threadIdx.x;
  {
    int row = tid >> 2, part = tid & 3;
    int node = n0 + row;
    unsigned sw = (row & 7) << 4;
    const uint2* ap = (const uint2*)(ag1f8 + (size_t)node * DIN);  // 16 chunks of 8 fp8
    const uint2* xp = (const uint2*)(xf8 + (size_t)node * DIN);
#pragma unroll
    for (int i = 0; i < 4; ++i) {
      int mi = i * 4 + part;                 // 0..15
      uint2 va = {0u, 0u}, vx = {0u, 0u};
      if (node < NN) { va = ap[mi]; vx = xp[mi]; }
      float oa[8], ox[8];
      unpack8_fp8(va, oa);
      unpack8_fp8(vx, ox);
      bf16x8 wa, wx;
#pragma unroll
      for (int j = 0; j < 8; ++j) { wa[j] = (bf16_t)oa[j]; wx[j] = (bf16_t)ox[j]; }
      *(bf16x8*)(smem + row * 512 + (((unsigned)(mi * 16)) ^ sw)) = wa;
      *(bf16x8*)(smem + row * 512 + ((unsigned)(256 + mi * 16) ^ sw)) = wx;
    }
  }
  __syncthreads();
  int wave = tid >> 6, lane = tid & 63, lhi = lane >> 4, llo = lane & 15;
  f32x4 acc[4][4] = {};
  const bf16x8* bptr = (const bf16x8*)Bp;
#pragma unroll
  for (int kc = 0; kc < 8; ++kc) {
    bf16x8 a[4], b[4];
#pragma unroll
    for (int mi = 0; mi < 4; ++mi) {
      int row = mi * 16 + llo;
      unsigned cb = ((unsigned)((kc * 32 + lhi * 8) * 2)) ^ ((row & 7) << 4);
      a[mi] = *(const bf16x8*)(smem + row * 512 + cb);
    }
#pragma unroll
    for (int ni = 0; ni < 4; ++ni)
      b[ni] = bptr[(kc * 16 + wave * 4 + ni) * 64 + lane];
#pragma unroll
    for (int mi = 0; mi < 4; ++mi)
#pragma unroll
      for (int ni = 0; ni < 4; ++ni)
        acc[mi][ni] = __builtin_amdgcn_mfma_f32_16x16x32_bf16(a[mi], b[ni], acc[mi][ni], 0, 0, 0);
  }
  float bias[4];
#pragma unroll
  for (int ni = 0; ni < 4; ++ni) bias[ni] = b1[wave * 64 + ni * 16 + llo];
#pragma unroll
  for (int mi = 0; mi < 4; ++mi)
#pragma unroll
    for (int j = 0; j < 4; ++j) {
      int node = n0 + mi * 16 + lhi * 4 + j;
      if (node < NN) {
        float v0 = fmaxf(acc[mi][0][j] + bias[0], 0.f);
        float v1 = fmaxf(acc[mi][1][j] + bias[1], 0.f);
        float v2 = fmaxf(acc[mi][2][j] + bias[2], 0.f);
        float v3 = fmaxf(acc[mi][3][j] + bias[3], 0.f);
        unsigned u = pack4_fp8(v0, v1, v2, v3);
        *(unsigned*)(hf8 + (size_t)node * 256 + wave * 64 + llo * 4) = u;
      }
    }
}

// ---------------- edge pool: Y1[g] += (1/deg_dst) * h[src]; wave/chunk, unroll-16 ----------------
__global__ void k_poolE2(const int* __restrict__ col, const unsigned* __restrict__ wg,
                         const unsigned char* __restrict__ hf8, float* __restrict__ Y1) {
  __shared__ float gbuf[GSP][256];
  int tid = threadIdx.x;
  int c0 = blockIdx.x * CPE;
  int c1 = (c0 + CPE < NE) ? c0 + CPE : NE;
  if (c0 >= c1) return;
  int gmin = (int)(wg[c0] >> 16), gmax = (int)(wg[c1 - 1] >> 16);
  bool ldsok = (gmax - gmin) < GSP;
  for (int i = tid; i < GSP * 256; i += 256) (&gbuf[0][0])[i] = 0.f;
  __syncthreads();
  int wv = tid >> 6, lane = tid & 63;
  int e0 = __builtin_amdgcn_readfirstlane(c0 + wv * PECH);
  int e1 = e0 + PECH; if (e1 > c1) e1 = c1;
  int dmb = ((lane >> 4) << 6) | (lane & 15);
  float acc[4] = {0.f, 0.f, 0.f, 0.f};
  int curg = -1;
#define EFLUSH() do { if (curg >= 0) {                                        \
    if (ldsok) { float* gp = gbuf[curg - gmin];                               \
      atomicAdd(gp + (dmb | 0),  acc[0]); atomicAdd(gp + (dmb | 16), acc[1]); \
      atomicAdd(gp + (dmb | 32), acc[2]); atomicAdd(gp + (dmb | 48), acc[3]); \
    } else { float* yp = Y1 + (size_t)curg * 256;                             \
      unsafeAtomicAdd(yp + (dmb | 0),  acc[0]);                               \
      unsafeAtomicAdd(yp + (dmb | 16), acc[1]);                               \
      unsafeAtomicAdd(yp + (dmb | 32), acc[2]);                               \
      unsafeAtomicAdd(yp + (dmb | 48), acc[3]); }                             \
    acc[0] = acc[1] = acc[2] = acc[3] = 0.f; } } while (0)
  if (e0 < e1) {
    int e = e0;
    for (; e + 16 <= e1; e += 16) {
      unsigned wvv[16]; unsigned hv[16];
#pragma unroll
      for (int i = 0; i < 16; ++i) {
        int c = col[e + i];
        wvv[i] = wg[e + i];
        hv[i] = *(const unsigned*)(hf8 + (size_t)c * 256 + lane * 4);
      }
#pragma unroll
      for (int i = 0; i < 16; ++i) {
        int g = (int)(wvv[i] >> 16);
        if (g != curg) { EFLUSH(); curg = g; }
        float w = __builtin_amdgcn_rcpf((float)(wvv[i] & 0xffffu));
        float o[4]; unpack4_fp8(hv[i], o);
        acc[0] += w * o[0]; acc[1] += w * o[1];
        acc[2] += w * o[2]; acc[3] += w * o[3];
      }
    }
    for (; e < e1; ++e) {
      int c = col[e]; unsigned wv2 = wg[e];
      unsigned hvv = *(const unsigned*)(hf8 + (size_t)c * 256 + lane * 4);
      int g = (int)(wv2 >> 16);
      if (g != curg) { EFLUSH(); curg = g; }
      float w = __builtin_amdgcn_rcpf((float)(wv2 & 0xffffu));
      float o[4]; unpack4_fp8(hvv, o);
      acc[0] += w * o[0]; acc[1] += w * o[1];
      acc[2] += w * o[2]; acc[3] += w * o[3];
    }
    EFLUSH();
  }
#undef EFLUSH
  __syncthreads();
  if (ldsok) {
    int ng = gmax - gmin + 1;
    for (int gi = 0; gi < ng; ++gi)
      unsafeAtomicAdd(&Y1[(size_t)(gmin + gi) * 256 + tid], gbuf[gi][tid]);
  }
}

// ---------------- node pool: Y2[g] += h[n]; wave sub-ranges, LDS slab ----------------
__global__ void k_poolN(const int* __restrict__ batch, const unsigned char* __restrict__ hf8,
                        float* __restrict__ Y2) {
  __shared__ float gbuf[GSP][256];
  int tid = threadIdx.x;
  int n0 = blockIdx.x * CHN2;
  int n1 = (n0 + CHN2 < NN) ? n0 + CHN2 : NN;
  if (n0 >= n1) return;
  int gmin = batch[n0], gmax = batch[n1 - 1];
  bool ldsok = (gmax - gmin) < GSP;
  for (int i = tid; i < GSP * 256; i += 256) (&gbuf[0][0])[i] = 0.f;
  __syncthreads();
  int wv = tid >> 6, lane = tid & 63;
  const int per = (CHN2 + 3) >> 2;          // 25 nodes per wave
  int a0 = n0 + wv * per;
  int a1 = a0 + per; if (a1 > n1) a1 = n1;
  int dmb = ((lane >> 4) << 6) | (lane & 15);
  float acc[4] = {0.f, 0.f, 0.f, 0.f};
  int curg = -1;
#define NFLUSH() do { if (curg >= 0) {                                        \
    if (ldsok) { float* gp = gbuf[curg - gmin];                               \
      atomicAdd(gp + (dmb | 0),  acc[0]); atomicAdd(gp + (dmb | 16), acc[1]); \
      atomicAdd(gp + (dmb | 32), acc[2]); atomicAdd(gp + (dmb | 48), acc[3]); \
    } else { float* yp = Y2 + (size_t)curg * 256;                             \
      unsafeAtomicAdd(yp + (dmb | 0),  acc[0]);                               \
      unsafeAtomicAdd(yp + (dmb | 16), acc[1]);                               \
      unsafeAtomicAdd(yp + (dmb | 32), acc[2]);                               \
      unsafeAtomicAdd(yp + (dmb | 48), acc[3]); }                             \
    acc[0] = acc[1] = acc[2] = acc[3] = 0.f; } } while (0)
  for (int n = a0; n < a1; ++n) {
    int g = batch[n];
    if (g != curg) { NFLUSH(); curg = g; }
    unsigned v = *(const unsigned*)(hf8 + (size_t)n * 256 + lane * 4);
    float o[4]; unpack4_fp8(v, o);
    acc[0] += o[0]; acc[1] += o[1]; acc[2] += o[2]; acc[3] += o[3];
  }
  NFLUSH();
#undef NFLUSH
  __syncthreads();
  if (ldsok) {
    int ng = gmax - gmin + 1;
    for (int gi = 0; gi < ng; ++gi)
      unsafeAtomicAdd(&Y2[(size_t)(gmin + gi) * 256 + tid], gbuf[gi][tid]);
  }
}

// ---------------- final GEMM, split-K: out[g] += y_slice @ W_slice (+bias on ks==0) ----------------
__global__ void k_out2(const float* __restrict__ Y1, const float* __restrict__ Y2,
                       const float* __restrict__ W2l, const float* __restrict__ W2r,
                       const float* __restrict__ b2, const int* __restrict__ gstart,
                       float* __restrict__ out) {
  __shared__ float ys[128];
  int g = blockIdx.x, ks = blockIdx.y, t = threadIdx.x;
  const float* Ysrc = (ks < 2) ? Y1 : Y2;
  const float* Wsrc = (ks < 2) ? W2l : W2r;
  int kbase = (ks & 1) * 128;
  if (t < 128) ys[t] = Ysrc[(size_t)g * 256 + kbase + t];
  __syncthreads();
  float s = 0.f;
  const float* wp = Wsrc + (size_t)kbase * 256 + t;
#pragma unroll 8
  for (int k = 0; k < 128; ++k) s += ys[k] * wp[(size_t)k * 256];
  if (ks == 0) {
    float cntf = (float)(gstart[g + 1] - gstart[g]);
    s += b2[t] * cntf;
  }
  unsafeAtomicAdd(&out[(size_t)g * 256 + t], s);
}

extern "C" void kernel_launch(void* const* d_in, const int* in_sizes, int n_in,
                              void* d_out, int out_size, void* d_ws, size_t ws_size,
                              hipStream_t stream) {
  const float* x   = (const float*)d_in[0];
  const int*   ei  = (const int*)d_in[1];     // [2][NE] int32
  const int*   bat = (const int*)d_in[2];     // [NN] int32 (sorted)
  const float* W1l = (const float*)d_in[3];
  const float* b1  = (const float*)d_in[4];
  const float* W1r = (const float*)d_in[5];
  const float* W2l = (const float*)d_in[6];
  const float* b2  = (const float*)d_in[7];
  const float* W2r = (const float*)d_in[8];
  const int* src = ei;
  const int* dst = ei + NE;

  char* ws = (char*)d_ws;
  size_t off = 0;
  int* cnt     = (int*)(ws + off); off += ((size_t)NN * 4 + 255) & ~(size_t)255;
  int* rowptr  = (int*)(ws + off); off += ((size_t)(NN + 1) * 4 + 255) & ~(size_t)255;
  int* part    = (int*)(ws + off); off += 512 * 4;
  int* fill    = (int*)(ws + off); off += ((size_t)NN * 4 + 255) & ~(size_t)255;
  int* gstart  = (int*)(ws + off); off += ((size_t)(NG + 1) * 4 + 255) & ~(size_t)255;
  int* col     = (int*)(ws + off); off += (size_t)NE * 4;
  unsigned* wg = (unsigned*)(ws + off); off += (size_t)NE * 4;
  bf16_t* Bp1  = (bf16_t*)(ws + off); off += (size_t)256 * 256 * 2;
  float* Y1    = (float*)(ws + off); off += (size_t)NG * 256 * 4;
  float* Y2    = (float*)(ws + off); off += (size_t)NG * 256 * 4;
  unsigned char* xf8 = (unsigned char*)(ws + off); off += (size_t)NN * DIN;
  unsigned char* ag1f8 = (unsigned char*)(ws + off); off += (size_t)NN * DIN;
  unsigned char* hf8 = (unsigned char*)(ws + off); off += (size_t)NN * DH;

  hipMemsetAsync(cnt, 0, (size_t)NN * 4, stream);
  hipMemsetAsync(fill, 0, (size_t)NN * 4, stream);
  hipMemsetAsync(Y1, 0, (size_t)NG * 256 * 4 * 2, stream);   // Y1,Y2 contiguous
  hipMemsetAsync(d_out, 0, (size_t)out_size * 4, stream);
  k_xcast<<<NN * DIN / 8 / 256, 256, 0, stream>>>(x, xf8);
  k_pack1<<<32, 256, 0, stream>>>(W1l, W1r, Bp1);
  k_count<<<(NE + 255) / 256, 256, 0, stream>>>(dst, cnt);
  k_scan1<<<NB1, 256, 0, stream>>>(cnt, rowptr, part);
  k_scan2<<<1, 512, 0, stream>>>(part);
  k_scan3<<<NB1, 256, 0, stream>>>(rowptr, part);
  k_gstart2<<<NB1, 256, 0, stream>>>(bat, rowptr, gstart, wg);
  k_bucket<<<BNB * 8, 256, 0, stream>>>(src, dst, rowptr, fill, col);
  k_agg1<<<AGB, 256, 0, stream>>>(rowptr, col, xf8, ag1f8);
  k_gemm1<<<(NN + 63) / 64, 256, 0, stream>>>(xf8, ag1f8, b1, Bp1, hf8);
  k_poolE2<<<PEB, 256, 0, stream>>>(col, wg, hf8, Y1);
  k_poolN<<<PNB, 256, 0, stream>>>(bat, hf8, Y2);
  k_out2<<<dim3(NG, 4), 256, 0, stream>>>(Y1, Y2, W2l, W2r, b2, gstart, (float*)d_out);
}

// Round 11
// 185.370 us; speedup vs baseline: 31.1117x; 1.0901x over previous
//
#include <hip/hip_runtime.h>

#define NN 100000   // nodes
#define NE 640000   // edges
#define DIN 128
#define DH 256
#define DOUT 256
#define NG 256      // graphs
#define NB1 ((NN + 255) / 256)   // 391 blocks for node-indexed kernels

// edge pool geometry: wave per chunk
#define PECH 157                          // edges per wave
#define CPE (4 * PECH)                    // edges per block (628)
#define PEB ((NE + CPE - 1) / CPE)        // 1020 blocks
#define GSP 8                             // graphs per LDS slab

// node pool geometry
#define PNB 1024
#define CHN2 ((NN + PNB - 1) / PNB)       // 98 nodes/block

// bucket geometry: 8 XCD classes x edge chunks
#define BCH 4096
#define BNB ((NE + BCH - 1) / BCH)        // 157 chunks

// fused-pre geometry
#define XCB (NN * DIN / 8 / 256)          // 6250 xcast blocks
#define CTB ((NE + 255) / 256)            // 2500 count blocks

typedef __bf16 bf16_t;
typedef __bf16 bf16x8 __attribute__((ext_vector_type(8)));
typedef __bf16 bf16x2 __attribute__((ext_vector_type(2)));
typedef float f32x4 __attribute__((ext_vector_type(4)));
typedef float f32v2 __attribute__((ext_vector_type(2)));

// ---------------- fp8 e4m3 pack/unpack (HW path; consistent-roundtrip) ----------------
#if __has_builtin(__builtin_amdgcn_cvt_pk_fp8_f32) && __has_builtin(__builtin_amdgcn_cvt_pk_f32_fp8)
#define USE_HW_FP8 1
#else
#define USE_HW_FP8 0
#endif

#if !USE_HW_FP8
__device__ __forceinline__ unsigned f32_to_fp8_1(float f) {  // signed e4m3fn
  unsigned sg = (__float_as_uint(f) >> 31) << 7;
  float af = fabsf(f);
  unsigned body;
  if (af < 0.015625f) {
    body = (unsigned)(int)rintf(af * 512.0f);
  } else {
    unsigned bits = __float_as_uint(af);
    unsigned rb = bits + 0x7FFFFu + ((bits >> 20) & 1u);
    unsigned e = rb >> 23;
    body = ((e - 120u) << 3) | ((rb >> 20) & 7u);
  }
  return (sg | body) & 0xffu;
}
__device__ __forceinline__ float fp8_to_f32_1(unsigned b) {
  unsigned s = b >> 7, e = (b >> 3) & 15u, m = b & 7u;
  float v = (e == 0) ? (float)m * 0.001953125f
                     : __uint_as_float(((e + 120u) << 23) | (m << 20));
  return s ? -v : v;
}
#endif

__device__ __forceinline__ unsigned pack4_fp8(float v0, float v1, float v2, float v3) {
#if USE_HW_FP8
  int u = __builtin_amdgcn_cvt_pk_fp8_f32(v0, v1, 0, false);
  u = __builtin_amdgcn_cvt_pk_fp8_f32(v2, v3, u, true);
  return (unsigned)u;
#else
  return f32_to_fp8_1(v0) | (f32_to_fp8_1(v1) << 8) |
         (f32_to_fp8_1(v2) << 16) | (f32_to_fp8_1(v3) << 24);
#endif
}

__device__ __forceinline__ void unpack4_fp8(unsigned v, float* o) {
#if USE_HW_FP8
  f32v2 a = __builtin_amdgcn_cvt_pk_f32_fp8((int)v, false);
  f32v2 b = __builtin_amdgcn_cvt_pk_f32_fp8((int)v, true);
  o[0] = a[0]; o[1] = a[1]; o[2] = b[0]; o[3] = b[1];
#else
  o[0] = fp8_to_f32_1(v & 0xffu);         o[1] = fp8_to_f32_1((v >> 8) & 0xffu);
  o[2] = fp8_to_f32_1((v >> 16) & 0xffu); o[3] = fp8_to_f32_1(v >> 24);
#endif
}

__device__ __forceinline__ void unpack2_fp8(unsigned v, float* o) {  // low 2 bytes
#if USE_HW_FP8
  f32v2 a = __builtin_amdgcn_cvt_pk_f32_fp8((int)v, false);
  o[0] = a[0]; o[1] = a[1];
#else
  o[0] = fp8_to_f32_1(v & 0xffu); o[1] = fp8_to_f32_1((v >> 8) & 0xffu);
#endif
}

// ---------------- fused pre: xcast || degree-count || weight-pack ----------------
__global__ void k_pre(const float* __restrict__ x, const int* __restrict__ dst,
                      const float* __restrict__ Wl, const float* __restrict__ Wr,
                      unsigned char* __restrict__ xf8, int* __restrict__ cnt,
                      bf16_t* __restrict__ Bp) {
  int b = blockIdx.x;
  if (b < XCB) {                         // x -> fp8 (row-major 128B rows)
    size_t i = ((size_t)b * 256 + threadIdx.x) * 8;
    float4 a = *(const float4*)(x + i), c = *(const float4*)(x + i + 4);
    uint2 p;
    p.x = pack4_fp8(a.x, a.y, a.z, a.w);
    p.y = pack4_fp8(c.x, c.y, c.z, c.w);
    *(uint2*)(xf8 + i) = p;
  } else if (b < XCB + CTB) {            // in-degree count
    int e = (b - XCB) * 256 + threadIdx.x;
    if (e < NE) atomicAdd(&cnt[dst[e]], 1);
  } else {                               // weight pack: MFMA b-frag order bf16
    int t = (b - XCB - CTB) * 256 + threadIdx.x;   // 0..8191
    if (t < 8192) {
      int lane = t & 63, nt = (t >> 6) & 15, kc = t >> 10;
      int n = nt * 16 + (lane & 15);
      int k0 = kc * 32 + (lane >> 4) * 8;
      bf16_t* o = Bp + ((size_t)(kc * 16 + nt) * 64 + lane) * 8;
      for (int j = 0; j < 8; ++j) {
        int k = k0 + j;
        float v = (k < 128) ? Wl[k * 256 + n] : Wr[(k - 128) * 256 + n];
        o[j] = (bf16_t)v;
      }
    }
  }
}

// ---------------- scan stage 1: block-local exclusive scan of cnt -> rpl, part ----------------
__global__ void k_scan1(const int* __restrict__ cnt, int* __restrict__ rpl,
                        int* __restrict__ part) {
  __shared__ int s[256];
  int t = threadIdx.x, i = blockIdx.x * 256 + t;
  int v = (i < NN) ? cnt[i] : 0;
  s[t] = v; __syncthreads();
#pragma unroll
  for (int off = 1; off < 256; off <<= 1) {
    int u = (t >= off) ? s[t - off] : 0;
    __syncthreads();
    s[t] += u;
    __syncthreads();
  }
  if (i < NN) rpl[i] = s[t] - v;
  if (t == 255) part[blockIdx.x] = s[255];
}

__global__ void k_scan2(int* __restrict__ part) {
  __shared__ int s[512];
  int t = threadIdx.x;
  int v = (t < NB1) ? part[t] : 0;
  s[t] = v; __syncthreads();
#pragma unroll
  for (int off = 1; off < 512; off <<= 1) {
    int u = (t >= off) ? s[t - off] : 0;
    __syncthreads();
    s[t] += u;
    __syncthreads();
  }
  if (t < NB1) part[t] = s[t] - v;
}

// ---------------- fused finish: final rowptr + gstart + per-edge (g,deg) metadata ----------------
// Writes final rowptr to a SEPARATE buffer (no race with rpl reads).
__global__ void k_finish(const int* __restrict__ rpl, const int* __restrict__ part,
                         const int* __restrict__ batch, int* __restrict__ rowptr,
                         int* __restrict__ gstart, unsigned* __restrict__ wg) {
  int n = blockIdx.x * 256 + threadIdx.x;
  if (n >= NN) return;
  int r0 = rpl[n] + part[n >> 8];
  int r1 = (n + 1 < NN) ? (rpl[n + 1] + part[(n + 1) >> 8]) : NE;
  rowptr[n] = r0;
  if (n == 0) rowptr[NN] = NE;
  int b = batch[n];
  int prev = (n == 0) ? -1 : batch[n - 1];
  for (int g = prev + 1; g <= b; ++g) gstart[g] = n;
  if (n == NN - 1) {
    for (int g = b + 1; g <= NG; ++g) gstart[g] = NN;
  }
  unsigned val = ((unsigned)b << 16) | (unsigned)(r1 - r0);
  for (int e = r0; e < r1; ++e) wg[e] = val;
}

// ---------------- bucket edges by dst, XCD-class partitioned ----------------
__global__ void k_bucket(const int* __restrict__ src, const int* __restrict__ dst,
                         const int* __restrict__ rowptr, int* __restrict__ fill,
                         int* __restrict__ col) {
  int cls = blockIdx.x & 7;
  int cb = blockIdx.x >> 3;
  int e0 = cb * BCH;
  int e1 = (e0 + BCH < NE) ? e0 + BCH : NE;
  for (int e = e0 + threadIdx.x; e < e1; e += 256) {
    int d = dst[e];
    if (((d >> 4) & 7) == cls) {
      int p = rowptr[d] + atomicAdd(&fill[d], 1);
      col[p] = src[e];
    }
  }
}

// ---------------- GEMM1 + fused gather-mean: hf8 = fp8(relu([mean|x]@[W1l;W1r]+b1)) ----------------
// Each wave gather-means its 16 nodes (8-deep edge pipeline, 2B/lane) writing bf16
// means directly into the LDS A-tile, then copies the direct-x half; MFMA follows.
__launch_bounds__(256, 4)
__global__ void k_gemm1(const unsigned char* __restrict__ xf8,
                        const int* __restrict__ rowptr, const int* __restrict__ col,
                        const float* __restrict__ b1,
                        const bf16_t* __restrict__ Bp, unsigned char* __restrict__ hf8) {
  __shared__ unsigned char smem[64 * 512];   // A tile 64 x 256 bf16, XOR-swizzled
  int n0 = blockIdx.x * 64;
  int tid = threadIdx.x;
  int wave = tid >> 6, lane = tid & 63;
  {
    int base = __builtin_amdgcn_readfirstlane(n0 + wave * 16);
    int nb1 = base + 16; if (nb1 > NN) nb1 = NN;
    if (base < NN) {
      int e = rowptr[base];
      int eTot = rowptr[nb1];
      int n = base;
      int estart = e;
      int eend = rowptr[n + 1];
      float a0 = 0.f, a1 = 0.f;
#define GFLUSH()                                                               \
      do {                                                                     \
        float r = (eend > estart)                                              \
                    ? __builtin_amdgcn_rcpf((float)(eend - estart)) : 0.f;     \
        int row = n - n0;                                                      \
        unsigned sw = (row & 7) << 4;                                          \
        bf16x2 mv; mv[0] = (bf16_t)(a0 * r); mv[1] = (bf16_t)(a1 * r);         \
        *(bf16x2*)(smem + row * 512 + (((unsigned)(lane * 4)) ^ sw)) = mv;     \
        a0 = 0.f; a1 = 0.f;                                                    \
        estart = eend; ++n;                                                    \
        if (n < nb1) eend = rowptr[n + 1];                                     \
      } while (0)
      while (e + 8 <= eTot) {
        unsigned v[8];
#pragma unroll
        for (int i = 0; i < 8; ++i) {
          int s = col[e + i];
          v[i] = *(const unsigned short*)(xf8 + (size_t)s * DIN + lane * 2);
        }
#pragma unroll
        for (int i = 0; i < 8; ++i) {
          while (e + i >= eend) GFLUSH();
          float o[2]; unpack2_fp8(v[i], o);
          a0 += o[0]; a1 += o[1];
        }
        e += 8;
      }
      while (e < eTot) {
        int s = col[e];
        unsigned v = *(const unsigned short*)(xf8 + (size_t)s * DIN + lane * 2);
        while (e >= eend) GFLUSH();
        float o[2]; unpack2_fp8(v, o);
        a0 += o[0]; a1 += o[1];
        ++e;
      }
      while (n < nb1) GFLUSH();
#undef GFLUSH
    }
    // direct-x half (byte cols 256..511), fp8 -> bf16 decode
#pragma unroll
    for (int i = 0; i < 16; ++i) {
      int node = base + i;
      int row = wave * 16 + i;
      unsigned sw = (row & 7) << 4;
      unsigned v = 0;
      if (node < NN) v = *(const unsigned short*)(xf8 + (size_t)node * DIN + lane * 2);
      float o[2]; unpack2_fp8(v, o);
      bf16x2 xv; xv[0] = (bf16_t)o[0]; xv[1] = (bf16_t)o[1];
      *(bf16x2*)(smem + row * 512 + ((unsigned)(256 + lane * 4) ^ sw)) = xv;
    }
  }
  __syncthreads();
  int lhi = lane >> 4, llo = lane & 15;
  f32x4 acc[4][4] = {};
  const bf16x8* bptr = (const bf16x8*)Bp;
#pragma unroll
  for (int kc = 0; kc < 8; ++kc) {
    bf16x8 a[4], b[4];
#pragma unroll
    for (int mi = 0; mi < 4; ++mi) {
      int row = mi * 16 + llo;
      unsigned cb = ((unsigned)((kc * 32 + lhi * 8) * 2)) ^ ((row & 7) << 4);
      a[mi] = *(const bf16x8*)(smem + row * 512 + cb);
    }
#pragma unroll
    for (int ni = 0; ni < 4; ++ni)
      b[ni] = bptr[(kc * 16 + wave * 4 + ni) * 64 + lane];
#pragma unroll
    for (int mi = 0; mi < 4; ++mi)
#pragma unroll
      for (int ni = 0; ni < 4; ++ni)
        acc[mi][ni] = __builtin_amdgcn_mfma_f32_16x16x32_bf16(a[mi], b[ni], acc[mi][ni], 0, 0, 0);
  }
  float bias[4];
#pragma unroll
  for (int ni = 0; ni < 4; ++ni) bias[ni] = b1[wave * 64 + ni * 16 + llo];
#pragma unroll
  for (int mi = 0; mi < 4; ++mi)
#pragma unroll
    for (int j = 0; j < 4; ++j) {
      int node = n0 + mi * 16 + lhi * 4 + j;
      if (node < NN) {
        float v0 = fmaxf(acc[mi][0][j] + bias[0], 0.f);
        float v1 = fmaxf(acc[mi][1][j] + bias[1], 0.f);
        float v2 = fmaxf(acc[mi][2][j] + bias[2], 0.f);
        float v3 = fmaxf(acc[mi][3][j] + bias[3], 0.f);
        unsigned u = pack4_fp8(v0, v1, v2, v3);
        *(unsigned*)(hf8 + (size_t)node * 256 + wave * 64 + llo * 4) = u;
      }
    }
}

// ---------------- fused pool: edge pool (Y1) || node pool (Y2) ----------------
__global__ void k_pool(const int* __restrict__ col, const unsigned* __restrict__ wg,
                       const int* __restrict__ batch, const unsigned char* __restrict__ hf8,
                       float* __restrict__ Y1, float* __restrict__ Y2) {
  __shared__ float gbuf[GSP][256];
  int tid = threadIdx.x;
  int wv = tid >> 6, lane = tid & 63;
  int dmb = ((lane >> 4) << 6) | (lane & 15);
  float acc[4] = {0.f, 0.f, 0.f, 0.f};
  int curg = -1;
  if (blockIdx.x < PEB) {
    // ---- edge pool: Y1[g] += (1/deg_dst) * h[src]; wave/chunk, unroll-16 ----
    int c0 = blockIdx.x * CPE;
    int c1 = (c0 + CPE < NE) ? c0 + CPE : NE;
    if (c0 >= c1) return;
    int gmin = (int)(wg[c0] >> 16), gmax = (int)(wg[c1 - 1] >> 16);
    bool ldsok = (gmax - gmin) < GSP;
    for (int i = tid; i < GSP * 256; i += 256) (&gbuf[0][0])[i] = 0.f;
    __syncthreads();
    int e0 = __builtin_amdgcn_readfirstlane(c0 + wv * PECH);
    int e1 = e0 + PECH; if (e1 > c1) e1 = c1;
#define EFLUSH() do { if (curg >= 0) {                                        \
    if (ldsok) { float* gp = gbuf[curg - gmin];                               \
      atomicAdd(gp + (dmb | 0),  acc[0]); atomicAdd(gp + (dmb | 16), acc[1]); \
      atomicAdd(gp + (dmb | 32), acc[2]); atomicAdd(gp + (dmb | 48), acc[3]); \
    } else { float* yp = Y1 + (size_t)curg * 256;                             \
      unsafeAtomicAdd(yp + (dmb | 0),  acc[0]);                               \
      unsafeAtomicAdd(yp + (dmb | 16), acc[1]);                               \
      unsafeAtomicAdd(yp + (dmb | 32), acc[2]);                               \
      unsafeAtomicAdd(yp + (dmb | 48), acc[3]); }                             \
    acc[0] = acc[1] = acc[2] = acc[3] = 0.f; } } while (0)
    if (e0 < e1) {
      int e = e0;
      for (; e + 16 <= e1; e += 16) {
        unsigned wvv[16]; unsigned hv[16];
#pragma unroll
        for (int i = 0; i < 16; ++i) {
          int c = col[e + i];
          wvv[i] = wg[e + i];
          hv[i] = *(const unsigned*)(hf8 + (size_t)c * 256 + lane * 4);
        }
#pragma unroll
        for (int i = 0; i < 16; ++i) {
          int g = (int)(wvv[i] >> 16);
          if (g != curg) { EFLUSH(); curg = g; }
          float w = __builtin_amdgcn_rcpf((float)(wvv[i] & 0xffffu));
          float o[4]; unpack4_fp8(hv[i], o);
          acc[0] += w * o[0]; acc[1] += w * o[1];
          acc[2] += w * o[2]; acc[3] += w * o[3];
        }
      }
      for (; e < e1; ++e) {
        int c = col[e]; unsigned wv2 = wg[e];
        unsigned hvv = *(const unsigned*)(hf8 + (size_t)c * 256 + lane * 4);
        int g = (int)(wv2 >> 16);
        if (g != curg) { EFLUSH(); curg = g; }
        float w = __builtin_amdgcn_rcpf((float)(wv2 & 0xffffu));
        float o[4]; unpack4_fp8(hvv, o);
        acc[0] += w * o[0]; acc[1] += w * o[1];
        acc[2] += w * o[2]; acc[3] += w * o[3];
      }
      EFLUSH();
    }
#undef EFLUSH
    __syncthreads();
    if (ldsok) {
      int ng = gmax - gmin + 1;
      for (int gi = 0; gi < ng; ++gi)
        unsafeAtomicAdd(&Y1[(size_t)(gmin + gi) * 256 + tid], gbuf[gi][tid]);
    }
  } else {
    // ---- node pool: Y2[g] += h[n]; wave sub-ranges ----
    int nb = blockIdx.x - PEB;
    int n0 = nb * CHN2;
    int n1 = (n0 + CHN2 < NN) ? n0 + CHN2 : NN;
    if (n0 >= n1) return;
    int gmin = batch[n0], gmax = batch[n1 - 1];
    bool ldsok = (gmax - gmin) < GSP;
    for (int i = tid; i < GSP * 256; i += 256) (&gbuf[0][0])[i] = 0.f;
    __syncthreads();
    const int per = (CHN2 + 3) >> 2;          // 25 nodes per wave
    int a0 = n0 + wv * per;
    int a1 = a0 + per; if (a1 > n1) a1 = n1;
#define NFLUSH() do { if (curg >= 0) {                                        \
    if (ldsok) { float* gp = gbuf[curg - gmin];                               \
      atomicAdd(gp + (dmb | 0),  acc[0]); atomicAdd(gp + (dmb | 16), acc[1]); \
      atomicAdd(gp + (dmb | 32), acc[2]); atomicAdd(gp + (dmb | 48), acc[3]); \
    } else { float* yp = Y2 + (size_t)curg * 256;                             \
      unsafeAtomicAdd(yp + (dmb | 0),  acc[0]);                               \
      unsafeAtomicAdd(yp + (dmb | 16), acc[1]);                               \
      unsafeAtomicAdd(yp + (dmb | 32), acc[2]);                               \
      unsafeAtomicAdd(yp + (dmb | 48), acc[3]); }                             \
    acc[0] = acc[1] = acc[2] = acc[3] = 0.f; } } while (0)
    for (int n = a0; n < a1; ++n) {
      int g = batch[n];
      if (g != curg) { NFLUSH(); curg = g; }
      unsigned v = *(const unsigned*)(hf8 + (size_t)n * 256 + lane * 4);
      float o[4]; unpack4_fp8(v, o);
      acc[0] += o[0]; acc[1] += o[1]; acc[2] += o[2]; acc[3] += o[3];
    }
    NFLUSH();
#undef NFLUSH
    __syncthreads();
    if (ldsok) {
      int ng = gmax - gmin + 1;
      for (int gi = 0; gi < ng; ++gi)
        unsafeAtomicAdd(&Y2[(size_t)(gmin + gi) * 256 + tid], gbuf[gi][tid]);
    }
  }
}

// ---------------- final GEMM, split-K: out[g] += y_slice @ W_slice (+bias on ks==0) ----------------
__global__ void k_out2(const float* __restrict__ Y1, const float* __restrict__ Y2,
                       const float* __restrict__ W2l, const float* __restrict__ W2r,
                       const float* __restrict__ b2, const int* __restrict__ gstart,
                       float* __restrict__ out) {
  __shared__ float ys[128];
  int g = blockIdx.x, ks = blockIdx.y, t = threadIdx.x;
  const float* Ysrc = (ks < 2) ? Y1 : Y2;
  const float* Wsrc = (ks < 2) ? W2l : W2r;
  int kbase = (ks & 1) * 128;
  if (t < 128) ys[t] = Ysrc[(size_t)g * 256 + kbase + t];
  __syncthreads();
  float s = 0.f;
  const float* wp = Wsrc + (size_t)kbase * 256 + t;
#pragma unroll 8
  for (int k = 0; k < 128; ++k) s += ys[k] * wp[(size_t)k * 256];
  if (ks == 0) {
    float cntf = (float)(gstart[g + 1] - gstart[g]);
    s += b2[t] * cntf;
  }
  unsafeAtomicAdd(&out[(size_t)g * 256 + t], s);
}

extern "C" void kernel_launch(void* const* d_in, const int* in_sizes, int n_in,
                              void* d_out, int out_size, void* d_ws, size_t ws_size,
                              hipStream_t stream) {
  const float* x   = (const float*)d_in[0];
  const int*   ei  = (const int*)d_in[1];     // [2][NE] int32
  const int*   bat = (const int*)d_in[2];     // [NN] int32 (sorted)
  const float* W1l = (const float*)d_in[3];
  const float* b1  = (const float*)d_in[4];
  const float* W1r = (const float*)d_in[5];
  const float* W2l = (const float*)d_in[6];
  const float* b2  = (const float*)d_in[7];
  const float* W2r = (const float*)d_in[8];
  const int* src = ei;
  const int* dst = ei + NE;

  char* ws = (char*)d_ws;
  size_t off = 0;
  int* cnt     = (int*)(ws + off); off += ((size_t)NN * 4 + 255) & ~(size_t)255;
  int* rpl     = (int*)(ws + off); off += ((size_t)(NN + 1) * 4 + 255) & ~(size_t)255;
  int* rowptr  = (int*)(ws + off); off += ((size_t)(NN + 1) * 4 + 255) & ~(size_t)255;
  int* part    = (int*)(ws + off); off += 512 * 4;
  int* fill    = (int*)(ws + off); off += ((size_t)NN * 4 + 255) & ~(size_t)255;
  int* gstart  = (int*)(ws + off); off += ((size_t)(NG + 1) * 4 + 255) & ~(size_t)255;
  int* col     = (int*)(ws + off); off += (size_t)NE * 4;
  unsigned* wg = (unsigned*)(ws + off); off += (size_t)NE * 4;
  bf16_t* Bp1  = (bf16_t*)(ws + off); off += (size_t)256 * 256 * 2;
  float* Y1    = (float*)(ws + off); off += (size_t)NG * 256 * 4;
  float* Y2    = (float*)(ws + off); off += (size_t)NG * 256 * 4;
  unsigned char* xf8 = (unsigned char*)(ws + off); off += (size_t)NN * DIN;
  unsigned char* hf8 = (unsigned char*)(ws + off); off += (size_t)NN * DH;

  hipMemsetAsync(cnt, 0, (size_t)NN * 4, stream);
  hipMemsetAsync(fill, 0, (size_t)NN * 4, stream);
  hipMemsetAsync(Y1, 0, (size_t)NG * 256 * 4 * 2, stream);   // Y1,Y2 contiguous
  hipMemsetAsync(d_out, 0, (size_t)out_size * 4, stream);
  k_pre<<<XCB + CTB + 32, 256, 0, stream>>>(x, dst, W1l, W1r, xf8, cnt, Bp1);
  k_scan1<<<NB1, 256, 0, stream>>>(cnt, rpl, part);
  k_scan2<<<1, 512, 0, stream>>>(part);
  k_finish<<<NB1, 256, 0, stream>>>(rpl, part, bat, rowptr, gstart, wg);
  k_bucket<<<BNB * 8, 256, 0, stream>>>(src, dst, rowptr, fill, col);
  k_gemm1<<<(NN + 63) / 64, 256, 0, stream>>>(xf8, rowptr, col, b1, Bp1, hf8);
  k_pool<<<PEB + PNB, 256, 0, stream>>>(col, wg, bat, hf8, Y1, Y2);
  k_out2<<<dim3(NG, 4), 256, 0, stream>>>(Y1, Y2, W2l, W2r, b2, gstart, (float*)d_out);
}